// Round 1
// baseline (845.856 us; speedup 1.0000x reference)
//
#include <hip/hip_runtime.h>
#include <hip/hip_bf16.h>
#include <math.h>

// ---------------- constants ----------------
#define NQ    1024
#define CC    128
#define CAM   6
#define RR    4
#define LL    4
#define PP    8
#define HHD   8     // heads
#define HDD   16    // head dim
#define GG    32
#define S_TOT 14960
#define PROPN 28

__device__ __forceinline__ float gelu_tanh(float x) {
    return 0.5f * x * (1.0f + tanhf(0.7978845608028654f * (x + 0.044715f * x * x * x)));
}

// ---------------- scatter-add into voxel grid ----------------
__global__ void k_scatter(const float* __restrict__ q, const float* __restrict__ gp,
                          float* __restrict__ grid, float* __restrict__ cnt,
                          int* __restrict__ flatidx) {
    int n = blockIdx.x;
    int c = threadIdx.x;
    __shared__ int sflat;
    if (c == 0) {
        float mx = gp[n * PROPN + 0], my = gp[n * PROPN + 1], mz = gp[n * PROPN + 2];
        int vx = (int)floorf((mx + 4.0f) * 4.0f);
        int vy = (int)floorf((my + 4.0f) * 4.0f);
        int vz = (int)floorf((mz + 4.0f) * 4.0f);
        vx = min(max(vx, 0), GG - 1);
        vy = min(max(vy, 0), GG - 1);
        vz = min(max(vz, 0), GG - 1);
        int f = (vx * GG + vy) * GG + vz;
        sflat = f;
        flatidx[n] = f;
        atomicAdd(&cnt[f], 1.0f);
    }
    __syncthreads();
    atomicAdd(&grid[sflat * CC + c], q[n * CC + c]);
}

// ---------------- sparse 3x3x3 conv at query voxels + bias + gelu ----------------
// 64 blocks x 256 threads; block handles 16 queries.
__global__ void k_conv(const float* __restrict__ grid, const float* __restrict__ cnt,
                       const int* __restrict__ flatidx, const float* __restrict__ Wsc,
                       const float* __restrict__ bsc, float* __restrict__ convout) {
    __shared__ float nb[16][CC];
    __shared__ int   nbase[16];
    __shared__ float nscale[16];
    __shared__ int   svx[16], svy[16], svz[16];
    int tid = threadIdx.x;
    int q0 = blockIdx.x * 16;
    if (tid < 16) {
        int f = flatidx[q0 + tid];
        svx[tid] = f >> 10;
        svy[tid] = (f >> 5) & 31;
        svz[tid] = f & 31;
    }
    float acc[8];
#pragma unroll
    for (int i = 0; i < 8; ++i) acc[i] = 0.f;
    int co = tid & 127, qg = tid >> 7;

    for (int tap = 0; tap < 27; ++tap) {
        int dz = tap / 9 - 1, dy = (tap / 3) % 3 - 1, dx = tap % 3 - 1;
        __syncthreads();  // protect nb/nbase of previous tap
        if (tid < 16) {
            int nx = svx[tid] + dz, ny = svy[tid] + dy, nz = svz[tid] + dx;
            bool ok = (nx >= 0 && nx < GG && ny >= 0 && ny < GG && nz >= 0 && nz < GG);
            int f = ok ? (nx * GG + ny) * GG + nz : -1;
            nbase[tid] = f;
            nscale[tid] = ok ? 1.0f / fmaxf(cnt[f], 1.0f) : 0.f;
        }
        __syncthreads();
        for (int idx = tid; idx < 16 * CC; idx += 256) {
            int qq = idx >> 7, cc2 = idx & 127;
            int f = nbase[qq];
            nb[qq][cc2] = (f >= 0) ? grid[f * CC + cc2] * nscale[qq] : 0.f;
        }
        __syncthreads();
        const float* Wt = Wsc + tap * CC * CC + co;
#pragma unroll 4
        for (int cin = 0; cin < CC; ++cin) {
            float w = Wt[cin * CC];
#pragma unroll
            for (int q8 = 0; q8 < 8; ++q8)
                acc[q8] += w * nb[qg * 8 + q8][cin];
        }
    }
    float b = bsc[co];
#pragma unroll
    for (int q8 = 0; q8 < 8; ++q8) {
        int qq = qg * 8 + q8;
        convout[(q0 + qq) * CC + co] = gelu_tanh(acc[q8] + b);
    }
}

// ---------------- layernorm: out = LN(a + b) * g + beta  (rows of 128) ----------------
__global__ void k_ln(const float* __restrict__ a, const float* __restrict__ b,
                     const float* __restrict__ g, const float* __restrict__ be,
                     float* __restrict__ out) {
    int n = blockIdx.x, c = threadIdx.x;
    float x = a[n * CC + c] + b[n * CC + c];
    __shared__ float red[CC];
    red[c] = x;
    __syncthreads();
    for (int s = 64; s >= 1; s >>= 1) { if (c < s) red[c] += red[c + s]; __syncthreads(); }
    float m = red[0] * (1.0f / CC);
    __syncthreads();
    float d = x - m;
    red[c] = d * d;
    __syncthreads();
    for (int s = 64; s >= 1; s >>= 1) { if (c < s) red[c] += red[c + s]; __syncthreads(); }
    float v = red[0] * (1.0f / CC);
    out[n * CC + c] = d * rsqrtf(v + 1e-5f) * g[c] + be[c];
}

// ---------------- generic GEMM: out = act(A[MxK] @ W[KxN] + bias) (+resid) ----------------
// tiles: 32 (M) x 64 (N), 256 threads, K in chunks of 128 (K % 128 == 0)
__global__ void k_gemm(const float* __restrict__ A, const float* __restrict__ W,
                       const float* __restrict__ bias, const float* __restrict__ resid,
                       float* __restrict__ out, int M, int K, int N, int act) {
    __shared__ float As[32][128];
    __shared__ float Ws[128][64];
    int tid = threadIdx.x;
    int tx = tid & 63, ty = tid >> 6;
    int m0 = blockIdx.y * 32, n0 = blockIdx.x * 64;
    int n = n0 + tx;
    float acc[8];
#pragma unroll
    for (int i = 0; i < 8; ++i) acc[i] = 0.f;

    for (int k0 = 0; k0 < K; k0 += 128) {
        __syncthreads();
        for (int idx = tid; idx < 32 * 128; idx += 256) {
            int m = idx >> 7, c = idx & 127;
            As[m][c] = (m0 + m < M) ? A[(size_t)(m0 + m) * K + k0 + c] : 0.f;
        }
        for (int idx = tid; idx < 128 * 64; idx += 256) {
            int c = idx >> 6, j = idx & 63;
            Ws[c][j] = (n0 + j < N) ? W[(size_t)(k0 + c) * N + n0 + j] : 0.f;
        }
        __syncthreads();
#pragma unroll 4
        for (int c = 0; c < 128; ++c) {
            float w = Ws[c][tx];
#pragma unroll
            for (int i = 0; i < 8; ++i)
                acc[i] += As[ty * 8 + i][c] * w;
        }
    }
    if (n < N) {
        float bv = bias[n];
#pragma unroll
        for (int i = 0; i < 8; ++i) {
            int m = m0 + ty * 8 + i;
            if (m < M) {
                float v = acc[i] + bv;
                if (act == 1) v = gelu_tanh(v);
                if (resid) v += resid[(size_t)m * N + n];
                out[(size_t)m * N + n] = v;
            }
        }
    }
}

// ---------------- softmax over contiguous 128-wide segments ----------------
__global__ void k_softmax(float* __restrict__ attn) {
    int row = blockIdx.x, c = threadIdx.x;
    float* p = attn + (size_t)row * 128;
    float x = p[c];
    __shared__ float red[128];
    red[c] = x;
    __syncthreads();
    for (int s = 64; s >= 1; s >>= 1) { if (c < s) red[c] = fmaxf(red[c], red[c + s]); __syncthreads(); }
    float mx = red[0];
    __syncthreads();
    float e = expf(x - mx);
    red[c] = e;
    __syncthreads();
    for (int s = 64; s >= 1; s >>= 1) { if (c < s) red[c] += red[c + s]; __syncthreads(); }
    p[c] = e / red[0];
}

// ---------------- projection + depth weighting ----------------
__global__ void k_proj(const float* __restrict__ gp, const float* __restrict__ refoff,
                       const float* __restrict__ l2i, const float* __restrict__ depth,
                       const int* __restrict__ ih, const int* __restrict__ iw,
                       float* __restrict__ wm, float* __restrict__ r2u, float* __restrict__ r2v) {
    int idx = blockIdx.x * blockDim.x + threadIdx.x;  // cam*1024 + n
    if (idx >= CAM * NQ) return;
    int cam = idx >> 10, n = idx & 1023;
    float fH = (float)(*ih), fW = (float)(*iw);
    const float* M = l2i + cam * 16;
    float mx = gp[n * PROPN], my = gp[n * PROPN + 1], mz = gp[n * PROPN + 2];
#pragma unroll
    for (int r = 0; r < RR; ++r) {
        float px = mx + refoff[n * 12 + r * 3 + 0];
        float py = my + refoff[n * 12 + r * 3 + 1];
        float pz = mz + refoff[n * 12 + r * 3 + 2];
        float p0 = M[0] * px + M[1] * py + M[2]  * pz + M[3];
        float p1 = M[4] * px + M[5] * py + M[6]  * pz + M[7];
        float p2 = M[8] * px + M[9] * py + M[10] * pz + M[11];
        float zc = fmaxf(p2, 1e-5f);
        float u = p0 / zc, v = p1 / zc;
        bool valid = (p2 > 1e-5f) && (u >= 0.f) && (u < fW) && (v >= 0.f) && (v < fH);
        int iu = min(max((int)(u / fW * 176.f), 0), 175);
        int iv = min(max((int)(v / fH * 64.f), 0), 63);
        float ds = depth[cam * 64 * 176 + iv * 176 + iu];
        int o = cam * (NQ * RR) + n * RR + r;
        wm[o]  = valid ? expf(-fabsf(p2 - ds)) : 0.f;
        r2u[o] = u / fW;
        r2v[o] = v / fH;
    }
}

// ---------------- deformable sampling + weighted reduce ----------------
// 1024 blocks (one per query) x 256 threads. thread = (h = tid>>5, slot = tid&31),
// slot -> fixed (l,p); loop over cam x r (24 items).
__global__ void k_sample(const float* __restrict__ value, const float* __restrict__ offsb,
                         const float* __restrict__ attn, const float* __restrict__ wm,
                         const float* __restrict__ r2u, const float* __restrict__ r2v,
                         float* __restrict__ sampout) {
    const int Wl_[4] = {176, 88, 44, 22};
    const int Hl_[4] = {64, 32, 16, 8};
    const int s0_[4] = {0, 11264, 14080, 14784};
    int n = blockIdx.x, tid = threadIdx.x;
    __shared__ float s_attn[1024];
    __shared__ float s_offs[2048];
    __shared__ float s_wm[24], s_ru[24], s_rv[24];
    __shared__ float red[8 * 32 * 16];

    for (int i = tid; i < 1024; i += 256) s_attn[i] = attn[(size_t)n * 1024 + i];
    for (int i = tid; i < 2048; i += 256) s_offs[i] = offsb[(size_t)n * 2048 + i];
    if (tid < 24) {
        int cam = tid >> 2, r = tid & 3;
        int o = cam * (NQ * RR) + n * RR + r;
        s_wm[tid] = wm[o]; s_ru[tid] = r2u[o]; s_rv[tid] = r2v[o];
    }
    __syncthreads();

    int h = tid >> 5, slot = tid & 31;
    int l = slot >> 3, p = slot & 7;
    int Wl = Wl_[l], Hl = Hl_[l];
    float fWl = (float)Wl, fHl = (float)Hl;
    float acc[16];
#pragma unroll
    for (int d = 0; d < 16; ++d) acc[d] = 0.f;

    float aw_base_ox = s_offs[h * 256 + l * 16 + p * 2];      // r=0 prefetch hint (unused math)
    (void)aw_base_ox;

    for (int cr = 0; cr < 24; ++cr) {
        int cam = cr >> 2, r = cr & 3;
        float ws = s_attn[h * 128 + r * 32 + l * 8 + p] * s_wm[cr];
        if (ws == 0.f) continue;
        float ox = s_offs[h * 256 + r * 64 + l * 16 + p * 2 + 0];
        float oy = s_offs[h * 256 + r * 64 + l * 16 + p * 2 + 1];
        float x = s_ru[cr] * fWl + ox - 0.5f;
        float y = s_rv[cr] * fHl + oy - 0.5f;
        float xf = floorf(x), yf = floorf(y);
        float wx = x - xf, wy = y - yf;
        int x0 = min(max((int)xf, 0), Wl - 1);
        int x1 = min(max((int)xf + 1, 0), Wl - 1);
        int y0 = min(max((int)yf, 0), Hl - 1);
        int y1 = min(max((int)yf + 1, 0), Hl - 1);
        size_t b = ((size_t)cam * S_TOT + s0_[l]) * CC + h * HDD;
        const float* p00 = value + b + (size_t)(y0 * Wl + x0) * CC;
        const float* p01 = value + b + (size_t)(y0 * Wl + x1) * CC;
        const float* p10 = value + b + (size_t)(y1 * Wl + x0) * CC;
        const float* p11 = value + b + (size_t)(y1 * Wl + x1) * CC;
        float w00 = ws * (1.f - wx) * (1.f - wy);
        float w01 = ws * wx * (1.f - wy);
        float w10 = ws * (1.f - wx) * wy;
        float w11 = ws * wx * wy;
#pragma unroll
        for (int d = 0; d < 16; ++d)
            acc[d] += w00 * p00[d] + w01 * p01[d] + w10 * p10[d] + w11 * p11[d];
    }

    int base = (h * 32 + slot) * 16;
#pragma unroll
    for (int d = 0; d < 16; ++d) red[base + d] = acc[d];
    __syncthreads();
    for (int s = 16; s >= 1; s >>= 1) {
        if (slot < s) {
#pragma unroll
            for (int d = 0; d < 16; ++d) red[base + d] += red[base + s * 16 + d];
        }
        __syncthreads();
    }
    if (tid < 128) {
        int hh = tid >> 4, dd = tid & 15;
        sampout[(size_t)n * CC + tid] = red[hh * 512 + dd];
    }
}

// ---------------- launch ----------------
extern "C" void kernel_launch(void* const* d_in, const int* in_sizes, int n_in,
                              void* d_out, int out_size, void* d_ws, size_t ws_size,
                              hipStream_t stream) {
    const float* query = (const float*)d_in[0];
    const float* gp    = (const float*)d_in[1];
    const float* ms    = (const float*)d_in[2];
    const float* depth = (const float*)d_in[3];
    const float* l2i   = (const float*)d_in[4];
    const int*   ih    = (const int*)d_in[5];
    const int*   iw    = (const int*)d_in[6];
    const float* Wsc   = (const float*)d_in[7];
    const float* bsc   = (const float*)d_in[8];
    const float* scg   = (const float*)d_in[9];
    const float* scb   = (const float*)d_in[10];
    const float* refw  = (const float*)d_in[11];
    const float* refb  = (const float*)d_in[12];
    const float* offw  = (const float*)d_in[13];
    const float* offbi = (const float*)d_in[14];
    const float* aww   = (const float*)d_in[15];
    const float* awb   = (const float*)d_in[16];
    const float* valw  = (const float*)d_in[17];
    const float* valb  = (const float*)d_in[18];
    const float* outw  = (const float*)d_in[19];
    const float* outb  = (const float*)d_in[20];
    const float* ang   = (const float*)d_in[21];
    const float* anb   = (const float*)d_in[22];
    const float* f1w   = (const float*)d_in[23];
    const float* f1b   = (const float*)d_in[24];
    const float* f2w   = (const float*)d_in[25];
    const float* f2b   = (const float*)d_in[26];
    const float* fng   = (const float*)d_in[27];
    const float* fnb   = (const float*)d_in[28];
    const float* p1w   = (const float*)d_in[29];
    const float* p1b   = (const float*)d_in[30];
    const float* p2w   = (const float*)d_in[31];
    const float* p2b   = (const float*)d_in[32];

    float* outq = (float*)d_out;            // 1024*128
    float* outp = outq + NQ * CC;           // 1024*28

    // workspace carve (floats). grid and value share the big buffer (disjoint lifetimes).
    float* ws = (float*)d_ws;
    size_t o = 0;
    float* bigbuf  = ws + o; o += (size_t)CAM * S_TOT * CC;  // 11,489,280 (value); grid uses first 4,194,304
    float* grid    = bigbuf;
    float* value   = bigbuf;
    float* cnt     = ws + o; o += GG * GG * GG;              // 32768
    int*   flatidx = (int*)(ws + o); o += NQ;
    float* q1      = ws + o; o += NQ * CC;
    float* refoff  = ws + o; o += NQ * 12;
    float* offsb   = ws + o; o += (size_t)NQ * 2048;
    float* attn    = ws + o; o += (size_t)NQ * 1024;
    float* wm      = ws + o; o += CAM * NQ * RR;
    float* r2u     = ws + o; o += CAM * NQ * RR;
    float* r2v     = ws + o; o += CAM * NQ * RR;
    float* convout = ws + o; o += NQ * CC;
    float* sampout = ws + o; o += NQ * CC;
    float* attnpr  = ws + o; o += NQ * CC;
    float* q2      = ws + o; o += NQ * CC;
    float* ffn1    = ws + o; o += NQ * 512;
    float* ffn2    = ws + o; o += NQ * CC;
    float* p1out   = ws + o; o += NQ * CC;
    (void)ws_size; (void)in_sizes; (void)n_in; (void)out_size;

    hipMemsetAsync(grid, 0, (size_t)GG * GG * GG * CC * sizeof(float), stream);
    hipMemsetAsync(cnt, 0, (size_t)GG * GG * GG * sizeof(float), stream);

    k_scatter<<<NQ, CC, 0, stream>>>(query, gp, grid, cnt, flatidx);
    k_conv<<<64, 256, 0, stream>>>(grid, cnt, flatidx, Wsc, bsc, convout);
    k_ln<<<NQ, CC, 0, stream>>>(query, convout, scg, scb, q1);

    k_gemm<<<dim3(1, 32), 256, 0, stream>>>(q1, refw, refb, nullptr, refoff, NQ, 128, 12, 0);
    k_gemm<<<dim3(32, 32), 256, 0, stream>>>(q1, offw, offbi, nullptr, offsb, NQ, 128, 2048, 0);
    k_gemm<<<dim3(16, 32), 256, 0, stream>>>(q1, aww, awb, nullptr, attn, NQ, 128, 1024, 0);
    k_softmax<<<NQ * HHD, 128, 0, stream>>>(attn);
    k_proj<<<24, 256, 0, stream>>>(gp, refoff, l2i, depth, ih, iw, wm, r2u, r2v);

    // value projection (must come after k_conv: overwrites the grid region)
    k_gemm<<<dim3(2, (CAM * S_TOT) / 32), 256, 0, stream>>>(ms, valw, valb, nullptr, value,
                                                           CAM * S_TOT, 128, 128, 0);
    k_sample<<<NQ, 256, 0, stream>>>(value, offsb, attn, wm, r2u, r2v, sampout);

    k_gemm<<<dim3(2, 32), 256, 0, stream>>>(sampout, outw, outb, nullptr, attnpr, NQ, 128, 128, 0);
    k_ln<<<NQ, CC, 0, stream>>>(q1, attnpr, ang, anb, q2);
    k_gemm<<<dim3(8, 32), 256, 0, stream>>>(q2, f1w, f1b, nullptr, ffn1, NQ, 128, 512, 1);
    k_gemm<<<dim3(2, 32), 256, 0, stream>>>(ffn1, f2w, f2b, nullptr, ffn2, NQ, 512, 128, 0);
    k_ln<<<NQ, CC, 0, stream>>>(q2, ffn2, fng, fnb, outq);
    k_gemm<<<dim3(2, 32), 256, 0, stream>>>(outq, p1w, p1b, nullptr, p1out, NQ, 128, 128, 1);
    k_gemm<<<dim3(1, 32), 256, 0, stream>>>(p1out, p2w, p2b, gp, outp, NQ, 128, PROPN, 0);
}

// Round 2
// 673.880 us; speedup vs baseline: 1.2552x; 1.2552x over previous
//
#include <hip/hip_runtime.h>
#include <hip/hip_bf16.h>
#include <math.h>

// ---------------- constants ----------------
#define NQ    1024
#define CC    128
#define CAM   6
#define RR    4
#define LL    4
#define PP    8
#define HHD   8     // heads
#define HDD   16    // head dim
#define GG    32
#define S_TOT 14960
#define PROPN 28

__device__ __forceinline__ float gelu_tanh(float x) {
    return 0.5f * x * (1.0f + tanhf(0.7978845608028654f * (x + 0.044715f * x * x * x)));
}

// ---------------- scatter-add into voxel grid ----------------
__global__ void k_scatter(const float* __restrict__ q, const float* __restrict__ gp,
                          float* __restrict__ grid, float* __restrict__ cnt,
                          int* __restrict__ flatidx) {
    int n = blockIdx.x;
    int c = threadIdx.x;
    __shared__ int sflat;
    if (c == 0) {
        float mx = gp[n * PROPN + 0], my = gp[n * PROPN + 1], mz = gp[n * PROPN + 2];
        int vx = (int)floorf((mx + 4.0f) * 4.0f);
        int vy = (int)floorf((my + 4.0f) * 4.0f);
        int vz = (int)floorf((mz + 4.0f) * 4.0f);
        vx = min(max(vx, 0), GG - 1);
        vy = min(max(vy, 0), GG - 1);
        vz = min(max(vz, 0), GG - 1);
        int f = (vx * GG + vy) * GG + vz;
        sflat = f;
        flatidx[n] = f;
        atomicAdd(&cnt[f], 1.0f);
    }
    __syncthreads();
    atomicAdd(&grid[sflat * CC + c], q[n * CC + c]);
}

// ---------------- conv stage 1: per-tap partial GEMM ----------------
// grid: (x = N-half 0..1, y = M-tile 0..15, z = tap 0..26), 256 threads.
// Each block: gather 64 neighbor rows (scaled) -> LDS, stage W[tap][:,n0:n0+64]
// -> LDS, compute 64x64 output partial with K=128, write to partials[tap].
__global__ void k_conv1(const float* __restrict__ grid, const float* __restrict__ cnt,
                        const int* __restrict__ flatidx, const float* __restrict__ Wsc,
                        float* __restrict__ partials) {
    __shared__ float As[64][CC];     // 32 KB
    __shared__ float Ws[CC][64];     // 32 KB
    __shared__ int   nbase[64];
    __shared__ float nscale[64];
    int tid = threadIdx.x;
    int tap = blockIdx.z;
    int q0 = blockIdx.y * 64;
    int n0 = blockIdx.x * 64;
    int dz = tap / 9 - 1, dy = (tap / 3) % 3 - 1, dx = tap % 3 - 1;

    if (tid < 64) {
        int f = flatidx[q0 + tid];
        int nx = (f >> 10) + dz, ny = ((f >> 5) & 31) + dy, nz = (f & 31) + dx;
        bool ok = (nx >= 0 && nx < GG && ny >= 0 && ny < GG && nz >= 0 && nz < GG);
        int nf = ok ? (nx * GG + ny) * GG + nz : -1;
        nbase[tid] = nf;
        nscale[tid] = ok ? 1.0f / fmaxf(cnt[nf], 1.0f) : 0.f;
    }
    __syncthreads();
    for (int idx = tid; idx < 64 * CC; idx += 256) {
        int q = idx >> 7, c = idx & 127;
        int f = nbase[q];
        As[q][c] = (f >= 0) ? grid[f * CC + c] * nscale[q] : 0.f;
    }
    const float* Wt = Wsc + (size_t)tap * CC * CC;
    for (int idx = tid; idx < CC * 64; idx += 256) {
        int cin = idx >> 6, j = idx & 63;
        Ws[cin][j] = Wt[cin * CC + n0 + j];
    }
    __syncthreads();

    int tx = tid & 63, ty = tid >> 6;   // ty: 0..3 -> rows ty*16..ty*16+15
    float acc[16];
#pragma unroll
    for (int i = 0; i < 16; ++i) acc[i] = 0.f;
#pragma unroll 8
    for (int c4 = 0; c4 < 32; ++c4) {
        float w0 = Ws[4 * c4 + 0][tx];
        float w1 = Ws[4 * c4 + 1][tx];
        float w2 = Ws[4 * c4 + 2][tx];
        float w3 = Ws[4 * c4 + 3][tx];
#pragma unroll
        for (int i = 0; i < 16; ++i) {
            float4 av = *(const float4*)&As[ty * 16 + i][c4 * 4];
            acc[i] += av.x * w0 + av.y * w1 + av.z * w2 + av.w * w3;
        }
    }
    float* pp = partials + (size_t)tap * (NQ * CC) + (size_t)q0 * CC + n0;
#pragma unroll
    for (int i = 0; i < 16; ++i)
        pp[(ty * 16 + i) * CC + tx] = acc[i];
}

// ---------------- conv stage 2: reduce taps + bias + gelu ----------------
__global__ void k_conv2(const float* __restrict__ partials, const float* __restrict__ bsc,
                        float* __restrict__ convout) {
    int n = blockIdx.x, c = threadIdx.x;
    float s = 0.f;
#pragma unroll
    for (int t = 0; t < 27; ++t)
        s += partials[(size_t)t * (NQ * CC) + n * CC + c];
    convout[n * CC + c] = gelu_tanh(s + bsc[c]);
}

// ---------------- layernorm: out = LN(a + b) * g + beta  (rows of 128) ----------------
__global__ void k_ln(const float* __restrict__ a, const float* __restrict__ b,
                     const float* __restrict__ g, const float* __restrict__ be,
                     float* __restrict__ out) {
    int n = blockIdx.x, c = threadIdx.x;
    float x = a[n * CC + c] + b[n * CC + c];
    __shared__ float red[CC];
    red[c] = x;
    __syncthreads();
    for (int s = 64; s >= 1; s >>= 1) { if (c < s) red[c] += red[c + s]; __syncthreads(); }
    float m = red[0] * (1.0f / CC);
    __syncthreads();
    float d = x - m;
    red[c] = d * d;
    __syncthreads();
    for (int s = 64; s >= 1; s >>= 1) { if (c < s) red[c] += red[c + s]; __syncthreads(); }
    float v = red[0] * (1.0f / CC);
    out[n * CC + c] = d * rsqrtf(v + 1e-5f) * g[c] + be[c];
}

// ---------------- generic GEMM: out = act(A[MxK] @ W[KxN] + bias) (+resid) ----------------
// tiles: 32 (M) x 64 (N), 256 threads, K in chunks of 128 (K % 128 == 0)
__global__ void k_gemm(const float* __restrict__ A, const float* __restrict__ W,
                       const float* __restrict__ bias, const float* __restrict__ resid,
                       float* __restrict__ out, int M, int K, int N, int act) {
    __shared__ float As[32][128];
    __shared__ float Ws[128][64];
    int tid = threadIdx.x;
    int tx = tid & 63, ty = tid >> 6;
    int m0 = blockIdx.y * 32, n0 = blockIdx.x * 64;
    int n = n0 + tx;
    float acc[8];
#pragma unroll
    for (int i = 0; i < 8; ++i) acc[i] = 0.f;

    for (int k0 = 0; k0 < K; k0 += 128) {
        __syncthreads();
        for (int idx = tid; idx < 32 * 128; idx += 256) {
            int m = idx >> 7, c = idx & 127;
            As[m][c] = (m0 + m < M) ? A[(size_t)(m0 + m) * K + k0 + c] : 0.f;
        }
        for (int idx = tid; idx < 128 * 64; idx += 256) {
            int c = idx >> 6, j = idx & 63;
            Ws[c][j] = (n0 + j < N) ? W[(size_t)(k0 + c) * N + n0 + j] : 0.f;
        }
        __syncthreads();
#pragma unroll 4
        for (int c4 = 0; c4 < 32; ++c4) {
            float w0 = Ws[4 * c4 + 0][tx];
            float w1 = Ws[4 * c4 + 1][tx];
            float w2 = Ws[4 * c4 + 2][tx];
            float w3 = Ws[4 * c4 + 3][tx];
#pragma unroll
            for (int i = 0; i < 8; ++i) {
                float4 av = *(const float4*)&As[ty * 8 + i][c4 * 4];
                acc[i] += av.x * w0 + av.y * w1 + av.z * w2 + av.w * w3;
            }
        }
    }
    if (n < N) {
        float bv = bias[n];
#pragma unroll
        for (int i = 0; i < 8; ++i) {
            int m = m0 + ty * 8 + i;
            if (m < M) {
                float v = acc[i] + bv;
                if (act == 1) v = gelu_tanh(v);
                if (resid) v += resid[(size_t)m * N + n];
                out[(size_t)m * N + n] = v;
            }
        }
    }
}

// ---------------- softmax over contiguous 128-wide segments ----------------
__global__ void k_softmax(float* __restrict__ attn) {
    int row = blockIdx.x, c = threadIdx.x;
    float* p = attn + (size_t)row * 128;
    float x = p[c];
    __shared__ float red[128];
    red[c] = x;
    __syncthreads();
    for (int s = 64; s >= 1; s >>= 1) { if (c < s) red[c] = fmaxf(red[c], red[c + s]); __syncthreads(); }
    float mx = red[0];
    __syncthreads();
    float e = expf(x - mx);
    red[c] = e;
    __syncthreads();
    for (int s = 64; s >= 1; s >>= 1) { if (c < s) red[c] += red[c + s]; __syncthreads(); }
    p[c] = e / red[0];
}

// ---------------- projection + depth weighting ----------------
__global__ void k_proj(const float* __restrict__ gp, const float* __restrict__ refoff,
                       const float* __restrict__ l2i, const float* __restrict__ depth,
                       const int* __restrict__ ih, const int* __restrict__ iw,
                       float* __restrict__ wm, float* __restrict__ r2u, float* __restrict__ r2v) {
    int idx = blockIdx.x * blockDim.x + threadIdx.x;  // cam*1024 + n
    if (idx >= CAM * NQ) return;
    int cam = idx >> 10, n = idx & 1023;
    float fH = (float)(*ih), fW = (float)(*iw);
    const float* M = l2i + cam * 16;
    float mx = gp[n * PROPN], my = gp[n * PROPN + 1], mz = gp[n * PROPN + 2];
#pragma unroll
    for (int r = 0; r < RR; ++r) {
        float px = mx + refoff[n * 12 + r * 3 + 0];
        float py = my + refoff[n * 12 + r * 3 + 1];
        float pz = mz + refoff[n * 12 + r * 3 + 2];
        float p0 = M[0] * px + M[1] * py + M[2]  * pz + M[3];
        float p1 = M[4] * px + M[5] * py + M[6]  * pz + M[7];
        float p2 = M[8] * px + M[9] * py + M[10] * pz + M[11];
        float zc = fmaxf(p2, 1e-5f);
        float u = p0 / zc, v = p1 / zc;
        bool valid = (p2 > 1e-5f) && (u >= 0.f) && (u < fW) && (v >= 0.f) && (v < fH);
        int iu = min(max((int)(u / fW * 176.f), 0), 175);
        int iv = min(max((int)(v / fH * 64.f), 0), 63);
        float ds = depth[cam * 64 * 176 + iv * 176 + iu];
        int o = cam * (NQ * RR) + n * RR + r;
        wm[o]  = valid ? expf(-fabsf(p2 - ds)) : 0.f;
        r2u[o] = u / fW;
        r2v[o] = v / fH;
    }
}

// ---------------- deformable sampling + weighted reduce ----------------
// 1024 blocks (one per query) x 256 threads. thread = (h = tid>>5, slot = tid&31),
// slot -> fixed (l,p); loop over cam x r (24 items).
__global__ void k_sample(const float* __restrict__ value, const float* __restrict__ offsb,
                         const float* __restrict__ attn, const float* __restrict__ wm,
                         const float* __restrict__ r2u, const float* __restrict__ r2v,
                         float* __restrict__ sampout) {
    const int Wl_[4] = {176, 88, 44, 22};
    const int Hl_[4] = {64, 32, 16, 8};
    const int s0_[4] = {0, 11264, 14080, 14784};
    int n = blockIdx.x, tid = threadIdx.x;
    __shared__ float s_attn[1024];
    __shared__ float s_offs[2048];
    __shared__ float s_wm[24], s_ru[24], s_rv[24];
    __shared__ float red[8 * 32 * 16];

    for (int i = tid; i < 1024; i += 256) s_attn[i] = attn[(size_t)n * 1024 + i];
    for (int i = tid; i < 2048; i += 256) s_offs[i] = offsb[(size_t)n * 2048 + i];
    if (tid < 24) {
        int cam = tid >> 2, r = tid & 3;
        int o = cam * (NQ * RR) + n * RR + r;
        s_wm[tid] = wm[o]; s_ru[tid] = r2u[o]; s_rv[tid] = r2v[o];
    }
    __syncthreads();

    int h = tid >> 5, slot = tid & 31;
    int l = slot >> 3, p = slot & 7;
    int Wl = Wl_[l], Hl = Hl_[l];
    float fWl = (float)Wl, fHl = (float)Hl;
    float acc[16];
#pragma unroll
    for (int d = 0; d < 16; ++d) acc[d] = 0.f;

    for (int cr = 0; cr < 24; ++cr) {
        int cam = cr >> 2, r = cr & 3;
        float ws = s_attn[h * 128 + r * 32 + l * 8 + p] * s_wm[cr];
        if (ws == 0.f) continue;
        float ox = s_offs[h * 256 + r * 64 + l * 16 + p * 2 + 0];
        float oy = s_offs[h * 256 + r * 64 + l * 16 + p * 2 + 1];
        float x = s_ru[cr] * fWl + ox - 0.5f;
        float y = s_rv[cr] * fHl + oy - 0.5f;
        float xf = floorf(x), yf = floorf(y);
        float wx = x - xf, wy = y - yf;
        int x0 = min(max((int)xf, 0), Wl - 1);
        int x1 = min(max((int)xf + 1, 0), Wl - 1);
        int y0 = min(max((int)yf, 0), Hl - 1);
        int y1 = min(max((int)yf + 1, 0), Hl - 1);
        size_t b = ((size_t)cam * S_TOT + s0_[l]) * CC + h * HDD;
        const float* p00 = value + b + (size_t)(y0 * Wl + x0) * CC;
        const float* p01 = value + b + (size_t)(y0 * Wl + x1) * CC;
        const float* p10 = value + b + (size_t)(y1 * Wl + x0) * CC;
        const float* p11 = value + b + (size_t)(y1 * Wl + x1) * CC;
        float w00 = ws * (1.f - wx) * (1.f - wy);
        float w01 = ws * wx * (1.f - wy);
        float w10 = ws * (1.f - wx) * wy;
        float w11 = ws * wx * wy;
#pragma unroll
        for (int d = 0; d < 16; ++d)
            acc[d] += w00 * p00[d] + w01 * p01[d] + w10 * p10[d] + w11 * p11[d];
    }

    int base = (h * 32 + slot) * 16;
#pragma unroll
    for (int d = 0; d < 16; ++d) red[base + d] = acc[d];
    __syncthreads();
    for (int s = 16; s >= 1; s >>= 1) {
        if (slot < s) {
#pragma unroll
            for (int d = 0; d < 16; ++d) red[base + d] += red[base + s * 16 + d];
        }
        __syncthreads();
    }
    if (tid < 128) {
        int hh = tid >> 4, dd = tid & 15;
        sampout[(size_t)n * CC + tid] = red[hh * 512 + dd];
    }
}

// ---------------- launch ----------------
extern "C" void kernel_launch(void* const* d_in, const int* in_sizes, int n_in,
                              void* d_out, int out_size, void* d_ws, size_t ws_size,
                              hipStream_t stream) {
    const float* query = (const float*)d_in[0];
    const float* gp    = (const float*)d_in[1];
    const float* ms    = (const float*)d_in[2];
    const float* depth = (const float*)d_in[3];
    const float* l2i   = (const float*)d_in[4];
    const int*   ih    = (const int*)d_in[5];
    const int*   iw    = (const int*)d_in[6];
    const float* Wsc   = (const float*)d_in[7];
    const float* bsc   = (const float*)d_in[8];
    const float* scg   = (const float*)d_in[9];
    const float* scb   = (const float*)d_in[10];
    const float* refw  = (const float*)d_in[11];
    const float* refb  = (const float*)d_in[12];
    const float* offw  = (const float*)d_in[13];
    const float* offbi = (const float*)d_in[14];
    const float* aww   = (const float*)d_in[15];
    const float* awb   = (const float*)d_in[16];
    const float* valw  = (const float*)d_in[17];
    const float* valb  = (const float*)d_in[18];
    const float* outw  = (const float*)d_in[19];
    const float* outb  = (const float*)d_in[20];
    const float* ang   = (const float*)d_in[21];
    const float* anb   = (const float*)d_in[22];
    const float* f1w   = (const float*)d_in[23];
    const float* f1b   = (const float*)d_in[24];
    const float* f2w   = (const float*)d_in[25];
    const float* f2b   = (const float*)d_in[26];
    const float* fng   = (const float*)d_in[27];
    const float* fnb   = (const float*)d_in[28];
    const float* p1w   = (const float*)d_in[29];
    const float* p1b   = (const float*)d_in[30];
    const float* p2w   = (const float*)d_in[31];
    const float* p2b   = (const float*)d_in[32];

    float* outq = (float*)d_out;            // 1024*128
    float* outp = outq + NQ * CC;           // 1024*28

    // workspace carve (floats). grid, conv partials, and value share the big
    // buffer: grid = [0, 4.19M), partials = [4.19M, 7.73M) -- both dead before
    // the value GEMM overwrites [0, 11.49M).
    float* ws = (float*)d_ws;
    size_t o = 0;
    float* bigbuf  = ws + o; o += (size_t)CAM * S_TOT * CC;  // 11,489,280 floats
    float* grid    = bigbuf;
    float* value   = bigbuf;
    float* partials = bigbuf + (size_t)GG * GG * GG * CC;    // 27*1024*128 = 3,538,944
    float* cnt     = ws + o; o += GG * GG * GG;              // 32768
    int*   flatidx = (int*)(ws + o); o += NQ;
    float* q1      = ws + o; o += NQ * CC;
    float* refoff  = ws + o; o += NQ * 12;
    float* offsb   = ws + o; o += (size_t)NQ * 2048;
    float* attn    = ws + o; o += (size_t)NQ * 1024;
    float* wm      = ws + o; o += CAM * NQ * RR;
    float* r2u     = ws + o; o += CAM * NQ * RR;
    float* r2v     = ws + o; o += CAM * NQ * RR;
    float* convout = ws + o; o += NQ * CC;
    float* sampout = ws + o; o += NQ * CC;
    float* attnpr  = ws + o; o += NQ * CC;
    float* q2      = ws + o; o += NQ * CC;
    float* ffn1    = ws + o; o += NQ * 512;
    float* ffn2    = ws + o; o += NQ * CC;
    float* p1out   = ws + o; o += NQ * CC;
    (void)ws_size; (void)in_sizes; (void)n_in; (void)out_size;

    hipMemsetAsync(grid, 0, (size_t)GG * GG * GG * CC * sizeof(float), stream);
    hipMemsetAsync(cnt, 0, (size_t)GG * GG * GG * sizeof(float), stream);

    k_scatter<<<NQ, CC, 0, stream>>>(query, gp, grid, cnt, flatidx);
    k_conv1<<<dim3(2, 16, 27), 256, 0, stream>>>(grid, cnt, flatidx, Wsc, partials);
    k_conv2<<<NQ, CC, 0, stream>>>(partials, bsc, convout);
    k_ln<<<NQ, CC, 0, stream>>>(query, convout, scg, scb, q1);

    k_gemm<<<dim3(1, 32), 256, 0, stream>>>(q1, refw, refb, nullptr, refoff, NQ, 128, 12, 0);
    k_gemm<<<dim3(32, 32), 256, 0, stream>>>(q1, offw, offbi, nullptr, offsb, NQ, 128, 2048, 0);
    k_gemm<<<dim3(16, 32), 256, 0, stream>>>(q1, aww, awb, nullptr, attn, NQ, 128, 1024, 0);
    k_softmax<<<NQ * HHD, 128, 0, stream>>>(attn);
    k_proj<<<24, 256, 0, stream>>>(gp, refoff, l2i, depth, ih, iw, wm, r2u, r2v);

    // value projection (must come after conv: overwrites grid+partials region)
    k_gemm<<<dim3(2, (CAM * S_TOT) / 32), 256, 0, stream>>>(ms, valw, valb, nullptr, value,
                                                           CAM * S_TOT, 128, 128, 0);
    k_sample<<<NQ, 256, 0, stream>>>(value, offsb, attn, wm, r2u, r2v, sampout);

    k_gemm<<<dim3(2, 32), 256, 0, stream>>>(sampout, outw, outb, nullptr, attnpr, NQ, 128, 128, 0);
    k_ln<<<NQ, CC, 0, stream>>>(q1, attnpr, ang, anb, q2);
    k_gemm<<<dim3(8, 32), 256, 0, stream>>>(q2, f1w, f1b, nullptr, ffn1, NQ, 128, 512, 1);
    k_gemm<<<dim3(2, 32), 256, 0, stream>>>(ffn1, f2w, f2b, nullptr, ffn2, NQ, 512, 128, 0);
    k_ln<<<NQ, CC, 0, stream>>>(q2, ffn2, fng, fnb, outq);
    k_gemm<<<dim3(2, 32), 256, 0, stream>>>(outq, p1w, p1b, nullptr, p1out, NQ, 128, 128, 1);
    k_gemm<<<dim3(1, 32), 256, 0, stream>>>(p1out, p2w, p2b, gp, outp, NQ, 128, PROPN, 0);
}

// Round 3
// 462.537 us; speedup vs baseline: 1.8287x; 1.4569x over previous
//
#include <hip/hip_runtime.h>
#include <hip/hip_bf16.h>
#include <math.h>

// ---------------- constants ----------------
#define NQ    1024
#define CC    128
#define CAM   6
#define RR    4
#define LL    4
#define PP    8
#define HHD   8     // heads
#define HDD   16    // head dim
#define GG    32
#define S_TOT 14960
#define PROPN 28

typedef __attribute__((ext_vector_type(8))) short bf16x8;
typedef __attribute__((ext_vector_type(4))) float f32x4;

__device__ __forceinline__ float gelu_tanh(float x) {
    return 0.5f * x * (1.0f + tanhf(0.7978845608028654f * (x + 0.044715f * x * x * x)));
}

__device__ __forceinline__ unsigned short f2bf(float f) {
    union { float f; unsigned int u; } x; x.f = f;
    unsigned int r = (x.u + 0x7FFFu + ((x.u >> 16) & 1u)) >> 16;
    return (unsigned short)r;
}

// ---------------- scatter-add into voxel grid ----------------
__global__ void k_scatter(const float* __restrict__ q, const float* __restrict__ gp,
                          float* __restrict__ grid, float* __restrict__ cnt,
                          int* __restrict__ flatidx) {
    int n = blockIdx.x;
    int c = threadIdx.x;
    __shared__ int sflat;
    if (c == 0) {
        float mx = gp[n * PROPN + 0], my = gp[n * PROPN + 1], mz = gp[n * PROPN + 2];
        int vx = (int)floorf((mx + 4.0f) * 4.0f);
        int vy = (int)floorf((my + 4.0f) * 4.0f);
        int vz = (int)floorf((mz + 4.0f) * 4.0f);
        vx = min(max(vx, 0), GG - 1);
        vy = min(max(vy, 0), GG - 1);
        vz = min(max(vz, 0), GG - 1);
        int f = (vx * GG + vy) * GG + vz;
        sflat = f;
        flatidx[n] = f;
        atomicAdd(&cnt[f], 1.0f);
    }
    __syncthreads();
    atomicAdd(&grid[sflat * CC + c], q[n * CC + c]);
}

// ---------------- generic MFMA bf16 GEMM ----------------
// out[M,N] = act(A[M,K] @ W[K,N] + bias) (+resid). N % 128 == 0, K % 128 == 0.
// grid: (N/128, ceil(M/128)), 256 threads (4 waves in 2x2, each wave 64x64).
__global__ void k_mfma(const float* __restrict__ A, const float* __restrict__ W,
                       const float* __restrict__ bias, const float* __restrict__ resid,
                       float* __restrict__ out, int M, int K, int N, int act) {
    __shared__ bf16x8 As[128 * 16];   // [m][kchunk swizzled]
    __shared__ bf16x8 Bs[128 * 16];   // [n][kchunk swizzled] (B transposed)
    int tid = threadIdx.x;
    int m0 = blockIdx.y * 128, n0 = blockIdx.x * 128;
    int lane = tid & 63, wv = tid >> 6;
    int wr = (wv >> 1) * 64, wc = (wv & 1) * 64;
    int r = lane & 15, q = lane >> 4;

    f32x4 acc[4][4];
#pragma unroll
    for (int i = 0; i < 4; ++i)
#pragma unroll
        for (int j = 0; j < 4; ++j)
#pragma unroll
            for (int e = 0; e < 4; ++e) acc[i][j][e] = 0.f;

    for (int kc = 0; kc < K; kc += 128) {
        if (kc) __syncthreads();
        // stage A -> bf16 LDS
        for (int idx = tid; idx < 2048; idx += 256) {
            int m = idx >> 4, c = idx & 15;
            float v[8];
            if (m0 + m < M) {
                const float* p = A + (size_t)(m0 + m) * K + kc + c * 8;
                float4 a = *(const float4*)p;
                float4 b = *(const float4*)(p + 4);
                v[0] = a.x; v[1] = a.y; v[2] = a.z; v[3] = a.w;
                v[4] = b.x; v[5] = b.y; v[6] = b.z; v[7] = b.w;
            } else {
#pragma unroll
                for (int j = 0; j < 8; ++j) v[j] = 0.f;
            }
            bf16x8 u;
#pragma unroll
            for (int j = 0; j < 8; ++j) u[j] = (short)f2bf(v[j]);
            As[m * 16 + (c ^ (m & 15))] = u;
        }
        // stage B transposed -> bf16 LDS
        unsigned short* Bsu = (unsigned short*)Bs;
        for (int idx = tid; idx < 4096; idx += 256) {
            int k = idx >> 5, ng = (idx & 31) * 4;
            const float* p = W + (size_t)(kc + k) * N + n0 + ng;
            float4 w4 = *(const float4*)p;
            float wa[4] = {w4.x, w4.y, w4.z, w4.w};
#pragma unroll
            for (int j = 0; j < 4; ++j) {
                int n = ng + j;
                Bsu[(n * 16 + ((k >> 3) ^ (n & 15))) * 8 + (k & 7)] = f2bf(wa[j]);
            }
        }
        __syncthreads();
#pragma unroll
        for (int ks = 0; ks < 4; ++ks) {
            bf16x8 af[4], bfr[4];
#pragma unroll
            for (int i = 0; i < 4; ++i)
                af[i] = As[(wr + i * 16 + r) * 16 + ((ks * 4 + q) ^ r)];
#pragma unroll
            for (int j = 0; j < 4; ++j)
                bfr[j] = Bs[(wc + j * 16 + r) * 16 + ((ks * 4 + q) ^ r)];
#pragma unroll
            for (int i = 0; i < 4; ++i)
#pragma unroll
                for (int j = 0; j < 4; ++j)
                    acc[i][j] = __builtin_amdgcn_mfma_f32_16x16x32_bf16(af[i], bfr[j], acc[i][j], 0, 0, 0);
        }
    }
    // epilogue
#pragma unroll
    for (int i = 0; i < 4; ++i) {
#pragma unroll
        for (int e = 0; e < 4; ++e) {
            int m = m0 + wr + i * 16 + q * 4 + e;
            if (m < M) {
#pragma unroll
                for (int j = 0; j < 4; ++j) {
                    int col = n0 + wc + j * 16 + r;
                    float v = acc[i][j][e] + bias[col];
                    if (act == 1) v = gelu_tanh(v);
                    if (resid) v += resid[(size_t)m * N + col];
                    out[(size_t)m * N + col] = v;
                }
            }
        }
    }
}

// ---------------- conv as 27 per-tap MFMA GEMMs with atomic accumulate ----------------
// grid: (8 m-tiles, 27 taps), 256 threads. accum must be zeroed.
__global__ void k_conv1m(const float* __restrict__ grid, const float* __restrict__ cnt,
                         const int* __restrict__ flatidx, const float* __restrict__ Wsc,
                         float* __restrict__ accum) {
    __shared__ bf16x8 As[128 * 16];
    __shared__ bf16x8 Bs[128 * 16];
    __shared__ int   nbase[128];
    __shared__ float nscale[128];
    int tid = threadIdx.x;
    int tap = blockIdx.y;
    int q0 = blockIdx.x * 128;
    int dz = tap / 9 - 1, dy = (tap / 3) % 3 - 1, dx = tap % 3 - 1;

    if (tid < 128) {
        int f = flatidx[q0 + tid];
        int nx = (f >> 10) + dz, ny = ((f >> 5) & 31) + dy, nz = (f & 31) + dx;
        bool ok = (nx >= 0 && nx < GG && ny >= 0 && ny < GG && nz >= 0 && nz < GG);
        int nf = ok ? (nx * GG + ny) * GG + nz : -1;
        nbase[tid] = nf;
        nscale[tid] = ok ? 1.0f / fmaxf(cnt[nf], 1.0f) : 0.f;
    }
    __syncthreads();
    // stage gathered A
    for (int idx = tid; idx < 2048; idx += 256) {
        int m = idx >> 4, c = idx & 15;
        int f = nbase[m];
        float s = nscale[m];
        float v[8];
        if (f >= 0) {
            const float* p = grid + (size_t)f * CC + c * 8;
            float4 a = *(const float4*)p;
            float4 b = *(const float4*)(p + 4);
            v[0] = a.x * s; v[1] = a.y * s; v[2] = a.z * s; v[3] = a.w * s;
            v[4] = b.x * s; v[5] = b.y * s; v[6] = b.z * s; v[7] = b.w * s;
        } else {
#pragma unroll
            for (int j = 0; j < 8; ++j) v[j] = 0.f;
        }
        bf16x8 u;
#pragma unroll
        for (int j = 0; j < 8; ++j) u[j] = (short)f2bf(v[j]);
        As[m * 16 + (c ^ (m & 15))] = u;
    }
    // stage W[tap] transposed
    const float* W = Wsc + (size_t)tap * CC * CC;
    unsigned short* Bsu = (unsigned short*)Bs;
    for (int idx = tid; idx < 4096; idx += 256) {
        int k = idx >> 5, ng = (idx & 31) * 4;
        const float* p = W + (size_t)k * CC + ng;
        float4 w4 = *(const float4*)p;
        float wa[4] = {w4.x, w4.y, w4.z, w4.w};
#pragma unroll
        for (int j = 0; j < 4; ++j) {
            int n = ng + j;
            Bsu[(n * 16 + ((k >> 3) ^ (n & 15))) * 8 + (k & 7)] = f2bf(wa[j]);
        }
    }
    __syncthreads();

    int lane = tid & 63, wv = tid >> 6;
    int wr = (wv >> 1) * 64, wc = (wv & 1) * 64;
    int r = lane & 15, q = lane >> 4;
    f32x4 acc[4][4];
#pragma unroll
    for (int i = 0; i < 4; ++i)
#pragma unroll
        for (int j = 0; j < 4; ++j)
#pragma unroll
            for (int e = 0; e < 4; ++e) acc[i][j][e] = 0.f;
#pragma unroll
    for (int ks = 0; ks < 4; ++ks) {
        bf16x8 af[4], bfr[4];
#pragma unroll
        for (int i = 0; i < 4; ++i)
            af[i] = As[(wr + i * 16 + r) * 16 + ((ks * 4 + q) ^ r)];
#pragma unroll
        for (int j = 0; j < 4; ++j)
            bfr[j] = Bs[(wc + j * 16 + r) * 16 + ((ks * 4 + q) ^ r)];
#pragma unroll
        for (int i = 0; i < 4; ++i)
#pragma unroll
            for (int j = 0; j < 4; ++j)
                acc[i][j] = __builtin_amdgcn_mfma_f32_16x16x32_bf16(af[i], bfr[j], acc[i][j], 0, 0, 0);
    }
#pragma unroll
    for (int i = 0; i < 4; ++i)
#pragma unroll
        for (int e = 0; e < 4; ++e) {
            int m = q0 + wr + i * 16 + q * 4 + e;
#pragma unroll
            for (int j = 0; j < 4; ++j) {
                int col = wc + j * 16 + r;
                atomicAdd(&accum[(size_t)m * CC + col], acc[i][j][e]);
            }
        }
}

// ---------------- LN variants ----------------
__global__ void k_ln(const float* __restrict__ a, const float* __restrict__ b,
                     const float* __restrict__ g, const float* __restrict__ be,
                     float* __restrict__ out) {
    int n = blockIdx.x, c = threadIdx.x;
    float x = a[n * CC + c] + b[n * CC + c];
    __shared__ float red[CC];
    red[c] = x;
    __syncthreads();
    for (int s = 64; s >= 1; s >>= 1) { if (c < s) red[c] += red[c + s]; __syncthreads(); }
    float m = red[0] * (1.0f / CC);
    __syncthreads();
    float d = x - m;
    red[c] = d * d;
    __syncthreads();
    for (int s = 64; s >= 1; s >>= 1) { if (c < s) red[c] += red[c + s]; __syncthreads(); }
    float v = red[0] * (1.0f / CC);
    out[n * CC + c] = d * rsqrtf(v + 1e-5f) * g[c] + be[c];
}

// q1 = LN(query + gelu(accum + bias)) * g + be
__global__ void k_ln_conv(const float* __restrict__ a, const float* __restrict__ accum,
                          const float* __restrict__ bconv,
                          const float* __restrict__ g, const float* __restrict__ be,
                          float* __restrict__ out) {
    int n = blockIdx.x, c = threadIdx.x;
    float x = a[n * CC + c] + gelu_tanh(accum[n * CC + c] + bconv[c]);
    __shared__ float red[CC];
    red[c] = x;
    __syncthreads();
    for (int s = 64; s >= 1; s >>= 1) { if (c < s) red[c] += red[c + s]; __syncthreads(); }
    float m = red[0] * (1.0f / CC);
    __syncthreads();
    float d = x - m;
    red[c] = d * d;
    __syncthreads();
    for (int s = 64; s >= 1; s >>= 1) { if (c < s) red[c] += red[c + s]; __syncthreads(); }
    float v = red[0] * (1.0f / CC);
    out[n * CC + c] = d * rsqrtf(v + 1e-5f) * g[c] + be[c];
}

// ---------------- fp32 GEMM for small N (12, 28) ----------------
__global__ void k_gemm(const float* __restrict__ A, const float* __restrict__ W,
                       const float* __restrict__ bias, const float* __restrict__ resid,
                       float* __restrict__ out, int M, int K, int N, int act) {
    __shared__ float As[32][128];
    __shared__ float Ws[128][64];
    int tid = threadIdx.x;
    int tx = tid & 63, ty = tid >> 6;
    int m0 = blockIdx.y * 32, n0 = blockIdx.x * 64;
    int n = n0 + tx;
    float acc[8];
#pragma unroll
    for (int i = 0; i < 8; ++i) acc[i] = 0.f;

    for (int k0 = 0; k0 < K; k0 += 128) {
        __syncthreads();
        for (int idx = tid; idx < 32 * 128; idx += 256) {
            int m = idx >> 7, c = idx & 127;
            As[m][c] = (m0 + m < M) ? A[(size_t)(m0 + m) * K + k0 + c] : 0.f;
        }
        for (int idx = tid; idx < 128 * 64; idx += 256) {
            int c = idx >> 6, j = idx & 63;
            Ws[c][j] = (n0 + j < N) ? W[(size_t)(k0 + c) * N + n0 + j] : 0.f;
        }
        __syncthreads();
#pragma unroll 4
        for (int c4 = 0; c4 < 32; ++c4) {
            float w0 = Ws[4 * c4 + 0][tx];
            float w1 = Ws[4 * c4 + 1][tx];
            float w2 = Ws[4 * c4 + 2][tx];
            float w3 = Ws[4 * c4 + 3][tx];
#pragma unroll
            for (int i = 0; i < 8; ++i) {
                float4 av = *(const float4*)&As[ty * 8 + i][c4 * 4];
                acc[i] += av.x * w0 + av.y * w1 + av.z * w2 + av.w * w3;
            }
        }
    }
    if (n < N) {
        float bv = bias[n];
#pragma unroll
        for (int i = 0; i < 8; ++i) {
            int m = m0 + ty * 8 + i;
            if (m < M) {
                float v = acc[i] + bv;
                if (act == 1) v = gelu_tanh(v);
                if (resid) v += resid[(size_t)m * N + n];
                out[(size_t)m * N + n] = v;
            }
        }
    }
}

// ---------------- softmax over contiguous 128-wide segments ----------------
__global__ void k_softmax(float* __restrict__ attn) {
    int row = blockIdx.x, c = threadIdx.x;
    float* p = attn + (size_t)row * 128;
    float x = p[c];
    __shared__ float red[128];
    red[c] = x;
    __syncthreads();
    for (int s = 64; s >= 1; s >>= 1) { if (c < s) red[c] = fmaxf(red[c], red[c + s]); __syncthreads(); }
    float mx = red[0];
    __syncthreads();
    float e = expf(x - mx);
    red[c] = e;
    __syncthreads();
    for (int s = 64; s >= 1; s >>= 1) { if (c < s) red[c] += red[c + s]; __syncthreads(); }
    p[c] = e / red[0];
}

// ---------------- projection + depth weighting ----------------
__global__ void k_proj(const float* __restrict__ gp, const float* __restrict__ refoff,
                       const float* __restrict__ l2i, const float* __restrict__ depth,
                       const int* __restrict__ ih, const int* __restrict__ iw,
                       float* __restrict__ wm, float* __restrict__ r2u, float* __restrict__ r2v) {
    int idx = blockIdx.x * blockDim.x + threadIdx.x;  // cam*1024 + n
    if (idx >= CAM * NQ) return;
    int cam = idx >> 10, n = idx & 1023;
    float fH = (float)(*ih), fW = (float)(*iw);
    const float* M = l2i + cam * 16;
    float mx = gp[n * PROPN], my = gp[n * PROPN + 1], mz = gp[n * PROPN + 2];
#pragma unroll
    for (int r = 0; r < RR; ++r) {
        float px = mx + refoff[n * 12 + r * 3 + 0];
        float py = my + refoff[n * 12 + r * 3 + 1];
        float pz = mz + refoff[n * 12 + r * 3 + 2];
        float p0 = M[0] * px + M[1] * py + M[2]  * pz + M[3];
        float p1 = M[4] * px + M[5] * py + M[6]  * pz + M[7];
        float p2 = M[8] * px + M[9] * py + M[10] * pz + M[11];
        float zc = fmaxf(p2, 1e-5f);
        float u = p0 / zc, v = p1 / zc;
        bool valid = (p2 > 1e-5f) && (u >= 0.f) && (u < fW) && (v >= 0.f) && (v < fH);
        int iu = min(max((int)(u / fW * 176.f), 0), 175);
        int iv = min(max((int)(v / fH * 64.f), 0), 63);
        float ds = depth[cam * 64 * 176 + iv * 176 + iu];
        int o = cam * (NQ * RR) + n * RR + r;
        wm[o]  = valid ? expf(-fabsf(p2 - ds)) : 0.f;
        r2u[o] = u / fW;
        r2v[o] = v / fH;
    }
}

// ---------------- deformable sampling + weighted reduce ----------------
__global__ void k_sample(const float* __restrict__ value, const float* __restrict__ offsb,
                         const float* __restrict__ attn, const float* __restrict__ wm,
                         const float* __restrict__ r2u, const float* __restrict__ r2v,
                         float* __restrict__ sampout) {
    const int Wl_[4] = {176, 88, 44, 22};
    const int Hl_[4] = {64, 32, 16, 8};
    const int s0_[4] = {0, 11264, 14080, 14784};
    int n = blockIdx.x, tid = threadIdx.x;
    __shared__ float s_attn[1024];
    __shared__ float s_offs[2048];
    __shared__ float s_wm[24], s_ru[24], s_rv[24];
    __shared__ float red[8 * 32 * 16];

    for (int i = tid; i < 1024; i += 256) s_attn[i] = attn[(size_t)n * 1024 + i];
    for (int i = tid; i < 2048; i += 256) s_offs[i] = offsb[(size_t)n * 2048 + i];
    if (tid < 24) {
        int cam = tid >> 2, r = tid & 3;
        int o = cam * (NQ * RR) + n * RR + r;
        s_wm[tid] = wm[o]; s_ru[tid] = r2u[o]; s_rv[tid] = r2v[o];
    }
    __syncthreads();

    int h = tid >> 5, slot = tid & 31;
    int l = slot >> 3, p = slot & 7;
    int Wl = Wl_[l], Hl = Hl_[l];
    float fWl = (float)Wl, fHl = (float)Hl;
    float acc[16];
#pragma unroll
    for (int d = 0; d < 16; ++d) acc[d] = 0.f;

    for (int cr = 0; cr < 24; ++cr) {
        int cam = cr >> 2, r = cr & 3;
        float ws = s_attn[h * 128 + r * 32 + l * 8 + p] * s_wm[cr];
        if (ws == 0.f) continue;
        float ox = s_offs[h * 256 + r * 64 + l * 16 + p * 2 + 0];
        float oy = s_offs[h * 256 + r * 64 + l * 16 + p * 2 + 1];
        float x = s_ru[cr] * fWl + ox - 0.5f;
        float y = s_rv[cr] * fHl + oy - 0.5f;
        float xf = floorf(x), yf = floorf(y);
        float wx = x - xf, wy = y - yf;
        int x0 = min(max((int)xf, 0), Wl - 1);
        int x1 = min(max((int)xf + 1, 0), Wl - 1);
        int y0 = min(max((int)yf, 0), Hl - 1);
        int y1 = min(max((int)yf + 1, 0), Hl - 1);
        size_t b = ((size_t)cam * S_TOT + s0_[l]) * CC + h * HDD;
        const float* p00 = value + b + (size_t)(y0 * Wl + x0) * CC;
        const float* p01 = value + b + (size_t)(y0 * Wl + x1) * CC;
        const float* p10 = value + b + (size_t)(y1 * Wl + x0) * CC;
        const float* p11 = value + b + (size_t)(y1 * Wl + x1) * CC;
        float w00 = ws * (1.f - wx) * (1.f - wy);
        float w01 = ws * wx * (1.f - wy);
        float w10 = ws * (1.f - wx) * wy;
        float w11 = ws * wx * wy;
#pragma unroll
        for (int d = 0; d < 16; ++d)
            acc[d] += w00 * p00[d] + w01 * p01[d] + w10 * p10[d] + w11 * p11[d];
    }

    int base = (h * 32 + slot) * 16;
#pragma unroll
    for (int d = 0; d < 16; ++d) red[base + d] = acc[d];
    __syncthreads();
    for (int s = 16; s >= 1; s >>= 1) {
        if (slot < s) {
#pragma unroll
            for (int d = 0; d < 16; ++d) red[base + d] += red[base + s * 16 + d];
        }
        __syncthreads();
    }
    if (tid < 128) {
        int hh = tid >> 4, dd = tid & 15;
        sampout[(size_t)n * CC + tid] = red[hh * 512 + dd];
    }
}

// ---------------- launch ----------------
extern "C" void kernel_launch(void* const* d_in, const int* in_sizes, int n_in,
                              void* d_out, int out_size, void* d_ws, size_t ws_size,
                              hipStream_t stream) {
    const float* query = (const float*)d_in[0];
    const float* gp    = (const float*)d_in[1];
    const float* ms    = (const float*)d_in[2];
    const float* depth = (const float*)d_in[3];
    const float* l2i   = (const float*)d_in[4];
    const int*   ih    = (const int*)d_in[5];
    const int*   iw    = (const int*)d_in[6];
    const float* Wsc   = (const float*)d_in[7];
    const float* bsc   = (const float*)d_in[8];
    const float* scg   = (const float*)d_in[9];
    const float* scb   = (const float*)d_in[10];
    const float* refw  = (const float*)d_in[11];
    const float* refb  = (const float*)d_in[12];
    const float* offw  = (const float*)d_in[13];
    const float* offbi = (const float*)d_in[14];
    const float* aww   = (const float*)d_in[15];
    const float* awb   = (const float*)d_in[16];
    const float* valw  = (const float*)d_in[17];
    const float* valb  = (const float*)d_in[18];
    const float* outw  = (const float*)d_in[19];
    const float* outb  = (const float*)d_in[20];
    const float* ang   = (const float*)d_in[21];
    const float* anb   = (const float*)d_in[22];
    const float* f1w   = (const float*)d_in[23];
    const float* f1b   = (const float*)d_in[24];
    const float* f2w   = (const float*)d_in[25];
    const float* f2b   = (const float*)d_in[26];
    const float* fng   = (const float*)d_in[27];
    const float* fnb   = (const float*)d_in[28];
    const float* p1w   = (const float*)d_in[29];
    const float* p1b   = (const float*)d_in[30];
    const float* p2w   = (const float*)d_in[31];
    const float* p2b   = (const float*)d_in[32];

    float* outq = (float*)d_out;            // 1024*128
    float* outp = outq + NQ * CC;           // 1024*28

    // workspace carve (floats). grid and value share the big buffer
    // (disjoint lifetimes: conv reads grid before value GEMM overwrites).
    float* ws = (float*)d_ws;
    size_t o = 0;
    float* bigbuf  = ws + o; o += (size_t)CAM * S_TOT * CC;  // 11,489,280 floats
    float* grid    = bigbuf;
    float* value   = bigbuf;
    float* cnt     = ws + o; o += GG * GG * GG;
    int*   flatidx = (int*)(ws + o); o += NQ;
    float* convacc = ws + o; o += NQ * CC;
    float* q1      = ws + o; o += NQ * CC;
    float* refoff  = ws + o; o += NQ * 12;
    float* offsb   = ws + o; o += (size_t)NQ * 2048;
    float* attn    = ws + o; o += (size_t)NQ * 1024;
    float* wm      = ws + o; o += CAM * NQ * RR;
    float* r2u     = ws + o; o += CAM * NQ * RR;
    float* r2v     = ws + o; o += CAM * NQ * RR;
    float* sampout = ws + o; o += NQ * CC;
    float* attnpr  = ws + o; o += NQ * CC;
    float* q2      = ws + o; o += NQ * CC;
    float* ffn1    = ws + o; o += NQ * 512;
    float* ffn2    = ws + o; o += NQ * CC;
    float* p1out   = ws + o; o += NQ * CC;
    (void)ws_size; (void)in_sizes; (void)n_in; (void)out_size;

    hipMemsetAsync(grid, 0, (size_t)GG * GG * GG * CC * sizeof(float), stream);
    hipMemsetAsync(cnt, 0, (size_t)GG * GG * GG * sizeof(float), stream);
    hipMemsetAsync(convacc, 0, (size_t)NQ * CC * sizeof(float), stream);

    k_scatter<<<NQ, CC, 0, stream>>>(query, gp, grid, cnt, flatidx);
    k_conv1m<<<dim3(8, 27), 256, 0, stream>>>(grid, cnt, flatidx, Wsc, convacc);
    k_ln_conv<<<NQ, CC, 0, stream>>>(query, convacc, bsc, scg, scb, q1);

    k_gemm<<<dim3(1, 32), 256, 0, stream>>>(q1, refw, refb, nullptr, refoff, NQ, 128, 12, 0);
    k_mfma<<<dim3(16, 8), 256, 0, stream>>>(q1, offw, offbi, nullptr, offsb, NQ, 128, 2048, 0);
    k_mfma<<<dim3(8, 8), 256, 0, stream>>>(q1, aww, awb, nullptr, attn, NQ, 128, 1024, 0);
    k_softmax<<<NQ * HHD, 128, 0, stream>>>(attn);
    k_proj<<<24, 256, 0, stream>>>(gp, refoff, l2i, depth, ih, iw, wm, r2u, r2v);

    // value projection (after conv: overwrites grid region)
    k_mfma<<<dim3(1, 702), 256, 0, stream>>>(ms, valw, valb, nullptr, value,
                                             CAM * S_TOT, 128, 128, 0);
    k_sample<<<NQ, 256, 0, stream>>>(value, offsb, attn, wm, r2u, r2v, sampout);

    k_mfma<<<dim3(1, 8), 256, 0, stream>>>(sampout, outw, outb, nullptr, attnpr, NQ, 128, 128, 0);
    k_ln<<<NQ, CC, 0, stream>>>(q1, attnpr, ang, anb, q2);
    k_mfma<<<dim3(4, 8), 256, 0, stream>>>(q2, f1w, f1b, nullptr, ffn1, NQ, 128, 512, 1);
    k_mfma<<<dim3(1, 8), 256, 0, stream>>>(ffn1, f2w, f2b, nullptr, ffn2, NQ, 512, 128, 0);
    k_ln<<<NQ, CC, 0, stream>>>(q2, ffn2, fng, fnb, outq);
    k_mfma<<<dim3(1, 8), 256, 0, stream>>>(outq, p1w, p1b, nullptr, p1out, NQ, 128, 128, 1);
    k_gemm<<<dim3(1, 32), 256, 0, stream>>>(p1out, p2w, p2b, gp, outp, NQ, 128, PROPN, 0);
}

// Round 4
// 364.140 us; speedup vs baseline: 2.3229x; 1.2702x over previous
//
#include <hip/hip_runtime.h>
#include <hip/hip_bf16.h>
#include <math.h>

// ---------------- constants ----------------
#define NQ    1024
#define CC    128
#define CAM   6
#define RR    4
#define LL    4
#define PP    8
#define HHD   8     // heads
#define HDD   16    // head dim
#define GG    32
#define S_TOT 14960
#define PROPN 28

typedef __attribute__((ext_vector_type(8))) short bf16x8;
typedef __attribute__((ext_vector_type(4))) float f32x4;

__device__ __forceinline__ float gelu_tanh(float x) {
    return 0.5f * x * (1.0f + tanhf(0.7978845608028654f * (x + 0.044715f * x * x * x)));
}

__device__ __forceinline__ unsigned short f2bf(float f) {
    union { float f; unsigned int u; } x; x.f = f;
    unsigned int r = (x.u + 0x7FFFu + ((x.u >> 16) & 1u)) >> 16;
    return (unsigned short)r;
}

// ---------------- weight transpose+convert: W[K][N] fp32 -> WT[N][K] bf16 ----------------
// grid (N/64, K/64, Z) ; Z slices advance both pointers by K*N.
__global__ void k_wt(const float* __restrict__ W, unsigned short* __restrict__ WT,
                     int K, int N) {
    __shared__ float t[64][65];
    int n0 = blockIdx.x * 64, k0 = blockIdx.y * 64;
    size_t zo = (size_t)blockIdx.z * K * N;
    const float* Wz = W + zo;
    unsigned short* WTz = WT + zo;
    int tid = threadIdx.x;
#pragma unroll
    for (int it = 0; it < 16; ++it) {
        int idx = tid + it * 256;
        int r = idx >> 6, c = idx & 63;
        t[r][c] = Wz[(size_t)(k0 + r) * N + n0 + c];
    }
    __syncthreads();
#pragma unroll
    for (int it = 0; it < 16; ++it) {
        int idx = tid + it * 256;
        int r = idx >> 6, c = idx & 63;
        WTz[(size_t)(n0 + r) * K + k0 + c] = f2bf(t[c][r]);
    }
}

// batched 128x128 transposes: z<27 -> conv taps, 27/28/29 -> val/out/p1
__global__ void k_wt128(const float* __restrict__ wc0, unsigned short* __restrict__ tc0,
                        const float* __restrict__ w1, unsigned short* __restrict__ t1,
                        const float* __restrict__ w2, unsigned short* __restrict__ t2,
                        const float* __restrict__ w3, unsigned short* __restrict__ t3) {
    __shared__ float t[64][65];
    int z = blockIdx.z;
    const float* W; unsigned short* WT;
    if (z < 27)      { W = wc0 + (size_t)z * 16384; WT = tc0 + (size_t)z * 16384; }
    else if (z == 27){ W = w1; WT = t1; }
    else if (z == 28){ W = w2; WT = t2; }
    else             { W = w3; WT = t3; }
    int n0 = blockIdx.x * 64, k0 = blockIdx.y * 64;
    int tid = threadIdx.x;
#pragma unroll
    for (int it = 0; it < 16; ++it) {
        int idx = tid + it * 256;
        int r = idx >> 6, c = idx & 63;
        t[r][c] = W[(size_t)(k0 + r) * 128 + n0 + c];
    }
    __syncthreads();
#pragma unroll
    for (int it = 0; it < 16; ++it) {
        int idx = tid + it * 256;
        int r = idx >> 6, c = idx & 63;
        WT[(size_t)(n0 + r) * 128 + k0 + c] = f2bf(t[c][r]);
    }
}

// ---------------- scatter-add into voxel grid ----------------
__global__ void k_scatter(const float* __restrict__ q, const float* __restrict__ gp,
                          float* __restrict__ grid, float* __restrict__ cnt,
                          int* __restrict__ flatidx) {
    int n = blockIdx.x;
    int c = threadIdx.x;
    __shared__ int sflat;
    if (c == 0) {
        float mx = gp[n * PROPN + 0], my = gp[n * PROPN + 1], mz = gp[n * PROPN + 2];
        int vx = (int)floorf((mx + 4.0f) * 4.0f);
        int vy = (int)floorf((my + 4.0f) * 4.0f);
        int vz = (int)floorf((mz + 4.0f) * 4.0f);
        vx = min(max(vx, 0), GG - 1);
        vy = min(max(vy, 0), GG - 1);
        vz = min(max(vz, 0), GG - 1);
        int f = (vx * GG + vy) * GG + vz;
        sflat = f;
        flatidx[n] = f;
        atomicAdd(&cnt[f], 1.0f);
    }
    __syncthreads();
    atomicAdd(&grid[sflat * CC + c], q[n * CC + c]);
}

// ---------------- generic MFMA bf16 GEMM with bf16 pre-transposed weights ----------------
// out[M,N] = epilogue(A[M,K] @ WT[N,K]^T). BN = 128. FUSE: 0 plain(+act/+resid),
// 1 = +bias +resid +LayerNorm (N must be 128), 2 = +bias +softmax over the 128-col tile.
template<int BM, int FUSE>
__global__ __launch_bounds__(256) void k_mfma_bt(
    const float* __restrict__ A, const unsigned short* __restrict__ WT,
    const float* __restrict__ bias, const float* __restrict__ resid,
    const float* __restrict__ lng, const float* __restrict__ lnb,
    float* __restrict__ out, int M, int K, int N, int act)
{
    constexpr int WM = BM / 32;            // 16-row tiles per wave
    __shared__ bf16x8 As[BM * 16];
    __shared__ bf16x8 Bs[128 * 16];
    __shared__ float xrow[(FUSE != 0) ? BM * 128 : 1];
    int tid = threadIdx.x;
    int m0 = blockIdx.y * BM, n0 = blockIdx.x * 128;
    int lane = tid & 63, wv = tid >> 6;
    int wr = (wv >> 1) * (BM / 2), wc = (wv & 1) * 64;
    int r = lane & 15, q = lane >> 4;

    f32x4 acc[WM][4];
#pragma unroll
    for (int i = 0; i < WM; ++i)
#pragma unroll
        for (int j = 0; j < 4; ++j)
#pragma unroll
            for (int e = 0; e < 4; ++e) acc[i][j][e] = 0.f;

    for (int kc = 0; kc < K; kc += 128) {
        if (kc) __syncthreads();
        // stage A (fp32 -> bf16), unrolled
#pragma unroll
        for (int it = 0; it < BM * 16 / 256; ++it) {
            int idx = tid + it * 256;
            int m = idx >> 4, c = idx & 15;
            int mg = min(m0 + m, M - 1);
            const float* p = A + (size_t)mg * K + kc + c * 8;
            float4 a = *(const float4*)p;
            float4 b = *(const float4*)(p + 4);
            bf16x8 u;
            u[0] = (short)f2bf(a.x); u[1] = (short)f2bf(a.y);
            u[2] = (short)f2bf(a.z); u[3] = (short)f2bf(a.w);
            u[4] = (short)f2bf(b.x); u[5] = (short)f2bf(b.y);
            u[6] = (short)f2bf(b.z); u[7] = (short)f2bf(b.w);
            As[m * 16 + (c ^ (m & 15))] = u;
        }
        // stage B (bf16 rows, k-contiguous), unrolled
#pragma unroll
        for (int it = 0; it < 8; ++it) {
            int idx = tid + it * 256;
            int n = idx >> 4, c = idx & 15;
            bf16x8 w = *(const bf16x8*)(WT + (size_t)(n0 + n) * K + kc + c * 8);
            Bs[n * 16 + (c ^ (n & 15))] = w;
        }
        __syncthreads();
#pragma unroll
        for (int ks = 0; ks < 4; ++ks) {
            bf16x8 bfr[4];
#pragma unroll
            for (int j = 0; j < 4; ++j)
                bfr[j] = Bs[(wc + j * 16 + r) * 16 + ((ks * 4 + q) ^ r)];
#pragma unroll
            for (int i = 0; i < WM; ++i) {
                bf16x8 af = As[(wr + i * 16 + r) * 16 + ((ks * 4 + q) ^ r)];
#pragma unroll
                for (int j = 0; j < 4; ++j)
                    acc[i][j] = __builtin_amdgcn_mfma_f32_16x16x32_bf16(af, bfr[j], acc[i][j], 0, 0, 0);
            }
        }
    }

    if (FUSE == 0) {
#pragma unroll
        for (int i = 0; i < WM; ++i)
#pragma unroll
            for (int e = 0; e < 4; ++e) {
                int m = m0 + wr + i * 16 + q * 4 + e;
                if (m < M) {
#pragma unroll
                    for (int j = 0; j < 4; ++j) {
                        int col = n0 + wc + j * 16 + r;
                        float v = acc[i][j][e] + bias[col];
                        if (act) v = gelu_tanh(v);
                        if (resid) v += resid[(size_t)m * N + col];
                        out[(size_t)m * N + col] = v;
                    }
                }
            }
    } else {
        // row-local epilogue via LDS (M assumed multiple of BM)
#pragma unroll
        for (int i = 0; i < WM; ++i)
#pragma unroll
            for (int e = 0; e < 4; ++e) {
                int ml = wr + i * 16 + q * 4 + e;
#pragma unroll
                for (int j = 0; j < 4; ++j) {
                    int cl = wc + j * 16 + r;
                    float v = acc[i][j][e] + bias[n0 + cl];
                    if (FUSE == 1) v += resid[(size_t)(m0 + ml) * N + n0 + cl];
                    xrow[ml * 128 + cl] = v;
                }
            }
        __syncthreads();
        constexpr int TPR = 256 / BM;      // threads per row
        int row = tid / TPR, s = tid % TPR;
        float* xr = xrow + row * 128;
        float* orow = out + (size_t)(m0 + row) * N + n0;
        if (FUSE == 1) {
            float sum = 0.f;
#pragma unroll
            for (int e = s; e < 128; e += TPR) sum += xr[e];
#pragma unroll
            for (int d = TPR >> 1; d; d >>= 1) sum += __shfl_xor(sum, d, TPR);
            float mean = sum * (1.0f / 128.0f);
            float var = 0.f;
#pragma unroll
            for (int e = s; e < 128; e += TPR) { float dd = xr[e] - mean; var += dd * dd; }
#pragma unroll
            for (int d = TPR >> 1; d; d >>= 1) var += __shfl_xor(var, d, TPR);
            float rstd = rsqrtf(var * (1.0f / 128.0f) + 1e-5f);
#pragma unroll
            for (int e = s; e < 128; e += TPR)
                orow[e] = (xr[e] - mean) * rstd * lng[e] + lnb[e];
        } else {  // FUSE == 2: softmax over the 128-col tile
            float mx = -1e30f;
#pragma unroll
            for (int e = s; e < 128; e += TPR) mx = fmaxf(mx, xr[e]);
#pragma unroll
            for (int d = TPR >> 1; d; d >>= 1) mx = fmaxf(mx, __shfl_xor(mx, d, TPR));
            float sum = 0.f;
#pragma unroll
            for (int e = s; e < 128; e += TPR) { float ee = expf(xr[e] - mx); xr[e] = ee; sum += ee; }
#pragma unroll
            for (int d = TPR >> 1; d; d >>= 1) sum += __shfl_xor(sum, d, TPR);
            float inv = 1.0f / sum;
#pragma unroll
            for (int e = s; e < 128; e += TPR) orow[e] = xr[e] * inv;
        }
    }
}

// ---------------- conv as 27 per-tap MFMA GEMMs with atomic accumulate ----------------
// grid: (8 m-tiles, 27 taps). WT = pre-transposed bf16 [tap][cout][cin].
__global__ __launch_bounds__(256) void k_conv1m(
    const float* __restrict__ grid, const float* __restrict__ cnt,
    const int* __restrict__ flatidx, const unsigned short* __restrict__ WT,
    float* __restrict__ accum) {
    __shared__ bf16x8 As[128 * 16];
    __shared__ bf16x8 Bs[128 * 16];
    __shared__ int   nbase[128];
    __shared__ float nscale[128];
    int tid = threadIdx.x;
    int tap = blockIdx.y;
    int q0 = blockIdx.x * 128;
    int dz = tap / 9 - 1, dy = (tap / 3) % 3 - 1, dx = tap % 3 - 1;

    if (tid < 128) {
        int f = flatidx[q0 + tid];
        int nx = (f >> 10) + dz, ny = ((f >> 5) & 31) + dy, nz = (f & 31) + dx;
        bool ok = (nx >= 0 && nx < GG && ny >= 0 && ny < GG && nz >= 0 && nz < GG);
        int nf = ok ? (nx * GG + ny) * GG + nz : 0;
        nbase[tid] = nf;
        nscale[tid] = ok ? 1.0f / fmaxf(cnt[nf], 1.0f) : 0.f;
    }
    __syncthreads();
#pragma unroll
    for (int it = 0; it < 8; ++it) {
        int idx = tid + it * 256;
        int m = idx >> 4, c = idx & 15;
        const float* p = grid + (size_t)nbase[m] * CC + c * 8;
        float s = nscale[m];
        float4 a = *(const float4*)p;
        float4 b = *(const float4*)(p + 4);
        bf16x8 u;
        u[0] = (short)f2bf(a.x * s); u[1] = (short)f2bf(a.y * s);
        u[2] = (short)f2bf(a.z * s); u[3] = (short)f2bf(a.w * s);
        u[4] = (short)f2bf(b.x * s); u[5] = (short)f2bf(b.y * s);
        u[6] = (short)f2bf(b.z * s); u[7] = (short)f2bf(b.w * s);
        As[m * 16 + (c ^ (m & 15))] = u;
    }
    const unsigned short* Wt = WT + (size_t)tap * CC * CC;
#pragma unroll
    for (int it = 0; it < 8; ++it) {
        int idx = tid + it * 256;
        int n = idx >> 4, c = idx & 15;
        bf16x8 w = *(const bf16x8*)(Wt + (size_t)n * CC + c * 8);
        Bs[n * 16 + (c ^ (n & 15))] = w;
    }
    __syncthreads();

    int lane = tid & 63, wv = tid >> 6;
    int wr = (wv >> 1) * 64, wc = (wv & 1) * 64;
    int r = lane & 15, q = lane >> 4;
    f32x4 acc[4][4];
#pragma unroll
    for (int i = 0; i < 4; ++i)
#pragma unroll
        for (int j = 0; j < 4; ++j)
#pragma unroll
            for (int e = 0; e < 4; ++e) acc[i][j][e] = 0.f;
#pragma unroll
    for (int ks = 0; ks < 4; ++ks) {
        bf16x8 bfr[4];
#pragma unroll
        for (int j = 0; j < 4; ++j)
            bfr[j] = Bs[(wc + j * 16 + r) * 16 + ((ks * 4 + q) ^ r)];
#pragma unroll
        for (int i = 0; i < 4; ++i) {
            bf16x8 af = As[(wr + i * 16 + r) * 16 + ((ks * 4 + q) ^ r)];
#pragma unroll
            for (int j = 0; j < 4; ++j)
                acc[i][j] = __builtin_amdgcn_mfma_f32_16x16x32_bf16(af, bfr[j], acc[i][j], 0, 0, 0);
        }
    }
#pragma unroll
    for (int i = 0; i < 4; ++i)
#pragma unroll
        for (int e = 0; e < 4; ++e) {
            int m = q0 + wr + i * 16 + q * 4 + e;
#pragma unroll
            for (int j = 0; j < 4; ++j) {
                int col = wc + j * 16 + r;
                atomicAdd(&accum[(size_t)m * CC + col], acc[i][j][e]);
            }
        }
}

// q1 = LN(query + gelu(accum + bias)) * g + be
__global__ void k_ln_conv(const float* __restrict__ a, const float* __restrict__ accum,
                          const float* __restrict__ bconv,
                          const float* __restrict__ g, const float* __restrict__ be,
                          float* __restrict__ out) {
    int n = blockIdx.x, c = threadIdx.x;
    float x = a[n * CC + c] + gelu_tanh(accum[n * CC + c] + bconv[c]);
    __shared__ float red[CC];
    red[c] = x;
    __syncthreads();
    for (int s = 64; s >= 1; s >>= 1) { if (c < s) red[c] += red[c + s]; __syncthreads(); }
    float m = red[0] * (1.0f / CC);
    __syncthreads();
    float d = x - m;
    red[c] = d * d;
    __syncthreads();
    for (int s = 64; s >= 1; s >>= 1) { if (c < s) red[c] += red[c + s]; __syncthreads(); }
    float v = red[0] * (1.0f / CC);
    out[n * CC + c] = d * rsqrtf(v + 1e-5f) * g[c] + be[c];
}

// ---------------- fp32 GEMM for small N (12, 28) ----------------
__global__ void k_gemm(const float* __restrict__ A, const float* __restrict__ W,
                       const float* __restrict__ bias, const float* __restrict__ resid,
                       float* __restrict__ out, int M, int K, int N, int act) {
    __shared__ float As[32][128];
    __shared__ float Ws[128][64];
    int tid = threadIdx.x;
    int tx = tid & 63, ty = tid >> 6;
    int m0 = blockIdx.y * 32, n0 = blockIdx.x * 64;
    int n = n0 + tx;
    float acc[8];
#pragma unroll
    for (int i = 0; i < 8; ++i) acc[i] = 0.f;

    for (int k0 = 0; k0 < K; k0 += 128) {
        __syncthreads();
#pragma unroll
        for (int it = 0; it < 16; ++it) {
            int idx = tid + it * 256;
            int m = idx >> 7, c = idx & 127;
            As[m][c] = (m0 + m < M) ? A[(size_t)(m0 + m) * K + k0 + c] : 0.f;
        }
#pragma unroll
        for (int it = 0; it < 32; ++it) {
            int idx = tid + it * 256;
            int c = idx >> 6, j = idx & 63;
            Ws[c][j] = (n0 + j < N) ? W[(size_t)(k0 + c) * N + n0 + j] : 0.f;
        }
        __syncthreads();
#pragma unroll 4
        for (int c4 = 0; c4 < 32; ++c4) {
            float w0 = Ws[4 * c4 + 0][tx];
            float w1 = Ws[4 * c4 + 1][tx];
            float w2 = Ws[4 * c4 + 2][tx];
            float w3 = Ws[4 * c4 + 3][tx];
#pragma unroll
            for (int i = 0; i < 8; ++i) {
                float4 av = *(const float4*)&As[ty * 8 + i][c4 * 4];
                acc[i] += av.x * w0 + av.y * w1 + av.z * w2 + av.w * w3;
            }
        }
    }
    if (n < N) {
        float bv = bias[n];
#pragma unroll
        for (int i = 0; i < 8; ++i) {
            int m = m0 + ty * 8 + i;
            if (m < M) {
                float v = acc[i] + bv;
                if (act == 1) v = gelu_tanh(v);
                if (resid) v += resid[(size_t)m * N + n];
                out[(size_t)m * N + n] = v;
            }
        }
    }
}

// ---------------- projection + depth weighting ----------------
__global__ void k_proj(const float* __restrict__ gp, const float* __restrict__ refoff,
                       const float* __restrict__ l2i, const float* __restrict__ depth,
                       const int* __restrict__ ih, const int* __restrict__ iw,
                       float* __restrict__ wm, float* __restrict__ r2u, float* __restrict__ r2v) {
    int idx = blockIdx.x * blockDim.x + threadIdx.x;  // cam*1024 + n
    if (idx >= CAM * NQ) return;
    int cam = idx >> 10, n = idx & 1023;
    float fH = (float)(*ih), fW = (float)(*iw);
    const float* M = l2i + cam * 16;
    float mx = gp[n * PROPN], my = gp[n * PROPN + 1], mz = gp[n * PROPN + 2];
#pragma unroll
    for (int r = 0; r < RR; ++r) {
        float px = mx + refoff[n * 12 + r * 3 + 0];
        float py = my + refoff[n * 12 + r * 3 + 1];
        float pz = mz + refoff[n * 12 + r * 3 + 2];
        float p0 = M[0] * px + M[1] * py + M[2]  * pz + M[3];
        float p1 = M[4] * px + M[5] * py + M[6]  * pz + M[7];
        float p2 = M[8] * px + M[9] * py + M[10] * pz + M[11];
        float zc = fmaxf(p2, 1e-5f);
        float u = p0 / zc, v = p1 / zc;
        bool valid = (p2 > 1e-5f) && (u >= 0.f) && (u < fW) && (v >= 0.f) && (v < fH);
        int iu = min(max((int)(u / fW * 176.f), 0), 175);
        int iv = min(max((int)(v / fH * 64.f), 0), 63);
        float ds = depth[cam * 64 * 176 + iv * 176 + iu];
        int o = cam * (NQ * RR) + n * RR + r;
        wm[o]  = valid ? expf(-fabsf(p2 - ds)) : 0.f;
        r2u[o] = u / fW;
        r2v[o] = v / fH;
    }
}

// ---------------- deformable sampling + weighted reduce ----------------
__global__ void k_sample(const float* __restrict__ value, const float* __restrict__ offsb,
                         const float* __restrict__ attn, const float* __restrict__ wm,
                         const float* __restrict__ r2u, const float* __restrict__ r2v,
                         float* __restrict__ sampout) {
    const int Wl_[4] = {176, 88, 44, 22};
    const int Hl_[4] = {64, 32, 16, 8};
    const int s0_[4] = {0, 11264, 14080, 14784};
    int n = blockIdx.x, tid = threadIdx.x;
    __shared__ float s_attn[1024];
    __shared__ float s_offs[2048];
    __shared__ float s_wm[24], s_ru[24], s_rv[24];
    __shared__ float red[8 * 32 * 16];

    for (int i = tid; i < 1024; i += 256) s_attn[i] = attn[(size_t)n * 1024 + i];
    for (int i = tid; i < 2048; i += 256) s_offs[i] = offsb[(size_t)n * 2048 + i];
    if (tid < 24) {
        int cam = tid >> 2, r = tid & 3;
        int o = cam * (NQ * RR) + n * RR + r;
        s_wm[tid] = wm[o]; s_ru[tid] = r2u[o]; s_rv[tid] = r2v[o];
    }
    __syncthreads();

    int h = tid >> 5, slot = tid & 31;
    int l = slot >> 3, p = slot & 7;
    int Wl = Wl_[l], Hl = Hl_[l];
    float fWl = (float)Wl, fHl = (float)Hl;
    float acc[16];
#pragma unroll
    for (int d = 0; d < 16; ++d) acc[d] = 0.f;

    for (int cr = 0; cr < 24; ++cr) {
        int cam = cr >> 2, r = cr & 3;
        float ws = s_attn[h * 128 + r * 32 + l * 8 + p] * s_wm[cr];
        if (ws == 0.f) continue;
        float ox = s_offs[h * 256 + r * 64 + l * 16 + p * 2 + 0];
        float oy = s_offs[h * 256 + r * 64 + l * 16 + p * 2 + 1];
        float x = s_ru[cr] * fWl + ox - 0.5f;
        float y = s_rv[cr] * fHl + oy - 0.5f;
        float xf = floorf(x), yf = floorf(y);
        float wx = x - xf, wy = y - yf;
        int x0 = min(max((int)xf, 0), Wl - 1);
        int x1 = min(max((int)xf + 1, 0), Wl - 1);
        int y0 = min(max((int)yf, 0), Hl - 1);
        int y1 = min(max((int)yf + 1, 0), Hl - 1);
        size_t b = ((size_t)cam * S_TOT + s0_[l]) * CC + h * HDD;
        const float* p00 = value + b + (size_t)(y0 * Wl + x0) * CC;
        const float* p01 = value + b + (size_t)(y0 * Wl + x1) * CC;
        const float* p10 = value + b + (size_t)(y1 * Wl + x0) * CC;
        const float* p11 = value + b + (size_t)(y1 * Wl + x1) * CC;
        float w00 = ws * (1.f - wx) * (1.f - wy);
        float w01 = ws * wx * (1.f - wy);
        float w10 = ws * (1.f - wx) * wy;
        float w11 = ws * wx * wy;
#pragma unroll
        for (int d = 0; d < 16; ++d)
            acc[d] += w00 * p00[d] + w01 * p01[d] + w10 * p10[d] + w11 * p11[d];
    }

    int base = (h * 32 + slot) * 16;
#pragma unroll
    for (int d = 0; d < 16; ++d) red[base + d] = acc[d];
    __syncthreads();
    for (int s = 16; s >= 1; s >>= 1) {
        if (slot < s) {
#pragma unroll
            for (int d = 0; d < 16; ++d) red[base + d] += red[base + s * 16 + d];
        }
        __syncthreads();
    }
    if (tid < 128) {
        int hh = tid >> 4, dd = tid & 15;
        sampout[(size_t)n * CC + tid] = red[hh * 512 + dd];
    }
}

// ---------------- launch ----------------
extern "C" void kernel_launch(void* const* d_in, const int* in_sizes, int n_in,
                              void* d_out, int out_size, void* d_ws, size_t ws_size,
                              hipStream_t stream) {
    const float* query = (const float*)d_in[0];
    const float* gp    = (const float*)d_in[1];
    const float* ms    = (const float*)d_in[2];
    const float* depth = (const float*)d_in[3];
    const float* l2i   = (const float*)d_in[4];
    const int*   ih    = (const int*)d_in[5];
    const int*   iw    = (const int*)d_in[6];
    const float* Wsc   = (const float*)d_in[7];
    const float* bsc   = (const float*)d_in[8];
    const float* scg   = (const float*)d_in[9];
    const float* scb   = (const float*)d_in[10];
    const float* refw  = (const float*)d_in[11];
    const float* refb  = (const float*)d_in[12];
    const float* offw  = (const float*)d_in[13];
    const float* offbi = (const float*)d_in[14];
    const float* aww   = (const float*)d_in[15];
    const float* awb   = (const float*)d_in[16];
    const float* valw  = (const float*)d_in[17];
    const float* valb  = (const float*)d_in[18];
    const float* outw  = (const float*)d_in[19];
    const float* outb  = (const float*)d_in[20];
    const float* ang   = (const float*)d_in[21];
    const float* anb   = (const float*)d_in[22];
    const float* f1w   = (const float*)d_in[23];
    const float* f1b   = (const float*)d_in[24];
    const float* f2w   = (const float*)d_in[25];
    const float* f2b   = (const float*)d_in[26];
    const float* fng   = (const float*)d_in[27];
    const float* fnb   = (const float*)d_in[28];
    const float* p1w   = (const float*)d_in[29];
    const float* p1b   = (const float*)d_in[30];
    const float* p2w   = (const float*)d_in[31];
    const float* p2b   = (const float*)d_in[32];

    float* outq = (float*)d_out;            // 1024*128
    float* outp = outq + NQ * CC;           // 1024*28

    // workspace carve (floats). grid and value share the big buffer
    // (disjoint lifetimes: conv reads grid before value GEMM overwrites).
    float* ws = (float*)d_ws;
    size_t o = 0;
    float* bigbuf  = ws + o; o += (size_t)CAM * S_TOT * CC;  // 11,489,280 floats
    float* grid    = bigbuf;
    float* value   = bigbuf;
    float* cnt     = ws + o; o += GG * GG * GG;
    int*   flatidx = (int*)(ws + o); o += NQ;
    float* convacc = ws + o; o += NQ * CC;
    float* q1      = ws + o; o += NQ * CC;
    float* refoff  = ws + o; o += NQ * 12;
    float* offsb   = ws + o; o += (size_t)NQ * 2048;
    float* attn    = ws + o; o += (size_t)NQ * 1024;
    float* wm      = ws + o; o += CAM * NQ * RR;
    float* r2u     = ws + o; o += CAM * NQ * RR;
    float* r2v     = ws + o; o += CAM * NQ * RR;
    float* sampout = ws + o; o += NQ * CC;
    float* q2      = ws + o; o += NQ * CC;
    float* ffn1    = ws + o; o += NQ * 512;
    float* p1out   = ws + o; o += NQ * CC;
    // bf16 transposed weights (u16)
    unsigned short* u16base = (unsigned short*)(ws + o);
    size_t uo = 0;
    unsigned short* offwT = u16base + uo; uo += (size_t)2048 * 128;
    unsigned short* awwT  = u16base + uo; uo += (size_t)1024 * 128;
    unsigned short* valwT = u16base + uo; uo += 128 * 128;
    unsigned short* outwT = u16base + uo; uo += 128 * 128;
    unsigned short* f1wT  = u16base + uo; uo += 512 * 128;
    unsigned short* f2wT  = u16base + uo; uo += 128 * 512;
    unsigned short* p1wT  = u16base + uo; uo += 128 * 128;
    unsigned short* WscT  = u16base + uo; uo += (size_t)27 * 128 * 128;
    (void)ws_size; (void)in_sizes; (void)n_in; (void)out_size;

    // weight conversions (independent of everything)
    k_wt128<<<dim3(2, 2, 30), 256, 0, stream>>>(Wsc, WscT, valw, valwT, outw, outwT, p1w, p1wT);
    k_wt<<<dim3(32, 2, 1), 256, 0, stream>>>(offw, offwT, 128, 2048);
    k_wt<<<dim3(16, 2, 1), 256, 0, stream>>>(aww, awwT, 128, 1024);
    k_wt<<<dim3(8, 2, 1), 256, 0, stream>>>(f1w, f1wT, 128, 512);
    k_wt<<<dim3(2, 8, 1), 256, 0, stream>>>(f2w, f2wT, 512, 128);

    hipMemsetAsync(grid, 0, (size_t)GG * GG * GG * CC * sizeof(float), stream);
    hipMemsetAsync(cnt, 0, (size_t)GG * GG * GG * sizeof(float), stream);
    hipMemsetAsync(convacc, 0, (size_t)NQ * CC * sizeof(float), stream);

    k_scatter<<<NQ, CC, 0, stream>>>(query, gp, grid, cnt, flatidx);
    k_conv1m<<<dim3(8, 27), 256, 0, stream>>>(grid, cnt, flatidx, WscT, convacc);
    k_ln_conv<<<NQ, CC, 0, stream>>>(query, convacc, bsc, scg, scb, q1);

    k_gemm<<<dim3(1, 32), 256, 0, stream>>>(q1, refw, refb, nullptr, refoff, NQ, 128, 12, 0);
    k_mfma_bt<128, 0><<<dim3(16, 8), 256, 0, stream>>>(q1, offwT, offbi, nullptr, nullptr, nullptr,
                                                       offsb, NQ, 128, 2048, 0);
    k_mfma_bt<128, 2><<<dim3(8, 8), 256, 0, stream>>>(q1, awwT, awb, nullptr, nullptr, nullptr,
                                                      attn, NQ, 128, 1024, 0);
    k_proj<<<24, 256, 0, stream>>>(gp, refoff, l2i, depth, ih, iw, wm, r2u, r2v);

    // value projection (after conv: overwrites grid region)
    k_mfma_bt<128, 0><<<dim3(1, 702), 256, 0, stream>>>(ms, valwT, valb, nullptr, nullptr, nullptr,
                                                        value, CAM * S_TOT, 128, 128, 0);
    k_sample<<<NQ, 256, 0, stream>>>(value, offsb, attn, wm, r2u, r2v, sampout);

    // attn out-proj + residual + LN  -> q2
    k_mfma_bt<32, 1><<<dim3(1, 32), 256, 0, stream>>>(sampout, outwT, outb, q1, ang, anb,
                                                      q2, NQ, 128, 128, 0);
    // FFN
    k_mfma_bt<32, 0><<<dim3(4, 32), 256, 0, stream>>>(q2, f1wT, f1b, nullptr, nullptr, nullptr,
                                                      ffn1, NQ, 128, 512, 1);
    k_mfma_bt<32, 1><<<dim3(1, 32), 256, 0, stream>>>(ffn1, f2wT, f2b, q2, fng, fnb,
                                                      outq, NQ, 512, 128, 0);
    // props head
    k_mfma_bt<32, 0><<<dim3(1, 32), 256, 0, stream>>>(outq, p1wT, p1b, nullptr, nullptr, nullptr,
                                                      p1out, NQ, 128, 128, 1);
    k_gemm<<<dim3(1, 32), 256, 0, stream>>>(p1out, p2w, p2b, gp, outp, NQ, 128, PROPN, 0);
}

// Round 5
// 326.183 us; speedup vs baseline: 2.5932x; 1.1164x over previous
//
#include <hip/hip_runtime.h>
#include <hip/hip_bf16.h>
#include <math.h>

// ---------------- constants ----------------
#define NQ    1024
#define CC    128
#define CAM   6
#define RR    4
#define LL    4
#define PP    8
#define HHD   8     // heads
#define HDD   16    // head dim
#define GG    32
#define S_TOT 14960
#define PROPN 28

typedef __attribute__((ext_vector_type(8))) short bf16x8;
typedef __attribute__((ext_vector_type(4))) float f32x4;

__device__ __forceinline__ float gelu_tanh(float x) {
    return 0.5f * x * (1.0f + tanhf(0.7978845608028654f * (x + 0.044715f * x * x * x)));
}

__device__ __forceinline__ unsigned short f2bf(float f) {
    union { float f; unsigned int u; } x; x.f = f;
    unsigned int r = (x.u + 0x7FFFu + ((x.u >> 16) & 1u)) >> 16;
    return (unsigned short)r;
}

__device__ __forceinline__ float bf2f(short s) {
    union { unsigned int u; float f; } x;
    x.u = ((unsigned int)(unsigned short)s) << 16;
    return x.f;
}

// ---------------- fused weight transpose+convert (all weights, one dispatch) ----------
// Each z handles one 128x128 submatrix: WT[n][k] = bf16(W[k][n]).
// grid (2,2,62), 256 threads.
__global__ void k_wt_all(const float* __restrict__ Wsc, unsigned short* __restrict__ WscT,
                         const float* __restrict__ valw, unsigned short* __restrict__ valwT,
                         const float* __restrict__ outw, unsigned short* __restrict__ outwT,
                         const float* __restrict__ p1w, unsigned short* __restrict__ p1wT,
                         const float* __restrict__ f1w, unsigned short* __restrict__ f1wT,
                         const float* __restrict__ f2w, unsigned short* __restrict__ f2wT,
                         const float* __restrict__ offw, unsigned short* __restrict__ offwT,
                         const float* __restrict__ aww, unsigned short* __restrict__ awwT) {
    int z = blockIdx.z;
    const float* src; unsigned short* dst; int ss, ds;
    if (z < 27)       { src = Wsc + (size_t)z * 16384; dst = WscT + (size_t)z * 16384; ss = 128; ds = 128; }
    else if (z == 27) { src = valw; dst = valwT; ss = 128; ds = 128; }
    else if (z == 28) { src = outw; dst = outwT; ss = 128; ds = 128; }
    else if (z == 29) { src = p1w;  dst = p1wT;  ss = 128; ds = 128; }
    else if (z < 34)  { int t = z - 30; src = f1w + t * 128; dst = f1wT + (size_t)t * 16384; ss = 512;  ds = 128; }
    else if (z < 38)  { int t = z - 34; src = f2w + (size_t)t * 16384; dst = f2wT + t * 128; ss = 128;  ds = 512; }
    else if (z < 54)  { int t = z - 38; src = offw + t * 128; dst = offwT + (size_t)t * 16384; ss = 2048; ds = 128; }
    else              { int t = z - 54; src = aww + t * 128;  dst = awwT + (size_t)t * 16384; ss = 1024; ds = 128; }
    __shared__ float t[64][65];
    int n0 = blockIdx.x * 64, k0 = blockIdx.y * 64, tid = threadIdx.x;
#pragma unroll
    for (int it = 0; it < 16; ++it) {
        int idx = tid + it * 256;
        int r = idx >> 6, c = idx & 63;
        t[r][c] = src[(size_t)(k0 + r) * ss + n0 + c];
    }
    __syncthreads();
#pragma unroll
    for (int it = 0; it < 16; ++it) {
        int idx = tid + it * 256;
        int r = idx >> 6, c = idx & 63;
        dst[(size_t)(n0 + r) * ds + k0 + c] = f2bf(t[c][r]);
    }
}

// ---------------- scatter-add into voxel grid ----------------
__global__ void k_scatter(const float* __restrict__ q, const float* __restrict__ gp,
                          float* __restrict__ grid, float* __restrict__ cnt,
                          int* __restrict__ flatidx) {
    int n = blockIdx.x;
    int c = threadIdx.x;
    __shared__ int sflat;
    if (c == 0) {
        float mx = gp[n * PROPN + 0], my = gp[n * PROPN + 1], mz = gp[n * PROPN + 2];
        int vx = (int)floorf((mx + 4.0f) * 4.0f);
        int vy = (int)floorf((my + 4.0f) * 4.0f);
        int vz = (int)floorf((mz + 4.0f) * 4.0f);
        vx = min(max(vx, 0), GG - 1);
        vy = min(max(vy, 0), GG - 1);
        vz = min(max(vz, 0), GG - 1);
        int f = (vx * GG + vy) * GG + vz;
        sflat = f;
        flatidx[n] = f;
        atomicAdd(&cnt[f], 1.0f);
    }
    __syncthreads();
    atomicAdd(&grid[sflat * CC + c], q[n * CC + c]);
}

// ---------------- generic MFMA bf16 GEMM with bf16 pre-transposed weights ----------------
// out[M,N] = epilogue(A[M,K] @ WT[N,K]^T). BN = 128. FUSE: 0 plain(+act/+resid),
// 1 = +bias +resid +LayerNorm (N must be 128), 2 = +bias +softmax over the 128-col tile.
template<int BM, int FUSE>
__global__ __launch_bounds__(256) void k_mfma_bt(
    const float* __restrict__ A, const unsigned short* __restrict__ WT,
    const float* __restrict__ bias, const float* __restrict__ resid,
    const float* __restrict__ lng, const float* __restrict__ lnb,
    float* __restrict__ out, int M, int K, int N, int act)
{
    constexpr int WM = BM / 32;            // 16-row tiles per wave
    __shared__ bf16x8 As[BM * 16];
    __shared__ bf16x8 Bs[128 * 16];
    __shared__ float xrow[(FUSE != 0) ? BM * 128 : 1];
    int tid = threadIdx.x;
    int m0 = blockIdx.y * BM, n0 = blockIdx.x * 128;
    int lane = tid & 63, wv = tid >> 6;
    int wr = (wv >> 1) * (BM / 2), wc = (wv & 1) * 64;
    int r = lane & 15, q = lane >> 4;

    f32x4 acc[WM][4];
#pragma unroll
    for (int i = 0; i < WM; ++i)
#pragma unroll
        for (int j = 0; j < 4; ++j)
#pragma unroll
            for (int e = 0; e < 4; ++e) acc[i][j][e] = 0.f;

    for (int kc = 0; kc < K; kc += 128) {
        if (kc) __syncthreads();
        // stage A (fp32 -> bf16), unrolled
#pragma unroll
        for (int it = 0; it < BM * 16 / 256; ++it) {
            int idx = tid + it * 256;
            int m = idx >> 4, c = idx & 15;
            int mg = min(m0 + m, M - 1);
            const float* p = A + (size_t)mg * K + kc + c * 8;
            float4 a = *(const float4*)p;
            float4 b = *(const float4*)(p + 4);
            bf16x8 u;
            u[0] = (short)f2bf(a.x); u[1] = (short)f2bf(a.y);
            u[2] = (short)f2bf(a.z); u[3] = (short)f2bf(a.w);
            u[4] = (short)f2bf(b.x); u[5] = (short)f2bf(b.y);
            u[6] = (short)f2bf(b.z); u[7] = (short)f2bf(b.w);
            As[m * 16 + (c ^ (m & 15))] = u;
        }
        // stage B (bf16 rows, k-contiguous), unrolled
#pragma unroll
        for (int it = 0; it < 8; ++it) {
            int idx = tid + it * 256;
            int n = idx >> 4, c = idx & 15;
            bf16x8 w = *(const bf16x8*)(WT + (size_t)(n0 + n) * K + kc + c * 8);
            Bs[n * 16 + (c ^ (n & 15))] = w;
        }
        __syncthreads();
#pragma unroll
        for (int ks = 0; ks < 4; ++ks) {
            bf16x8 bfr[4];
#pragma unroll
            for (int j = 0; j < 4; ++j)
                bfr[j] = Bs[(wc + j * 16 + r) * 16 + ((ks * 4 + q) ^ r)];
#pragma unroll
            for (int i = 0; i < WM; ++i) {
                bf16x8 af = As[(wr + i * 16 + r) * 16 + ((ks * 4 + q) ^ r)];
#pragma unroll
                for (int j = 0; j < 4; ++j)
                    acc[i][j] = __builtin_amdgcn_mfma_f32_16x16x32_bf16(af, bfr[j], acc[i][j], 0, 0, 0);
            }
        }
    }

    if (FUSE == 0) {
#pragma unroll
        for (int i = 0; i < WM; ++i)
#pragma unroll
            for (int e = 0; e < 4; ++e) {
                int m = m0 + wr + i * 16 + q * 4 + e;
                if (m < M) {
#pragma unroll
                    for (int j = 0; j < 4; ++j) {
                        int col = n0 + wc + j * 16 + r;
                        float v = acc[i][j][e] + bias[col];
                        if (act) v = gelu_tanh(v);
                        if (resid) v += resid[(size_t)m * N + col];
                        out[(size_t)m * N + col] = v;
                    }
                }
            }
    } else {
        // row-local epilogue via LDS (M assumed multiple of BM)
#pragma unroll
        for (int i = 0; i < WM; ++i)
#pragma unroll
            for (int e = 0; e < 4; ++e) {
                int ml = wr + i * 16 + q * 4 + e;
#pragma unroll
                for (int j = 0; j < 4; ++j) {
                    int cl = wc + j * 16 + r;
                    float v = acc[i][j][e] + bias[n0 + cl];
                    if (FUSE == 1) v += resid[(size_t)(m0 + ml) * N + n0 + cl];
                    xrow[ml * 128 + cl] = v;
                }
            }
        __syncthreads();
        constexpr int TPR = 256 / BM;      // threads per row
        int row = tid / TPR, s = tid % TPR;
        float* xr = xrow + row * 128;
        float* orow = out + (size_t)(m0 + row) * N + n0;
        if (FUSE == 1) {
            float sum = 0.f;
#pragma unroll
            for (int e = s; e < 128; e += TPR) sum += xr[e];
#pragma unroll
            for (int d = TPR >> 1; d; d >>= 1) sum += __shfl_xor(sum, d, TPR);
            float mean = sum * (1.0f / 128.0f);
            float var = 0.f;
#pragma unroll
            for (int e = s; e < 128; e += TPR) { float dd = xr[e] - mean; var += dd * dd; }
#pragma unroll
            for (int d = TPR >> 1; d; d >>= 1) var += __shfl_xor(var, d, TPR);
            float rstd = rsqrtf(var * (1.0f / 128.0f) + 1e-5f);
#pragma unroll
            for (int e = s; e < 128; e += TPR)
                orow[e] = (xr[e] - mean) * rstd * lng[e] + lnb[e];
        } else {  // FUSE == 2: softmax over the 128-col tile
            float mx = -1e30f;
#pragma unroll
            for (int e = s; e < 128; e += TPR) mx = fmaxf(mx, xr[e]);
#pragma unroll
            for (int d = TPR >> 1; d; d >>= 1) mx = fmaxf(mx, __shfl_xor(mx, d, TPR));
            float sum = 0.f;
#pragma unroll
            for (int e = s; e < 128; e += TPR) { float ee = expf(xr[e] - mx); xr[e] = ee; sum += ee; }
#pragma unroll
            for (int d = TPR >> 1; d; d >>= 1) sum += __shfl_xor(sum, d, TPR);
            float inv = 1.0f / sum;
#pragma unroll
            for (int e = s; e < 128; e += TPR) orow[e] = xr[e] * inv;
        }
    }
}

// ---------------- value projection: A[M,128] @ WT[128,128]^T -> bf16 out ----------------
// B staged once to LDS; A streamed global->registers; out staged via LDS for 16B stores.
// grid: ceil(M/64) blocks, 256 threads (4 waves x 16 rows).
__global__ __launch_bounds__(256) void k_valproj(
    const float* __restrict__ A, const unsigned short* __restrict__ WT,
    const float* __restrict__ bias, unsigned short* __restrict__ out, int M)
{
    __shared__ bf16x8 Bs[128 * 16];          // 32 KB
    __shared__ unsigned short Os[64 * 128];  // 16 KB
    __shared__ float sbias[128];
    int tid = threadIdx.x;
    int m0 = blockIdx.x * 64;
    int lane = tid & 63, wv = tid >> 6;
    int r = lane & 15, q = lane >> 4;

#pragma unroll
    for (int it = 0; it < 8; ++it) {
        int idx = tid + it * 256;
        int n = idx >> 4, c = idx & 15;
        Bs[n * 16 + (c ^ (n & 15))] = *(const bf16x8*)(WT + (size_t)n * 128 + c * 8);
    }
    if (tid < 128) sbias[tid] = bias[tid];
    __syncthreads();

    int row = m0 + wv * 16 + r;
    int mg = min(row, M - 1);
    const float* pA = A + (size_t)mg * 128;

    f32x4 acc[8];
#pragma unroll
    for (int j = 0; j < 8; ++j)
#pragma unroll
        for (int e = 0; e < 4; ++e) acc[j][e] = 0.f;

#pragma unroll
    for (int ks = 0; ks < 4; ++ks) {
        const float* p = pA + ks * 32 + q * 8;
        float4 a = *(const float4*)p;
        float4 b = *(const float4*)(p + 4);
        bf16x8 af;
        af[0] = (short)f2bf(a.x); af[1] = (short)f2bf(a.y);
        af[2] = (short)f2bf(a.z); af[3] = (short)f2bf(a.w);
        af[4] = (short)f2bf(b.x); af[5] = (short)f2bf(b.y);
        af[6] = (short)f2bf(b.z); af[7] = (short)f2bf(b.w);
        bf16x8 bfr[8];
#pragma unroll
        for (int j = 0; j < 8; ++j)
            bfr[j] = Bs[(j * 16 + r) * 16 + ((ks * 4 + q) ^ r)];
#pragma unroll
        for (int j = 0; j < 8; ++j)
            acc[j] = __builtin_amdgcn_mfma_f32_16x16x32_bf16(af, bfr[j], acc[j], 0, 0, 0);
    }

#pragma unroll
    for (int j = 0; j < 8; ++j)
#pragma unroll
        for (int e = 0; e < 4; ++e) {
            int rl = wv * 16 + q * 4 + e;
            Os[rl * 128 + j * 16 + r] = f2bf(acc[j][e] + sbias[j * 16 + r]);
        }
    __syncthreads();
#pragma unroll
    for (int it = 0; it < 4; ++it) {
        int idx = tid + it * 256;
        int rl = idx >> 4, ch = idx & 15;
        int m = m0 + rl;
        if (m < M)
            *(bf16x8*)(out + (size_t)m * 128 + ch * 8) = *(const bf16x8*)&Os[rl * 128 + ch * 8];
    }
}

// ---------------- conv as 27 per-tap MFMA GEMMs with atomic accumulate ----------------
// grid: (8 m-tiles, 27 taps). WT = pre-transposed bf16 [tap][cout][cin].
__global__ __launch_bounds__(256) void k_conv1m(
    const float* __restrict__ grid, const float* __restrict__ cnt,
    const int* __restrict__ flatidx, const unsigned short* __restrict__ WT,
    float* __restrict__ accum) {
    __shared__ bf16x8 As[128 * 16];
    __shared__ bf16x8 Bs[128 * 16];
    __shared__ int   nbase[128];
    __shared__ float nscale[128];
    int tid = threadIdx.x;
    int tap = blockIdx.y;
    int q0 = blockIdx.x * 128;
    int dz = tap / 9 - 1, dy = (tap / 3) % 3 - 1, dx = tap % 3 - 1;

    if (tid < 128) {
        int f = flatidx[q0 + tid];
        int nx = (f >> 10) + dz, ny = ((f >> 5) & 31) + dy, nz = (f & 31) + dx;
        bool ok = (nx >= 0 && nx < GG && ny >= 0 && ny < GG && nz >= 0 && nz < GG);
        int nf = ok ? (nx * GG + ny) * GG + nz : 0;
        nbase[tid] = nf;
        nscale[tid] = ok ? 1.0f / fmaxf(cnt[nf], 1.0f) : 0.f;
    }
    __syncthreads();
#pragma unroll
    for (int it = 0; it < 8; ++it) {
        int idx = tid + it * 256;
        int m = idx >> 4, c = idx & 15;
        const float* p = grid + (size_t)nbase[m] * CC + c * 8;
        float s = nscale[m];
        float4 a = *(const float4*)p;
        float4 b = *(const float4*)(p + 4);
        bf16x8 u;
        u[0] = (short)f2bf(a.x * s); u[1] = (short)f2bf(a.y * s);
        u[2] = (short)f2bf(a.z * s); u[3] = (short)f2bf(a.w * s);
        u[4] = (short)f2bf(b.x * s); u[5] = (short)f2bf(b.y * s);
        u[6] = (short)f2bf(b.z * s); u[7] = (short)f2bf(b.w * s);
        As[m * 16 + (c ^ (m & 15))] = u;
    }
    const unsigned short* Wt = WT + (size_t)tap * CC * CC;
#pragma unroll
    for (int it = 0; it < 8; ++it) {
        int idx = tid + it * 256;
        int n = idx >> 4, c = idx & 15;
        bf16x8 w = *(const bf16x8*)(Wt + (size_t)n * CC + c * 8);
        Bs[n * 16 + (c ^ (n & 15))] = w;
    }
    __syncthreads();

    int lane = tid & 63, wv = tid >> 6;
    int wr = (wv >> 1) * 64, wc = (wv & 1) * 64;
    int r = lane & 15, q = lane >> 4;
    f32x4 acc[4][4];
#pragma unroll
    for (int i = 0; i < 4; ++i)
#pragma unroll
        for (int j = 0; j < 4; ++j)
#pragma unroll
            for (int e = 0; e < 4; ++e) acc[i][j][e] = 0.f;
#pragma unroll
    for (int ks = 0; ks < 4; ++ks) {
        bf16x8 bfr[4];
#pragma unroll
        for (int j = 0; j < 4; ++j)
            bfr[j] = Bs[(wc + j * 16 + r) * 16 + ((ks * 4 + q) ^ r)];
#pragma unroll
        for (int i = 0; i < 4; ++i) {
            bf16x8 af = As[(wr + i * 16 + r) * 16 + ((ks * 4 + q) ^ r)];
#pragma unroll
            for (int j = 0; j < 4; ++j)
                acc[i][j] = __builtin_amdgcn_mfma_f32_16x16x32_bf16(af, bfr[j], acc[i][j], 0, 0, 0);
        }
    }
#pragma unroll
    for (int i = 0; i < 4; ++i)
#pragma unroll
        for (int e = 0; e < 4; ++e) {
            int m = q0 + wr + i * 16 + q * 4 + e;
#pragma unroll
            for (int j = 0; j < 4; ++j) {
                int col = wc + j * 16 + r;
                atomicAdd(&accum[(size_t)m * CC + col], acc[i][j][e]);
            }
        }
}

// q1 = LN(query + gelu(accum + bias)) * g + be
__global__ void k_ln_conv(const float* __restrict__ a, const float* __restrict__ accum,
                          const float* __restrict__ bconv,
                          const float* __restrict__ g, const float* __restrict__ be,
                          float* __restrict__ out) {
    int n = blockIdx.x, c = threadIdx.x;
    float x = a[n * CC + c] + gelu_tanh(accum[n * CC + c] + bconv[c]);
    __shared__ float red[CC];
    red[c] = x;
    __syncthreads();
    for (int s = 64; s >= 1; s >>= 1) { if (c < s) red[c] += red[c + s]; __syncthreads(); }
    float m = red[0] * (1.0f / CC);
    __syncthreads();
    float d = x - m;
    red[c] = d * d;
    __syncthreads();
    for (int s = 64; s >= 1; s >>= 1) { if (c < s) red[c] += red[c + s]; __syncthreads(); }
    float v = red[0] * (1.0f / CC);
    out[n * CC + c] = d * rsqrtf(v + 1e-5f) * g[c] + be[c];
}

// ---------------- fp32 GEMM for small N (12, 28) ----------------
__global__ void k_gemm(const float* __restrict__ A, const float* __restrict__ W,
                       const float* __restrict__ bias, const float* __restrict__ resid,
                       float* __restrict__ out, int M, int K, int N, int act) {
    __shared__ float As[32][128];
    __shared__ float Ws[128][64];
    int tid = threadIdx.x;
    int tx = tid & 63, ty = tid >> 6;
    int m0 = blockIdx.y * 32, n0 = blockIdx.x * 64;
    int n = n0 + tx;
    float acc[8];
#pragma unroll
    for (int i = 0; i < 8; ++i) acc[i] = 0.f;

    for (int k0 = 0; k0 < K; k0 += 128) {
        __syncthreads();
#pragma unroll
        for (int it = 0; it < 16; ++it) {
            int idx = tid + it * 256;
            int m = idx >> 7, c = idx & 127;
            As[m][c] = (m0 + m < M) ? A[(size_t)(m0 + m) * K + k0 + c] : 0.f;
        }
#pragma unroll
        for (int it = 0; it < 32; ++it) {
            int idx = tid + it * 256;
            int c = idx >> 6, j = idx & 63;
            Ws[c][j] = (n0 + j < N) ? W[(size_t)(k0 + c) * N + n0 + j] : 0.f;
        }
        __syncthreads();
#pragma unroll 4
        for (int c4 = 0; c4 < 32; ++c4) {
            float w0 = Ws[4 * c4 + 0][tx];
            float w1 = Ws[4 * c4 + 1][tx];
            float w2 = Ws[4 * c4 + 2][tx];
            float w3 = Ws[4 * c4 + 3][tx];
#pragma unroll
            for (int i = 0; i < 8; ++i) {
                float4 av = *(const float4*)&As[ty * 8 + i][c4 * 4];
                acc[i] += av.x * w0 + av.y * w1 + av.z * w2 + av.w * w3;
            }
        }
    }
    if (n < N) {
        float bv = bias[n];
#pragma unroll
        for (int i = 0; i < 8; ++i) {
            int m = m0 + ty * 8 + i;
            if (m < M) {
                float v = acc[i] + bv;
                if (act == 1) v = gelu_tanh(v);
                if (resid) v += resid[(size_t)m * N + n];
                out[(size_t)m * N + n] = v;
            }
        }
    }
}

// ---------------- projection + depth weighting ----------------
__global__ void k_proj(const float* __restrict__ gp, const float* __restrict__ refoff,
                       const float* __restrict__ l2i, const float* __restrict__ depth,
                       const int* __restrict__ ih, const int* __restrict__ iw,
                       float* __restrict__ wm, float* __restrict__ r2u, float* __restrict__ r2v) {
    int idx = blockIdx.x * blockDim.x + threadIdx.x;  // cam*1024 + n
    if (idx >= CAM * NQ) return;
    int cam = idx >> 10, n = idx & 1023;
    float fH = (float)(*ih), fW = (float)(*iw);
    const float* M = l2i + cam * 16;
    float mx = gp[n * PROPN], my = gp[n * PROPN + 1], mz = gp[n * PROPN + 2];
#pragma unroll
    for (int r = 0; r < RR; ++r) {
        float px = mx + refoff[n * 12 + r * 3 + 0];
        float py = my + refoff[n * 12 + r * 3 + 1];
        float pz = mz + refoff[n * 12 + r * 3 + 2];
        float p0 = M[0] * px + M[1] * py + M[2]  * pz + M[3];
        float p1 = M[4] * px + M[5] * py + M[6]  * pz + M[7];
        float p2 = M[8] * px + M[9] * py + M[10] * pz + M[11];
        float zc = fmaxf(p2, 1e-5f);
        float u = p0 / zc, v = p1 / zc;
        bool valid = (p2 > 1e-5f) && (u >= 0.f) && (u < fW) && (v >= 0.f) && (v < fH);
        int iu = min(max((int)(u / fW * 176.f), 0), 175);
        int iv = min(max((int)(v / fH * 64.f), 0), 63);
        float ds = depth[cam * 64 * 176 + iv * 176 + iu];
        int o = cam * (NQ * RR) + n * RR + r;
        wm[o]  = valid ? expf(-fabsf(p2 - ds)) : 0.f;
        r2u[o] = u / fW;
        r2v[o] = v / fH;
    }
}

// ---------------- deformable sampling + weighted reduce (bf16 value) ----------------
__global__ void k_sample(const unsigned short* __restrict__ value, const float* __restrict__ offsb,
                         const float* __restrict__ attn, const float* __restrict__ wm,
                         const float* __restrict__ r2u, const float* __restrict__ r2v,
                         float* __restrict__ sampout) {
    const int Wl_[4] = {176, 88, 44, 22};
    const int Hl_[4] = {64, 32, 16, 8};
    const int s0_[4] = {0, 11264, 14080, 14784};
    int n = blockIdx.x, tid = threadIdx.x;
    __shared__ float s_attn[1024];
    __shared__ float s_offs[2048];
    __shared__ float s_wm[24], s_ru[24], s_rv[24];
    __shared__ float red[8 * 32 * 16];

    for (int i = tid; i < 1024; i += 256) s_attn[i] = attn[(size_t)n * 1024 + i];
    for (int i = tid; i < 2048; i += 256) s_offs[i] = offsb[(size_t)n * 2048 + i];
    if (tid < 24) {
        int cam = tid >> 2, r = tid & 3;
        int o = cam * (NQ * RR) + n * RR + r;
        s_wm[tid] = wm[o]; s_ru[tid] = r2u[o]; s_rv[tid] = r2v[o];
    }
    __syncthreads();

    int h = tid >> 5, slot = tid & 31;
    int l = slot >> 3, p = slot & 7;
    int Wl = Wl_[l], Hl = Hl_[l];
    float fWl = (float)Wl, fHl = (float)Hl;
    float acc[16];
#pragma unroll
    for (int d = 0; d < 16; ++d) acc[d] = 0.f;

    for (int cr = 0; cr < 24; ++cr) {
        int cam = cr >> 2, r = cr & 3;
        float ws = s_attn[h * 128 + r * 32 + l * 8 + p] * s_wm[cr];
        if (ws == 0.f) continue;
        float ox = s_offs[h * 256 + r * 64 + l * 16 + p * 2 + 0];
        float oy = s_offs[h * 256 + r * 64 + l * 16 + p * 2 + 1];
        float x = s_ru[cr] * fWl + ox - 0.5f;
        float y = s_rv[cr] * fHl + oy - 0.5f;
        float xf = floorf(x), yf = floorf(y);
        float wx = x - xf, wy = y - yf;
        int x0 = min(max((int)xf, 0), Wl - 1);
        int x1 = min(max((int)xf + 1, 0), Wl - 1);
        int y0 = min(max((int)yf, 0), Hl - 1);
        int y1 = min(max((int)yf + 1, 0), Hl - 1);
        size_t b = ((size_t)cam * S_TOT + s0_[l]) * CC + h * HDD;
        const unsigned short* p00 = value + b + (size_t)(y0 * Wl + x0) * CC;
        const unsigned short* p01 = value + b + (size_t)(y0 * Wl + x1) * CC;
        const unsigned short* p10 = value + b + (size_t)(y1 * Wl + x0) * CC;
        const unsigned short* p11 = value + b + (size_t)(y1 * Wl + x1) * CC;
        float w00 = ws * (1.f - wx) * (1.f - wy);
        float w01 = ws * wx * (1.f - wy);
        float w10 = ws * (1.f - wx) * wy;
        float w11 = ws * wx * wy;
        bf16x8 va0 = *(const bf16x8*)p00, va1 = *(const bf16x8*)(p00 + 8);
        bf16x8 vb0 = *(const bf16x8*)p01, vb1 = *(const bf16x8*)(p01 + 8);
        bf16x8 vc0 = *(const bf16x8*)p10, vc1 = *(const bf16x8*)(p10 + 8);
        bf16x8 vd0 = *(const bf16x8*)p11, vd1 = *(const bf16x8*)(p11 + 8);
#pragma unroll
        for (int d = 0; d < 8; ++d)
            acc[d] += w00 * bf2f(va0[d]) + w01 * bf2f(vb0[d]) + w10 * bf2f(vc0[d]) + w11 * bf2f(vd0[d]);
#pragma unroll
        for (int d = 0; d < 8; ++d)
            acc[8 + d] += w00 * bf2f(va1[d]) + w01 * bf2f(vb1[d]) + w10 * bf2f(vc1[d]) + w11 * bf2f(vd1[d]);
    }

    int base = (h * 32 + slot) * 16;
#pragma unroll
    for (int d = 0; d < 16; ++d) red[base + d] = acc[d];
    __syncthreads();
    for (int s = 16; s >= 1; s >>= 1) {
        if (slot < s) {
#pragma unroll
            for (int d = 0; d < 16; ++d) red[base + d] += red[base + s * 16 + d];
        }
        __syncthreads();
    }
    if (tid < 128) {
        int hh = tid >> 4, dd = tid & 15;
        sampout[(size_t)n * CC + tid] = red[hh * 512 + dd];
    }
}

// ---------------- launch ----------------
extern "C" void kernel_launch(void* const* d_in, const int* in_sizes, int n_in,
                              void* d_out, int out_size, void* d_ws, size_t ws_size,
                              hipStream_t stream) {
    const float* query = (const float*)d_in[0];
    const float* gp    = (const float*)d_in[1];
    const float* ms    = (const float*)d_in[2];
    const float* depth = (const float*)d_in[3];
    const float* l2i   = (const float*)d_in[4];
    const int*   ih    = (const int*)d_in[5];
    const int*   iw    = (const int*)d_in[6];
    const float* Wsc   = (const float*)d_in[7];
    const float* bsc   = (const float*)d_in[8];
    const float* scg   = (const float*)d_in[9];
    const float* scb   = (const float*)d_in[10];
    const float* refw  = (const float*)d_in[11];
    const float* refb  = (const float*)d_in[12];
    const float* offw  = (const float*)d_in[13];
    const float* offbi = (const float*)d_in[14];
    const float* aww   = (const float*)d_in[15];
    const float* awb   = (const float*)d_in[16];
    const float* valw  = (const float*)d_in[17];
    const float* valb  = (const float*)d_in[18];
    const float* outw  = (const float*)d_in[19];
    const float* outb  = (const float*)d_in[20];
    const float* ang   = (const float*)d_in[21];
    const float* anb   = (const float*)d_in[22];
    const float* f1w   = (const float*)d_in[23];
    const float* f1b   = (const float*)d_in[24];
    const float* f2w   = (const float*)d_in[25];
    const float* f2b   = (const float*)d_in[26];
    const float* fng   = (const float*)d_in[27];
    const float* fnb   = (const float*)d_in[28];
    const float* p1w   = (const float*)d_in[29];
    const float* p1b   = (const float*)d_in[30];
    const float* p2w   = (const float*)d_in[31];
    const float* p2b   = (const float*)d_in[32];

    float* outq = (float*)d_out;            // 1024*128
    float* outp = outq + NQ * CC;           // 1024*28

    // workspace carve (floats). First region [grid|cnt|flatidx|convacc] is
    // contiguous and zeroed with ONE memset.
    float* ws = (float*)d_ws;
    size_t o = 0;
    float* grid    = ws + o; o += (size_t)GG * GG * GG * CC;   // 4,194,304
    float* cnt     = ws + o; o += GG * GG * GG;                // 32,768
    int*   flatidx = (int*)(ws + o); o += NQ;
    float* convacc = ws + o; o += NQ * CC;
    size_t zero_floats = o;                                    // 4,359,168
    float* q1      = ws + o; o += NQ * CC;
    float* refoff  = ws + o; o += NQ * 12;
    float* offsb   = ws + o; o += (size_t)NQ * 2048;
    float* attn    = ws + o; o += (size_t)NQ * 1024;
    float* wm      = ws + o; o += CAM * NQ * RR;
    float* r2u     = ws + o; o += CAM * NQ * RR;
    float* r2v     = ws + o; o += CAM * NQ * RR;
    float* sampout = ws + o; o += NQ * CC;
    float* q2      = ws + o; o += NQ * CC;
    float* ffn1    = ws + o; o += NQ * 512;
    float* p1out   = ws + o; o += NQ * CC;
    // u16 region: bf16 value + transposed bf16 weights
    unsigned short* u16base = (unsigned short*)(ws + o);
    size_t uo = 0;
    unsigned short* value = u16base + uo; uo += (size_t)CAM * S_TOT * CC;  // 11,489,280
    unsigned short* offwT = u16base + uo; uo += (size_t)2048 * 128;
    unsigned short* awwT  = u16base + uo; uo += (size_t)1024 * 128;
    unsigned short* valwT = u16base + uo; uo += 128 * 128;
    unsigned short* outwT = u16base + uo; uo += 128 * 128;
    unsigned short* f1wT  = u16base + uo; uo += 512 * 128;
    unsigned short* f2wT  = u16base + uo; uo += 128 * 512;
    unsigned short* p1wT  = u16base + uo; uo += 128 * 128;
    unsigned short* WscT  = u16base + uo; uo += (size_t)27 * 128 * 128;
    (void)ws_size; (void)in_sizes; (void)n_in; (void)out_size;

    // all weight transposes in one dispatch
    k_wt_all<<<dim3(2, 2, 62), 256, 0, stream>>>(Wsc, WscT, valw, valwT, outw, outwT,
                                                 p1w, p1wT, f1w, f1wT, f2w, f2wT,
                                                 offw, offwT, aww, awwT);
    hipMemsetAsync(ws, 0, zero_floats * sizeof(float), stream);

    k_scatter<<<NQ, CC, 0, stream>>>(query, gp, grid, cnt, flatidx);
    k_conv1m<<<dim3(8, 27), 256, 0, stream>>>(grid, cnt, flatidx, WscT, convacc);
    k_ln_conv<<<NQ, CC, 0, stream>>>(query, convacc, bsc, scg, scb, q1);

    k_gemm<<<dim3(1, 32), 256, 0, stream>>>(q1, refw, refb, nullptr, refoff, NQ, 128, 12, 0);
    k_mfma_bt<128, 0><<<dim3(16, 8), 256, 0, stream>>>(q1, offwT, offbi, nullptr, nullptr, nullptr,
                                                       offsb, NQ, 128, 2048, 0);
    k_mfma_bt<128, 2><<<dim3(8, 8), 256, 0, stream>>>(q1, awwT, awb, nullptr, nullptr, nullptr,
                                                      attn, NQ, 128, 1024, 0);
    k_proj<<<24, 256, 0, stream>>>(gp, refoff, l2i, depth, ih, iw, wm, r2u, r2v);

    // value projection -> bf16 (no aliasing with grid anymore)
    k_valproj<<<(CAM * S_TOT * 1 + 63) / 64, 256, 0, stream>>>(ms, valwT, valb, value, CAM * S_TOT);
    k_sample<<<NQ, 256, 0, stream>>>(value, offsb, attn, wm, r2u, r2v, sampout);

    // attn out-proj + residual + LN  -> q2
    k_mfma_bt<32, 1><<<dim3(1, 32), 256, 0, stream>>>(sampout, outwT, outb, q1, ang, anb,
                                                      q2, NQ, 128, 128, 0);
    // FFN
    k_mfma_bt<32, 0><<<dim3(4, 32), 256, 0, stream>>>(q2, f1wT, f1b, nullptr, nullptr, nullptr,
                                                      ffn1, NQ, 128, 512, 1);
    k_mfma_bt<32, 1><<<dim3(1, 32), 256, 0, stream>>>(ffn1, f2wT, f2b, q2, fng, fnb,
                                                      outq, NQ, 512, 128, 0);
    // props head
    k_mfma_bt<32, 0><<<dim3(1, 32), 256, 0, stream>>>(outq, p1wT, p1b, nullptr, nullptr, nullptr,
                                                      p1out, NQ, 128, 128, 1);
    k_gemm<<<dim3(1, 32), 256, 0, stream>>>(p1out, p2w, p2b, gp, outp, NQ, 128, PROPN, 0);
}

// Round 6
// 302.580 us; speedup vs baseline: 2.7955x; 1.0780x over previous
//
#include <hip/hip_runtime.h>
#include <hip/hip_bf16.h>
#include <math.h>

// ---------------- constants ----------------
#define NQ    1024
#define CC    128
#define CAM   6
#define RR    4
#define LL    4
#define PP    8
#define HHD   8     // heads
#define HDD   16    // head dim
#define GG    32
#define S_TOT 14960
#define PROPN 28

typedef __attribute__((ext_vector_type(8))) short bf16x8;
typedef __attribute__((ext_vector_type(4))) float f32x4;

__device__ __forceinline__ float gelu_tanh(float x) {
    return 0.5f * x * (1.0f + tanhf(0.7978845608028654f * (x + 0.044715f * x * x * x)));
}

__device__ __forceinline__ unsigned short f2bf(float f) {
    union { float f; unsigned int u; } x; x.f = f;
    unsigned int r = (x.u + 0x7FFFu + ((x.u >> 16) & 1u)) >> 16;
    return (unsigned short)r;
}

__device__ __forceinline__ float bf2f(short s) {
    union { unsigned int u; float f; } x;
    x.u = ((unsigned int)(unsigned short)s) << 16;
    return x.f;
}

// ---------------- fused weight transpose+convert (all weights, one dispatch) ----------
// z<27: conv taps; 27 val; 28 out; 29 p1; 30-33 f1; 34-37 f2; 38-53 off; 54-61 aw;
// 62: p2 zero-padded to 128x128 + padded bias.
__global__ void k_wt_all(const float* __restrict__ Wsc, unsigned short* __restrict__ WscT,
                         const float* __restrict__ valw, unsigned short* __restrict__ valwT,
                         const float* __restrict__ outw, unsigned short* __restrict__ outwT,
                         const float* __restrict__ p1w, unsigned short* __restrict__ p1wT,
                         const float* __restrict__ f1w, unsigned short* __restrict__ f1wT,
                         const float* __restrict__ f2w, unsigned short* __restrict__ f2wT,
                         const float* __restrict__ offw, unsigned short* __restrict__ offwT,
                         const float* __restrict__ aww, unsigned short* __restrict__ awwT,
                         const float* __restrict__ p2w, unsigned short* __restrict__ p2wT,
                         const float* __restrict__ p2b, float* __restrict__ p2bp) {
    __shared__ float t[64][65];
    int z = blockIdx.z;
    int n0 = blockIdx.x * 64, k0 = blockIdx.y * 64, tid = threadIdx.x;
    if (z == 62) {
        // p2w: [128 k][28 n] -> p2wT[128 n][128 k], zero-padded n>=28
#pragma unroll
        for (int it = 0; it < 16; ++it) {
            int idx = tid + it * 256;
            int r = idx >> 6, c = idx & 63;
            t[r][c] = (n0 + c < PROPN) ? p2w[(size_t)(k0 + r) * PROPN + n0 + c] : 0.f;
        }
        __syncthreads();
#pragma unroll
        for (int it = 0; it < 16; ++it) {
            int idx = tid + it * 256;
            int r = idx >> 6, c = idx & 63;
            p2wT[(size_t)(n0 + r) * 128 + k0 + c] = f2bf(t[c][r]);
        }
        if (blockIdx.x == 0 && blockIdx.y == 0 && tid < 128)
            p2bp[tid] = (tid < PROPN) ? p2b[tid] : 0.f;
        return;
    }
    const float* src; unsigned short* dst; int ss, ds;
    if (z < 27)       { src = Wsc + (size_t)z * 16384; dst = WscT + (size_t)z * 16384; ss = 128; ds = 128; }
    else if (z == 27) { src = valw; dst = valwT; ss = 128; ds = 128; }
    else if (z == 28) { src = outw; dst = outwT; ss = 128; ds = 128; }
    else if (z == 29) { src = p1w;  dst = p1wT;  ss = 128; ds = 128; }
    else if (z < 34)  { int q = z - 30; src = f1w + q * 128; dst = f1wT + (size_t)q * 16384; ss = 512;  ds = 128; }
    else if (z < 38)  { int q = z - 34; src = f2w + (size_t)q * 16384; dst = f2wT + q * 128; ss = 128;  ds = 512; }
    else if (z < 54)  { int q = z - 38; src = offw + q * 128; dst = offwT + (size_t)q * 16384; ss = 2048; ds = 128; }
    else              { int q = z - 54; src = aww + q * 128;  dst = awwT + (size_t)q * 16384; ss = 1024; ds = 128; }
#pragma unroll
    for (int it = 0; it < 16; ++it) {
        int idx = tid + it * 256;
        int r = idx >> 6, c = idx & 63;
        t[r][c] = src[(size_t)(k0 + r) * ss + n0 + c];
    }
    __syncthreads();
#pragma unroll
    for (int it = 0; it < 16; ++it) {
        int idx = tid + it * 256;
        int r = idx >> 6, c = idx & 63;
        dst[(size_t)(n0 + r) * ds + k0 + c] = f2bf(t[c][r]);
    }
}

// ---------------- scatter-add into voxel grid ----------------
__global__ void k_scatter(const float* __restrict__ q, const float* __restrict__ gp,
                          float* __restrict__ grid, float* __restrict__ cnt,
                          int* __restrict__ flatidx) {
    int n = blockIdx.x;
    int c = threadIdx.x;
    __shared__ int sflat;
    if (c == 0) {
        float mx = gp[n * PROPN + 0], my = gp[n * PROPN + 1], mz = gp[n * PROPN + 2];
        int vx = (int)floorf((mx + 4.0f) * 4.0f);
        int vy = (int)floorf((my + 4.0f) * 4.0f);
        int vz = (int)floorf((mz + 4.0f) * 4.0f);
        vx = min(max(vx, 0), GG - 1);
        vy = min(max(vy, 0), GG - 1);
        vz = min(max(vz, 0), GG - 1);
        int f = (vx * GG + vy) * GG + vz;
        sflat = f;
        flatidx[n] = f;
        atomicAdd(&cnt[f], 1.0f);
    }
    __syncthreads();
    atomicAdd(&grid[sflat * CC + c], q[n * CC + c]);
}

// ---------------- generic MFMA bf16 GEMM with bf16 pre-transposed weights ----------------
// out[M,*] = epilogue(A[M,K] @ WT[N,K]^T). FUSE: 0 plain(+act/+resid, Nout = out width
// & stride, cols >= Nout dropped), 1 = +bias +resid +LayerNorm (N==128), 2 = +bias
// +softmax over the 128-col tile. OUTBF: write bf16 instead of fp32 (FUSE 0/2).
template<int BM, int FUSE, bool OUTBF>
__global__ __launch_bounds__(256) void k_mfma_bt(
    const float* __restrict__ A, const unsigned short* __restrict__ WT,
    const float* __restrict__ bias, const float* __restrict__ resid,
    const float* __restrict__ lng, const float* __restrict__ lnb,
    void* __restrict__ outv, int M, int K, int N, int Nout, int act)
{
    constexpr int WM = BM / 32;            // 16-row tiles per wave
    __shared__ bf16x8 As[BM * 16];
    __shared__ bf16x8 Bs[128 * 16];
    __shared__ float xrow[(FUSE != 0) ? BM * 128 : 1];
    int tid = threadIdx.x;
    int m0 = blockIdx.y * BM, n0 = blockIdx.x * 128;
    int lane = tid & 63, wv = tid >> 6;
    int wr = (wv >> 1) * (BM / 2), wc = (wv & 1) * 64;
    int r = lane & 15, q = lane >> 4;

    f32x4 acc[WM][4];
#pragma unroll
    for (int i = 0; i < WM; ++i)
#pragma unroll
        for (int j = 0; j < 4; ++j)
#pragma unroll
            for (int e = 0; e < 4; ++e) acc[i][j][e] = 0.f;

    for (int kc = 0; kc < K; kc += 128) {
        if (kc) __syncthreads();
#pragma unroll
        for (int it = 0; it < BM * 16 / 256; ++it) {
            int idx = tid + it * 256;
            int m = idx >> 4, c = idx & 15;
            int mg = min(m0 + m, M - 1);
            const float* p = A + (size_t)mg * K + kc + c * 8;
            float4 a = *(const float4*)p;
            float4 b = *(const float4*)(p + 4);
            bf16x8 u;
            u[0] = (short)f2bf(a.x); u[1] = (short)f2bf(a.y);
            u[2] = (short)f2bf(a.z); u[3] = (short)f2bf(a.w);
            u[4] = (short)f2bf(b.x); u[5] = (short)f2bf(b.y);
            u[6] = (short)f2bf(b.z); u[7] = (short)f2bf(b.w);
            As[m * 16 + (c ^ (m & 15))] = u;
        }
#pragma unroll
        for (int it = 0; it < 8; ++it) {
            int idx = tid + it * 256;
            int n = idx >> 4, c = idx & 15;
            bf16x8 w = *(const bf16x8*)(WT + (size_t)(n0 + n) * K + kc + c * 8);
            Bs[n * 16 + (c ^ (n & 15))] = w;
        }
        __syncthreads();
#pragma unroll
        for (int ks = 0; ks < 4; ++ks) {
            bf16x8 bfr[4];
#pragma unroll
            for (int j = 0; j < 4; ++j)
                bfr[j] = Bs[(wc + j * 16 + r) * 16 + ((ks * 4 + q) ^ r)];
#pragma unroll
            for (int i = 0; i < WM; ++i) {
                bf16x8 af = As[(wr + i * 16 + r) * 16 + ((ks * 4 + q) ^ r)];
#pragma unroll
                for (int j = 0; j < 4; ++j)
                    acc[i][j] = __builtin_amdgcn_mfma_f32_16x16x32_bf16(af, bfr[j], acc[i][j], 0, 0, 0);
            }
        }
    }

    if (FUSE == 0) {
#pragma unroll
        for (int i = 0; i < WM; ++i)
#pragma unroll
            for (int e = 0; e < 4; ++e) {
                int m = m0 + wr + i * 16 + q * 4 + e;
                if (m < M) {
#pragma unroll
                    for (int j = 0; j < 4; ++j) {
                        int col = n0 + wc + j * 16 + r;
                        if (col < Nout) {
                            float v = acc[i][j][e] + bias[col];
                            if (act) v = gelu_tanh(v);
                            if (resid) v += resid[(size_t)m * Nout + col];
                            if (OUTBF) ((unsigned short*)outv)[(size_t)m * Nout + col] = f2bf(v);
                            else       ((float*)outv)[(size_t)m * Nout + col] = v;
                        }
                    }
                }
            }
    } else {
#pragma unroll
        for (int i = 0; i < WM; ++i)
#pragma unroll
            for (int e = 0; e < 4; ++e) {
                int ml = wr + i * 16 + q * 4 + e;
#pragma unroll
                for (int j = 0; j < 4; ++j) {
                    int cl = wc + j * 16 + r;
                    float v = acc[i][j][e] + bias[n0 + cl];
                    if (FUSE == 1) v += resid[(size_t)(m0 + ml) * N + n0 + cl];
                    xrow[ml * 128 + cl] = v;
                }
            }
        __syncthreads();
        constexpr int TPR = 256 / BM;      // threads per row
        int row = tid / TPR, s = tid % TPR;
        float* xr = xrow + row * 128;
        if (FUSE == 1) {
            float* orow = (float*)outv + (size_t)(m0 + row) * N + n0;
            float sum = 0.f;
#pragma unroll
            for (int e = s; e < 128; e += TPR) sum += xr[e];
#pragma unroll
            for (int d = TPR >> 1; d; d >>= 1) sum += __shfl_xor(sum, d, TPR);
            float mean = sum * (1.0f / 128.0f);
            float var = 0.f;
#pragma unroll
            for (int e = s; e < 128; e += TPR) { float dd = xr[e] - mean; var += dd * dd; }
#pragma unroll
            for (int d = TPR >> 1; d; d >>= 1) var += __shfl_xor(var, d, TPR);
            float rstd = rsqrtf(var * (1.0f / 128.0f) + 1e-5f);
#pragma unroll
            for (int e = s; e < 128; e += TPR)
                orow[e] = (xr[e] - mean) * rstd * lng[e] + lnb[e];
        } else {  // FUSE == 2: softmax over the 128-col tile
            float mx = -1e30f;
#pragma unroll
            for (int e = s; e < 128; e += TPR) mx = fmaxf(mx, xr[e]);
#pragma unroll
            for (int d = TPR >> 1; d; d >>= 1) mx = fmaxf(mx, __shfl_xor(mx, d, TPR));
            float sum = 0.f;
#pragma unroll
            for (int e = s; e < 128; e += TPR) { float ee = expf(xr[e] - mx); xr[e] = ee; sum += ee; }
#pragma unroll
            for (int d = TPR >> 1; d; d >>= 1) sum += __shfl_xor(sum, d, TPR);
            float inv = 1.0f / sum;
            if (OUTBF) {
                unsigned short* orow = (unsigned short*)outv + (size_t)(m0 + row) * N + n0;
#pragma unroll
                for (int e = s; e < 128; e += TPR) orow[e] = f2bf(xr[e] * inv);
            } else {
                float* orow = (float*)outv + (size_t)(m0 + row) * N + n0;
#pragma unroll
                for (int e = s; e < 128; e += TPR) orow[e] = xr[e] * inv;
            }
        }
    }
}

// ---------------- value projection: A[M,128] @ WT[128,128]^T -> bf16 out ----------------
__global__ __launch_bounds__(256) void k_valproj(
    const float* __restrict__ A, const unsigned short* __restrict__ WT,
    const float* __restrict__ bias, unsigned short* __restrict__ out, int M)
{
    __shared__ bf16x8 Bs[128 * 16];          // 32 KB
    __shared__ unsigned short Os[64 * 128];  // 16 KB
    __shared__ float sbias[128];
    int tid = threadIdx.x;
    int m0 = blockIdx.x * 64;
    int lane = tid & 63, wv = tid >> 6;
    int r = lane & 15, q = lane >> 4;

#pragma unroll
    for (int it = 0; it < 8; ++it) {
        int idx = tid + it * 256;
        int n = idx >> 4, c = idx & 15;
        Bs[n * 16 + (c ^ (n & 15))] = *(const bf16x8*)(WT + (size_t)n * 128 + c * 8);
    }
    if (tid < 128) sbias[tid] = bias[tid];
    __syncthreads();

    int row = m0 + wv * 16 + r;
    int mg = min(row, M - 1);
    const float* pA = A + (size_t)mg * 128;

    f32x4 acc[8];
#pragma unroll
    for (int j = 0; j < 8; ++j)
#pragma unroll
        for (int e = 0; e < 4; ++e) acc[j][e] = 0.f;

#pragma unroll
    for (int ks = 0; ks < 4; ++ks) {
        const float* p = pA + ks * 32 + q * 8;
        float4 a = *(const float4*)p;
        float4 b = *(const float4*)(p + 4);
        bf16x8 af;
        af[0] = (short)f2bf(a.x); af[1] = (short)f2bf(a.y);
        af[2] = (short)f2bf(a.z); af[3] = (short)f2bf(a.w);
        af[4] = (short)f2bf(b.x); af[5] = (short)f2bf(b.y);
        af[6] = (short)f2bf(b.z); af[7] = (short)f2bf(b.w);
        bf16x8 bfr[8];
#pragma unroll
        for (int j = 0; j < 8; ++j)
            bfr[j] = Bs[(j * 16 + r) * 16 + ((ks * 4 + q) ^ r)];
#pragma unroll
        for (int j = 0; j < 8; ++j)
            acc[j] = __builtin_amdgcn_mfma_f32_16x16x32_bf16(af, bfr[j], acc[j], 0, 0, 0);
    }

#pragma unroll
    for (int j = 0; j < 8; ++j)
#pragma unroll
        for (int e = 0; e < 4; ++e) {
            int rl = wv * 16 + q * 4 + e;
            Os[rl * 128 + j * 16 + r] = f2bf(acc[j][e] + sbias[j * 16 + r]);
        }
    __syncthreads();
#pragma unroll
    for (int it = 0; it < 4; ++it) {
        int idx = tid + it * 256;
        int rl = idx >> 4, ch = idx & 15;
        int m = m0 + rl;
        if (m < M)
            *(bf16x8*)(out + (size_t)m * 128 + ch * 8) = *(const bf16x8*)&Os[rl * 128 + ch * 8];
    }
}

// ---------------- conv as 27 per-tap MFMA GEMMs with atomic accumulate ----------------
__global__ __launch_bounds__(256) void k_conv1m(
    const float* __restrict__ grid, const float* __restrict__ cnt,
    const int* __restrict__ flatidx, const unsigned short* __restrict__ WT,
    float* __restrict__ accum) {
    __shared__ bf16x8 As[128 * 16];
    __shared__ bf16x8 Bs[128 * 16];
    __shared__ int   nbase[128];
    __shared__ float nscale[128];
    int tid = threadIdx.x;
    int tap = blockIdx.y;
    int q0 = blockIdx.x * 128;
    int dz = tap / 9 - 1, dy = (tap / 3) % 3 - 1, dx = tap % 3 - 1;

    if (tid < 128) {
        int f = flatidx[q0 + tid];
        int nx = (f >> 10) + dz, ny = ((f >> 5) & 31) + dy, nz = (f & 31) + dx;
        bool ok = (nx >= 0 && nx < GG && ny >= 0 && ny < GG && nz >= 0 && nz < GG);
        int nf = ok ? (nx * GG + ny) * GG + nz : 0;
        nbase[tid] = nf;
        nscale[tid] = ok ? 1.0f / fmaxf(cnt[nf], 1.0f) : 0.f;
    }
    __syncthreads();
#pragma unroll
    for (int it = 0; it < 8; ++it) {
        int idx = tid + it * 256;
        int m = idx >> 4, c = idx & 15;
        const float* p = grid + (size_t)nbase[m] * CC + c * 8;
        float s = nscale[m];
        float4 a = *(const float4*)p;
        float4 b = *(const float4*)(p + 4);
        bf16x8 u;
        u[0] = (short)f2bf(a.x * s); u[1] = (short)f2bf(a.y * s);
        u[2] = (short)f2bf(a.z * s); u[3] = (short)f2bf(a.w * s);
        u[4] = (short)f2bf(b.x * s); u[5] = (short)f2bf(b.y * s);
        u[6] = (short)f2bf(b.z * s); u[7] = (short)f2bf(b.w * s);
        As[m * 16 + (c ^ (m & 15))] = u;
    }
    const unsigned short* Wt = WT + (size_t)tap * CC * CC;
#pragma unroll
    for (int it = 0; it < 8; ++it) {
        int idx = tid + it * 256;
        int n = idx >> 4, c = idx & 15;
        bf16x8 w = *(const bf16x8*)(Wt + (size_t)n * CC + c * 8);
        Bs[n * 16 + (c ^ (n & 15))] = w;
    }
    __syncthreads();

    int lane = tid & 63, wv = tid >> 6;
    int wr = (wv >> 1) * 64, wc = (wv & 1) * 64;
    int r = lane & 15, q = lane >> 4;
    f32x4 acc[4][4];
#pragma unroll
    for (int i = 0; i < 4; ++i)
#pragma unroll
        for (int j = 0; j < 4; ++j)
#pragma unroll
            for (int e = 0; e < 4; ++e) acc[i][j][e] = 0.f;
#pragma unroll
    for (int ks = 0; ks < 4; ++ks) {
        bf16x8 bfr[4];
#pragma unroll
        for (int j = 0; j < 4; ++j)
            bfr[j] = Bs[(wc + j * 16 + r) * 16 + ((ks * 4 + q) ^ r)];
#pragma unroll
        for (int i = 0; i < 4; ++i) {
            bf16x8 af = As[(wr + i * 16 + r) * 16 + ((ks * 4 + q) ^ r)];
#pragma unroll
            for (int j = 0; j < 4; ++j)
                acc[i][j] = __builtin_amdgcn_mfma_f32_16x16x32_bf16(af, bfr[j], acc[i][j], 0, 0, 0);
        }
    }
#pragma unroll
    for (int i = 0; i < 4; ++i)
#pragma unroll
        for (int e = 0; e < 4; ++e) {
            int m = q0 + wr + i * 16 + q * 4 + e;
#pragma unroll
            for (int j = 0; j < 4; ++j) {
                int col = wc + j * 16 + r;
                atomicAdd(&accum[(size_t)m * CC + col], acc[i][j][e]);
            }
        }
}

// q1 = LN(query + gelu(accum + bias)) * g + be
__global__ void k_ln_conv(const float* __restrict__ a, const float* __restrict__ accum,
                          const float* __restrict__ bconv,
                          const float* __restrict__ g, const float* __restrict__ be,
                          float* __restrict__ out) {
    int n = blockIdx.x, c = threadIdx.x;
    float x = a[n * CC + c] + gelu_tanh(accum[n * CC + c] + bconv[c]);
    __shared__ float red[CC];
    red[c] = x;
    __syncthreads();
    for (int s = 64; s >= 1; s >>= 1) { if (c < s) red[c] += red[c + s]; __syncthreads(); }
    float m = red[0] * (1.0f / CC);
    __syncthreads();
    float d = x - m;
    red[c] = d * d;
    __syncthreads();
    for (int s = 64; s >= 1; s >>= 1) { if (c < s) red[c] += red[c + s]; __syncthreads(); }
    float v = red[0] * (1.0f / CC);
    out[n * CC + c] = d * rsqrtf(v + 1e-5f) * g[c] + be[c];
}

// ---------------- ref-offset dots + projection + depth weighting ----------------
// one block per query (64 threads): 12 refoff dots from LDS q1 row, then 24 (cam,r) projections.
__global__ void k_proj(const float* __restrict__ q1, const float* __restrict__ refw,
                       const float* __restrict__ refb, const float* __restrict__ gp,
                       const float* __restrict__ l2i, const float* __restrict__ depth,
                       const int* __restrict__ ih, const int* __restrict__ iw,
                       float* __restrict__ wm, float* __restrict__ r2u, float* __restrict__ r2v) {
    int n = blockIdx.x, tid = threadIdx.x;
    __shared__ float qrow[128];
    __shared__ float ro[12];
    qrow[tid]      = q1[n * CC + tid];
    qrow[tid + 64] = q1[n * CC + tid + 64];
    __syncthreads();
    if (tid < 12) {
        float s = refb[tid];
#pragma unroll 4
        for (int k = 0; k < 128; ++k) s += qrow[k] * refw[k * 12 + tid];
        ro[tid] = s;
    }
    __syncthreads();
    if (tid < 24) {
        int cam = tid >> 2, r = tid & 3;
        float fH = (float)(*ih), fW = (float)(*iw);
        const float* M = l2i + cam * 16;
        float px = gp[n * PROPN + 0] + ro[r * 3 + 0];
        float py = gp[n * PROPN + 1] + ro[r * 3 + 1];
        float pz = gp[n * PROPN + 2] + ro[r * 3 + 2];
        float p0 = M[0] * px + M[1] * py + M[2]  * pz + M[3];
        float p1 = M[4] * px + M[5] * py + M[6]  * pz + M[7];
        float p2 = M[8] * px + M[9] * py + M[10] * pz + M[11];
        float zc = fmaxf(p2, 1e-5f);
        float u = p0 / zc, v = p1 / zc;
        bool valid = (p2 > 1e-5f) && (u >= 0.f) && (u < fW) && (v >= 0.f) && (v < fH);
        int iu = min(max((int)(u / fW * 176.f), 0), 175);
        int iv = min(max((int)(v / fH * 64.f), 0), 63);
        float ds = depth[cam * 64 * 176 + iv * 176 + iu];
        int o = cam * (NQ * RR) + n * RR + r;
        wm[o]  = valid ? expf(-fabsf(p2 - ds)) : 0.f;
        r2u[o] = u / fW;
        r2v[o] = v / fH;
    }
}

// ---------------- deformable sampling + weighted reduce (all-bf16 inputs) ----------------
__global__ void k_sample(const unsigned short* __restrict__ value,
                         const unsigned short* __restrict__ offsb,
                         const unsigned short* __restrict__ attn,
                         const float* __restrict__ wm,
                         const float* __restrict__ r2u, const float* __restrict__ r2v,
                         float* __restrict__ sampout) {
    const int Wl_[4] = {176, 88, 44, 22};
    const int Hl_[4] = {64, 32, 16, 8};
    const int s0_[4] = {0, 11264, 14080, 14784};
    int n = blockIdx.x, tid = threadIdx.x;
    __shared__ float s_attn[1024];
    __shared__ float s_offs[2048];
    __shared__ float s_wm[24], s_ru[24], s_rv[24];

    if (tid < 128) {
        bf16x8 v = *(const bf16x8*)(attn + (size_t)n * 1024 + tid * 8);
#pragma unroll
        for (int d = 0; d < 8; ++d) s_attn[tid * 8 + d] = bf2f(v[d]);
    }
    {
        bf16x8 v = *(const bf16x8*)(offsb + (size_t)n * 2048 + tid * 8);
#pragma unroll
        for (int d = 0; d < 8; ++d) s_offs[tid * 8 + d] = bf2f(v[d]);
    }
    if (tid < 24) {
        int cam = tid >> 2, r = tid & 3;
        int o = cam * (NQ * RR) + n * RR + r;
        s_wm[tid] = wm[o]; s_ru[tid] = r2u[o]; s_rv[tid] = r2v[o];
    }
    __syncthreads();

    int h = tid >> 5, slot = tid & 31;
    int l = slot >> 3, p = slot & 7;
    int Wl = Wl_[l], Hl = Hl_[l];
    float fWl = (float)Wl, fHl = (float)Hl;
    float acc[16];
#pragma unroll
    for (int d = 0; d < 16; ++d) acc[d] = 0.f;

    for (int cr = 0; cr < 24; ++cr) {
        int cam = cr >> 2, r = cr & 3;
        float ws = s_attn[h * 128 + r * 32 + l * 8 + p] * s_wm[cr];
        if (ws == 0.f) continue;
        float ox = s_offs[h * 256 + r * 64 + l * 16 + p * 2 + 0];
        float oy = s_offs[h * 256 + r * 64 + l * 16 + p * 2 + 1];
        float x = s_ru[cr] * fWl + ox - 0.5f;
        float y = s_rv[cr] * fHl + oy - 0.5f;
        float xf = floorf(x), yf = floorf(y);
        float wx = x - xf, wy = y - yf;
        int x0 = min(max((int)xf, 0), Wl - 1);
        int x1 = min(max((int)xf + 1, 0), Wl - 1);
        int y0 = min(max((int)yf, 0), Hl - 1);
        int y1 = min(max((int)yf + 1, 0), Hl - 1);
        size_t b = ((size_t)cam * S_TOT + s0_[l]) * CC + h * HDD;
        const unsigned short* p00 = value + b + (size_t)(y0 * Wl + x0) * CC;
        const unsigned short* p01 = value + b + (size_t)(y0 * Wl + x1) * CC;
        const unsigned short* p10 = value + b + (size_t)(y1 * Wl + x0) * CC;
        const unsigned short* p11 = value + b + (size_t)(y1 * Wl + x1) * CC;
        float w00 = ws * (1.f - wx) * (1.f - wy);
        float w01 = ws * wx * (1.f - wy);
        float w10 = ws * (1.f - wx) * wy;
        float w11 = ws * wx * wy;
        bf16x8 va0 = *(const bf16x8*)p00, va1 = *(const bf16x8*)(p00 + 8);
        bf16x8 vb0 = *(const bf16x8*)p01, vb1 = *(const bf16x8*)(p01 + 8);
        bf16x8 vc0 = *(const bf16x8*)p10, vc1 = *(const bf16x8*)(p10 + 8);
        bf16x8 vd0 = *(const bf16x8*)p11, vd1 = *(const bf16x8*)(p11 + 8);
#pragma unroll
        for (int d = 0; d < 8; ++d)
            acc[d] += w00 * bf2f(va0[d]) + w01 * bf2f(vb0[d]) + w10 * bf2f(vc0[d]) + w11 * bf2f(vd0[d]);
#pragma unroll
        for (int d = 0; d < 8; ++d)
            acc[8 + d] += w00 * bf2f(va1[d]) + w01 * bf2f(vb1[d]) + w10 * bf2f(vc1[d]) + w11 * bf2f(vd1[d]);
    }

    // reduce over 32 slots via xor-shuffle within each 32-lane group (fixed h)
#pragma unroll
    for (int d = 0; d < 16; ++d) {
        float a = acc[d];
#pragma unroll
        for (int s = 16; s >= 1; s >>= 1) a += __shfl_xor(a, s, 32);
        acc[d] = a;
    }
    if (slot == 0) {
#pragma unroll
        for (int d = 0; d < 16; ++d)
            sampout[(size_t)n * CC + h * HDD + d] = acc[d];
    }
}

// ---------------- launch ----------------
extern "C" void kernel_launch(void* const* d_in, const int* in_sizes, int n_in,
                              void* d_out, int out_size, void* d_ws, size_t ws_size,
                              hipStream_t stream) {
    const float* query = (const float*)d_in[0];
    const float* gp    = (const float*)d_in[1];
    const float* ms    = (const float*)d_in[2];
    const float* depth = (const float*)d_in[3];
    const float* l2i   = (const float*)d_in[4];
    const int*   ih    = (const int*)d_in[5];
    const int*   iw    = (const int*)d_in[6];
    const float* Wsc   = (const float*)d_in[7];
    const float* bsc   = (const float*)d_in[8];
    const float* scg   = (const float*)d_in[9];
    const float* scb   = (const float*)d_in[10];
    const float* refw  = (const float*)d_in[11];
    const float* refb  = (const float*)d_in[12];
    const float* offw  = (const float*)d_in[13];
    const float* offbi = (const float*)d_in[14];
    const float* aww   = (const float*)d_in[15];
    const float* awb   = (const float*)d_in[16];
    const float* valw  = (const float*)d_in[17];
    const float* valb  = (const float*)d_in[18];
    const float* outw  = (const float*)d_in[19];
    const float* outb  = (const float*)d_in[20];
    const float* ang   = (const float*)d_in[21];
    const float* anb   = (const float*)d_in[22];
    const float* f1w   = (const float*)d_in[23];
    const float* f1b   = (const float*)d_in[24];
    const float* f2w   = (const float*)d_in[25];
    const float* f2b   = (const float*)d_in[26];
    const float* fng   = (const float*)d_in[27];
    const float* fnb   = (const float*)d_in[28];
    const float* p1w   = (const float*)d_in[29];
    const float* p1b   = (const float*)d_in[30];
    const float* p2w   = (const float*)d_in[31];
    const float* p2b   = (const float*)d_in[32];

    float* outq = (float*)d_out;            // 1024*128
    float* outp = outq + NQ * CC;           // 1024*28

    // workspace carve. [grid|cnt|flatidx|convacc] zeroed with one memset.
    float* ws = (float*)d_ws;
    size_t o = 0;
    float* grid    = ws + o; o += (size_t)GG * GG * GG * CC;   // 4,194,304
    float* cnt     = ws + o; o += GG * GG * GG;                // 32,768
    int*   flatidx = (int*)(ws + o); o += NQ;
    float* convacc = ws + o; o += NQ * CC;
    size_t zero_floats = o;
    float* q1      = ws + o; o += NQ * CC;
    float* wm      = ws + o; o += CAM * NQ * RR;
    float* r2u     = ws + o; o += CAM * NQ * RR;
    float* r2v     = ws + o; o += CAM * NQ * RR;
    float* sampout = ws + o; o += NQ * CC;
    float* q2      = ws + o; o += NQ * CC;
    float* ffn1    = ws + o; o += NQ * 512;
    float* p1out   = ws + o; o += NQ * CC;
    float* p2bp    = ws + o; o += 128;
    // u16 region
    unsigned short* u16base = (unsigned short*)(ws + o);
    size_t uo = 0;
    unsigned short* value = u16base + uo; uo += (size_t)CAM * S_TOT * CC;  // 11,489,280
    unsigned short* offsb = u16base + uo; uo += (size_t)NQ * 2048;
    unsigned short* attn  = u16base + uo; uo += (size_t)NQ * 1024;
    unsigned short* offwT = u16base + uo; uo += (size_t)2048 * 128;
    unsigned short* awwT  = u16base + uo; uo += (size_t)1024 * 128;
    unsigned short* valwT = u16base + uo; uo += 128 * 128;
    unsigned short* outwT = u16base + uo; uo += 128 * 128;
    unsigned short* f1wT  = u16base + uo; uo += 512 * 128;
    unsigned short* f2wT  = u16base + uo; uo += 128 * 512;
    unsigned short* p1wT  = u16base + uo; uo += 128 * 128;
    unsigned short* p2wT  = u16base + uo; uo += 128 * 128;
    unsigned short* WscT  = u16base + uo; uo += (size_t)27 * 128 * 128;
    (void)ws_size; (void)in_sizes; (void)n_in; (void)out_size;

    k_wt_all<<<dim3(2, 2, 63), 256, 0, stream>>>(Wsc, WscT, valw, valwT, outw, outwT,
                                                 p1w, p1wT, f1w, f1wT, f2w, f2wT,
                                                 offw, offwT, aww, awwT, p2w, p2wT, p2b, p2bp);
    hipMemsetAsync(ws, 0, zero_floats * sizeof(float), stream);

    k_scatter<<<NQ, CC, 0, stream>>>(query, gp, grid, cnt, flatidx);
    k_conv1m<<<dim3(8, 27), 256, 0, stream>>>(grid, cnt, flatidx, WscT, convacc);
    k_ln_conv<<<NQ, CC, 0, stream>>>(query, convacc, bsc, scg, scb, q1);

    k_mfma_bt<128, 0, true><<<dim3(16, 8), 256, 0, stream>>>(q1, offwT, offbi, nullptr, nullptr, nullptr,
                                                             offsb, NQ, 128, 2048, 2048, 0);
    k_mfma_bt<128, 2, true><<<dim3(8, 8), 256, 0, stream>>>(q1, awwT, awb, nullptr, nullptr, nullptr,
                                                            attn, NQ, 128, 1024, 1024, 0);
    k_proj<<<NQ, 64, 0, stream>>>(q1, refw, refb, gp, l2i, depth, ih, iw, wm, r2u, r2v);

    k_valproj<<<(CAM * S_TOT + 63) / 64, 256, 0, stream>>>(ms, valwT, valb, value, CAM * S_TOT);
    k_sample<<<NQ, 256, 0, stream>>>(value, offsb, attn, wm, r2u, r2v, sampout);

    // attn out-proj + residual + LN -> q2
    k_mfma_bt<32, 1, false><<<dim3(1, 32), 256, 0, stream>>>(sampout, outwT, outb, q1, ang, anb,
                                                             q2, NQ, 128, 128, 128, 0);
    // FFN
    k_mfma_bt<32, 0, false><<<dim3(4, 32), 256, 0, stream>>>(q2, f1wT, f1b, nullptr, nullptr, nullptr,
                                                             ffn1, NQ, 128, 512, 512, 1);
    k_mfma_bt<32, 1, false><<<dim3(1, 32), 256, 0, stream>>>(ffn1, f2wT, f2b, q2, fng, fnb,
                                                             outq, NQ, 512, 128, 128, 0);
    // props head
    k_mfma_bt<32, 0, false><<<dim3(1, 32), 256, 0, stream>>>(outq, p1wT, p1b, nullptr, nullptr, nullptr,
                                                             p1out, NQ, 128, 128, 128, 1);
    k_mfma_bt<32, 0, false><<<dim3(1, 32), 256, 0, stream>>>(p1out, p2wT, p2bp, gp, nullptr, nullptr,
                                                             outp, NQ, 128, 128, PROPN, 0);
}

// Round 8
// 282.639 us; speedup vs baseline: 2.9927x; 1.0706x over previous
//
#include <hip/hip_runtime.h>
#include <hip/hip_bf16.h>
#include <math.h>

// ---------------- constants ----------------
#define NQ    1024
#define CC    128
#define CAM   6
#define RR    4
#define LL    4
#define PP    8
#define HHD   8     // heads
#define HDD   16    // head dim
#define GG    32
#define S_TOT 14960
#define PROPN 28

typedef __attribute__((ext_vector_type(8))) short bf16x8;
typedef __attribute__((ext_vector_type(4))) float f32x4;

__device__ __forceinline__ float gelu_tanh(float x) {
    return 0.5f * x * (1.0f + tanhf(0.7978845608028654f * (x + 0.044715f * x * x * x)));
}

__device__ __forceinline__ unsigned short f2bf(float f) {
    union { float f; unsigned int u; } x; x.f = f;
    unsigned int r = (x.u + 0x7FFFu + ((x.u >> 16) & 1u)) >> 16;
    return (unsigned short)r;
}

__device__ __forceinline__ float bf2f(short s) {
    union { unsigned int u; float f; } x;
    x.u = ((unsigned int)(unsigned short)s) << 16;
    return x.f;
}

// ---------------- fused weight transpose+convert (all weights, one dispatch) ----------
__global__ void k_wt_all(const float* __restrict__ Wsc, unsigned short* __restrict__ WscT,
                         const float* __restrict__ valw, unsigned short* __restrict__ valwT,
                         const float* __restrict__ outw, unsigned short* __restrict__ outwT,
                         const float* __restrict__ p1w, unsigned short* __restrict__ p1wT,
                         const float* __restrict__ f1w, unsigned short* __restrict__ f1wT,
                         const float* __restrict__ f2w, unsigned short* __restrict__ f2wT,
                         const float* __restrict__ offw, unsigned short* __restrict__ offwT,
                         const float* __restrict__ aww, unsigned short* __restrict__ awwT,
                         const float* __restrict__ p2w, unsigned short* __restrict__ p2wT,
                         const float* __restrict__ p2b, float* __restrict__ p2bp) {
    __shared__ float t[64][65];
    int z = blockIdx.z;
    int n0 = blockIdx.x * 64, k0 = blockIdx.y * 64, tid = threadIdx.x;
    if (z == 62) {
#pragma unroll
        for (int it = 0; it < 16; ++it) {
            int idx = tid + it * 256;
            int r = idx >> 6, c = idx & 63;
            t[r][c] = (n0 + c < PROPN) ? p2w[(size_t)(k0 + r) * PROPN + n0 + c] : 0.f;
        }
        __syncthreads();
#pragma unroll
        for (int it = 0; it < 16; ++it) {
            int idx = tid + it * 256;
            int r = idx >> 6, c = idx & 63;
            p2wT[(size_t)(n0 + r) * 128 + k0 + c] = f2bf(t[c][r]);
        }
        if (blockIdx.x == 0 && blockIdx.y == 0 && tid < 128)
            p2bp[tid] = (tid < PROPN) ? p2b[tid] : 0.f;
        return;
    }
    const float* src; unsigned short* dst; int ss, ds;
    if (z < 27)       { src = Wsc + (size_t)z * 16384; dst = WscT + (size_t)z * 16384; ss = 128; ds = 128; }
    else if (z == 27) { src = valw; dst = valwT; ss = 128; ds = 128; }
    else if (z == 28) { src = outw; dst = outwT; ss = 128; ds = 128; }
    else if (z == 29) { src = p1w;  dst = p1wT;  ss = 128; ds = 128; }
    else if (z < 34)  { int q = z - 30; src = f1w + q * 128; dst = f1wT + (size_t)q * 16384; ss = 512;  ds = 128; }
    else if (z < 38)  { int q = z - 34; src = f2w + (size_t)q * 16384; dst = f2wT + q * 128; ss = 128;  ds = 512; }
    else if (z < 54)  { int q = z - 38; src = offw + q * 128; dst = offwT + (size_t)q * 16384; ss = 2048; ds = 128; }
    else              { int q = z - 54; src = aww + q * 128;  dst = awwT + (size_t)q * 16384; ss = 1024; ds = 128; }
#pragma unroll
    for (int it = 0; it < 16; ++it) {
        int idx = tid + it * 256;
        int r = idx >> 6, c = idx & 63;
        t[r][c] = src[(size_t)(k0 + r) * ss + n0 + c];
    }
    __syncthreads();
#pragma unroll
    for (int it = 0; it < 16; ++it) {
        int idx = tid + it * 256;
        int r = idx >> 6, c = idx & 63;
        dst[(size_t)(n0 + r) * ds + k0 + c] = f2bf(t[c][r]);
    }
}

// ---------------- scatter-add into voxel grid ----------------
__global__ void k_scatter(const float* __restrict__ q, const float* __restrict__ gp,
                          float* __restrict__ grid, float* __restrict__ cnt,
                          int* __restrict__ flatidx) {
    int n = blockIdx.x;
    int c = threadIdx.x;
    __shared__ int sflat;
    if (c == 0) {
        float mx = gp[n * PROPN + 0], my = gp[n * PROPN + 1], mz = gp[n * PROPN + 2];
        int vx = (int)floorf((mx + 4.0f) * 4.0f);
        int vy = (int)floorf((my + 4.0f) * 4.0f);
        int vz = (int)floorf((mz + 4.0f) * 4.0f);
        vx = min(max(vx, 0), GG - 1);
        vy = min(max(vy, 0), GG - 1);
        vz = min(max(vz, 0), GG - 1);
        int f = (vx * GG + vy) * GG + vz;
        sflat = f;
        flatidx[n] = f;
        atomicAdd(&cnt[f], 1.0f);
    }
    __syncthreads();
    atomicAdd(&grid[sflat * CC + c], q[n * CC + c]);
}

// ---------------- conv as 27 per-tap MFMA GEMMs with atomic accumulate ----------------
__global__ __launch_bounds__(256) void k_conv1m(
    const float* __restrict__ grid, const float* __restrict__ cnt,
    const int* __restrict__ flatidx, const unsigned short* __restrict__ WT,
    float* __restrict__ accum) {
    __shared__ bf16x8 As[128 * 16];
    __shared__ bf16x8 Bs[128 * 16];
    __shared__ int   nbase[128];
    __shared__ float nscale[128];
    int tid = threadIdx.x;
    int tap = blockIdx.y;
    int q0 = blockIdx.x * 128;
    int dz = tap / 9 - 1, dy = (tap / 3) % 3 - 1, dx = tap % 3 - 1;

    if (tid < 128) {
        int f = flatidx[q0 + tid];
        int nx = (f >> 10) + dz, ny = ((f >> 5) & 31) + dy, nz = (f & 31) + dx;
        bool ok = (nx >= 0 && nx < GG && ny >= 0 && ny < GG && nz >= 0 && nz < GG);
        int nf = ok ? (nx * GG + ny) * GG + nz : 0;
        nbase[tid] = nf;
        nscale[tid] = ok ? 1.0f / fmaxf(cnt[nf], 1.0f) : 0.f;
    }
    __syncthreads();
#pragma unroll
    for (int it = 0; it < 8; ++it) {
        int idx = tid + it * 256;
        int m = idx >> 4, c = idx & 15;
        const float* p = grid + (size_t)nbase[m] * CC + c * 8;
        float s = nscale[m];
        float4 a = *(const float4*)p;
        float4 b = *(const float4*)(p + 4);
        bf16x8 u;
        u[0] = (short)f2bf(a.x * s); u[1] = (short)f2bf(a.y * s);
        u[2] = (short)f2bf(a.z * s); u[3] = (short)f2bf(a.w * s);
        u[4] = (short)f2bf(b.x * s); u[5] = (short)f2bf(b.y * s);
        u[6] = (short)f2bf(b.z * s); u[7] = (short)f2bf(b.w * s);
        As[m * 16 + (c ^ (m & 15))] = u;
    }
    const unsigned short* Wt = WT + (size_t)tap * CC * CC;
#pragma unroll
    for (int it = 0; it < 8; ++it) {
        int idx = tid + it * 256;
        int n = idx >> 4, c = idx & 15;
        bf16x8 w = *(const bf16x8*)(Wt + (size_t)n * CC + c * 8);
        Bs[n * 16 + (c ^ (n & 15))] = w;
    }
    __syncthreads();

    int lane = tid & 63, wv = tid >> 6;
    int wr = (wv >> 1) * 64, wc = (wv & 1) * 64;
    int r = lane & 15, q = lane >> 4;
    f32x4 acc[4][4];
#pragma unroll
    for (int i = 0; i < 4; ++i)
#pragma unroll
        for (int j = 0; j < 4; ++j)
#pragma unroll
            for (int e = 0; e < 4; ++e) acc[i][j][e] = 0.f;
#pragma unroll
    for (int ks = 0; ks < 4; ++ks) {
        bf16x8 bfr[4];
#pragma unroll
        for (int j = 0; j < 4; ++j)
            bfr[j] = Bs[(wc + j * 16 + r) * 16 + ((ks * 4 + q) ^ r)];
#pragma unroll
        for (int i = 0; i < 4; ++i) {
            bf16x8 af = As[(wr + i * 16 + r) * 16 + ((ks * 4 + q) ^ r)];
#pragma unroll
            for (int j = 0; j < 4; ++j)
                acc[i][j] = __builtin_amdgcn_mfma_f32_16x16x32_bf16(af, bfr[j], acc[i][j], 0, 0, 0);
        }
    }
#pragma unroll
    for (int i = 0; i < 4; ++i)
#pragma unroll
        for (int e = 0; e < 4; ++e) {
            int m = q0 + wr + i * 16 + q * 4 + e;
#pragma unroll
            for (int j = 0; j < 4; ++j) {
                int col = wc + j * 16 + r;
                atomicAdd(&accum[(size_t)m * CC + col], acc[i][j][e]);
            }
        }
}

// ---------------- LN(conv) + refoff dots + projection, fused per query ----------------
__global__ void k_ln_conv_proj(const float* __restrict__ a, const float* __restrict__ accum,
                               const float* __restrict__ bconv,
                               const float* __restrict__ g, const float* __restrict__ be,
                               float* __restrict__ out,
                               const float* __restrict__ refw, const float* __restrict__ refb,
                               const float* __restrict__ gp, const float* __restrict__ l2i,
                               const float* __restrict__ depth,
                               const int* __restrict__ ih, const int* __restrict__ iw,
                               float* __restrict__ wm, float* __restrict__ r2u,
                               float* __restrict__ r2v) {
    int n = blockIdx.x, c = threadIdx.x;
    float x = a[n * CC + c] + gelu_tanh(accum[n * CC + c] + bconv[c]);
    __shared__ float red[CC];
    __shared__ float qrow[CC];
    __shared__ float ro[12];
    red[c] = x;
    __syncthreads();
    for (int s = 64; s >= 1; s >>= 1) { if (c < s) red[c] += red[c + s]; __syncthreads(); }
    float m = red[0] * (1.0f / CC);
    __syncthreads();
    float d = x - m;
    red[c] = d * d;
    __syncthreads();
    for (int s = 64; s >= 1; s >>= 1) { if (c < s) red[c] += red[c + s]; __syncthreads(); }
    float v = red[0] * (1.0f / CC);
    float qv = d * rsqrtf(v + 1e-5f) * g[c] + be[c];
    out[n * CC + c] = qv;
    qrow[c] = qv;
    __syncthreads();
    if (c < 12) {
        float s = refb[c];
#pragma unroll 4
        for (int k = 0; k < 128; ++k) s += qrow[k] * refw[k * 12 + c];
        ro[c] = s;
    }
    __syncthreads();
    if (c < 24) {
        int cam = c >> 2, r = c & 3;
        float fH = (float)(*ih), fW = (float)(*iw);
        const float* M = l2i + cam * 16;
        float px = gp[n * PROPN + 0] + ro[r * 3 + 0];
        float py = gp[n * PROPN + 1] + ro[r * 3 + 1];
        float pz = gp[n * PROPN + 2] + ro[r * 3 + 2];
        float p0 = M[0] * px + M[1] * py + M[2]  * pz + M[3];
        float p1 = M[4] * px + M[5] * py + M[6]  * pz + M[7];
        float p2 = M[8] * px + M[9] * py + M[10] * pz + M[11];
        float zc = fmaxf(p2, 1e-5f);
        float u = p0 / zc, vv = p1 / zc;
        bool valid = (p2 > 1e-5f) && (u >= 0.f) && (u < fW) && (vv >= 0.f) && (vv < fH);
        int iu = min(max((int)(u / fW * 176.f), 0), 175);
        int iv = min(max((int)(vv / fH * 64.f), 0), 63);
        float ds = depth[cam * 64 * 176 + iv * 176 + iu];
        int o = cam * (NQ * RR) + n * RR + r;
        wm[o]  = valid ? expf(-fabsf(p2 - ds)) : 0.f;
        r2u[o] = u / fW;
        r2v[o] = vv / fH;
    }
}

// ---------------- fused off + attn GEMMs (both K=128, M=1024, bf16 out) --------------
__global__ __launch_bounds__(256) void k_qhead(
    const float* __restrict__ A,
    const unsigned short* __restrict__ offwT, const float* __restrict__ offb,
    unsigned short* __restrict__ offsb,
    const unsigned short* __restrict__ awwT, const float* __restrict__ awb,
    unsigned short* __restrict__ attn)
{
    __shared__ bf16x8 As[128 * 16];
    __shared__ bf16x8 Bs[128 * 16];
    __shared__ float xrow[128 * 128];
    bool isoff = blockIdx.x < 16;
    int n0 = (isoff ? blockIdx.x : (blockIdx.x - 16)) * 128;
    const unsigned short* WT = isoff ? offwT : awwT;
    int m0 = blockIdx.y * 128;
    int tid = threadIdx.x, lane = tid & 63, wv = tid >> 6;
    int wr = (wv >> 1) * 64, wc = (wv & 1) * 64;
    int r = lane & 15, q = lane >> 4;

#pragma unroll
    for (int it = 0; it < 8; ++it) {
        int idx = tid + it * 256;
        int m = idx >> 4, c = idx & 15;
        const float* p = A + (size_t)(m0 + m) * 128 + c * 8;
        float4 a = *(const float4*)p;
        float4 b = *(const float4*)(p + 4);
        bf16x8 u;
        u[0] = (short)f2bf(a.x); u[1] = (short)f2bf(a.y);
        u[2] = (short)f2bf(a.z); u[3] = (short)f2bf(a.w);
        u[4] = (short)f2bf(b.x); u[5] = (short)f2bf(b.y);
        u[6] = (short)f2bf(b.z); u[7] = (short)f2bf(b.w);
        As[m * 16 + (c ^ (m & 15))] = u;
    }
#pragma unroll
    for (int it = 0; it < 8; ++it) {
        int idx = tid + it * 256;
        int n = idx >> 4, c = idx & 15;
        Bs[n * 16 + (c ^ (n & 15))] = *(const bf16x8*)(WT + (size_t)(n0 + n) * 128 + c * 8);
    }
    __syncthreads();

    f32x4 acc[4][4];
#pragma unroll
    for (int i = 0; i < 4; ++i)
#pragma unroll
        for (int j = 0; j < 4; ++j)
#pragma unroll
            for (int e = 0; e < 4; ++e) acc[i][j][e] = 0.f;
#pragma unroll
    for (int ks = 0; ks < 4; ++ks) {
        bf16x8 bfr[4];
#pragma unroll
        for (int j = 0; j < 4; ++j)
            bfr[j] = Bs[(wc + j * 16 + r) * 16 + ((ks * 4 + q) ^ r)];
#pragma unroll
        for (int i = 0; i < 4; ++i) {
            bf16x8 af = As[(wr + i * 16 + r) * 16 + ((ks * 4 + q) ^ r)];
#pragma unroll
            for (int j = 0; j < 4; ++j)
                acc[i][j] = __builtin_amdgcn_mfma_f32_16x16x32_bf16(af, bfr[j], acc[i][j], 0, 0, 0);
        }
    }

    if (isoff) {
#pragma unroll
        for (int i = 0; i < 4; ++i)
#pragma unroll
            for (int e = 0; e < 4; ++e) {
                int m = m0 + wr + i * 16 + q * 4 + e;
#pragma unroll
                for (int j = 0; j < 4; ++j) {
                    int col = n0 + wc + j * 16 + r;
                    offsb[(size_t)m * 2048 + col] = f2bf(acc[i][j][e] + offb[col]);
                }
            }
    } else {
#pragma unroll
        for (int i = 0; i < 4; ++i)
#pragma unroll
            for (int e = 0; e < 4; ++e) {
                int ml = wr + i * 16 + q * 4 + e;
#pragma unroll
                for (int j = 0; j < 4; ++j) {
                    int cl = wc + j * 16 + r;
                    xrow[ml * 128 + cl] = acc[i][j][e] + awb[n0 + cl];
                }
            }
        __syncthreads();
        int row = tid >> 1, s = tid & 1;   // TPR = 2
        float* xr = xrow + row * 128;
        float mx = -1e30f;
#pragma unroll
        for (int e = s; e < 128; e += 2) mx = fmaxf(mx, xr[e]);
        mx = fmaxf(mx, __shfl_xor(mx, 1, 2));
        float sum = 0.f;
#pragma unroll
        for (int e = s; e < 128; e += 2) { float ee = expf(xr[e] - mx); xr[e] = ee; sum += ee; }
        sum += __shfl_xor(sum, 1, 2);
        float inv = 1.0f / sum;
        unsigned short* orow = attn + (size_t)(m0 + row) * 1024 + n0;
#pragma unroll
        for (int e = s; e < 128; e += 2) orow[e] = f2bf(xr[e] * inv);
    }
}

// ---------------- value projection: A[M,128] @ WT[128,128]^T -> bf16 out ----------------
__global__ __launch_bounds__(256) void k_valproj(
    const float* __restrict__ A, const unsigned short* __restrict__ WT,
    const float* __restrict__ bias, unsigned short* __restrict__ out, int M)
{
    __shared__ bf16x8 Bs[128 * 16];
    __shared__ unsigned short Os[64 * 128];
    __shared__ float sbias[128];
    int tid = threadIdx.x;
    int m0 = blockIdx.x * 64;
    int lane = tid & 63, wv = tid >> 6;
    int r = lane & 15, q = lane >> 4;

#pragma unroll
    for (int it = 0; it < 8; ++it) {
        int idx = tid + it * 256;
        int n = idx >> 4, c = idx & 15;
        Bs[n * 16 + (c ^ (n & 15))] = *(const bf16x8*)(WT + (size_t)n * 128 + c * 8);
    }
    if (tid < 128) sbias[tid] = bias[tid];
    __syncthreads();

    int row = m0 + wv * 16 + r;
    int mg = min(row, M - 1);
    const float* pA = A + (size_t)mg * 128;

    f32x4 acc[8];
#pragma unroll
    for (int j = 0; j < 8; ++j)
#pragma unroll
        for (int e = 0; e < 4; ++e) acc[j][e] = 0.f;

#pragma unroll
    for (int ks = 0; ks < 4; ++ks) {
        const float* p = pA + ks * 32 + q * 8;
        float4 a = *(const float4*)p;
        float4 b = *(const float4*)(p + 4);
        bf16x8 af;
        af[0] = (short)f2bf(a.x); af[1] = (short)f2bf(a.y);
        af[2] = (short)f2bf(a.z); af[3] = (short)f2bf(a.w);
        af[4] = (short)f2bf(b.x); af[5] = (short)f2bf(b.y);
        af[6] = (short)f2bf(b.z); af[7] = (short)f2bf(b.w);
        bf16x8 bfr[8];
#pragma unroll
        for (int j = 0; j < 8; ++j)
            bfr[j] = Bs[(j * 16 + r) * 16 + ((ks * 4 + q) ^ r)];
#pragma unroll
        for (int j = 0; j < 8; ++j)
            acc[j] = __builtin_amdgcn_mfma_f32_16x16x32_bf16(af, bfr[j], acc[j], 0, 0, 0);
    }

#pragma unroll
    for (int j = 0; j < 8; ++j)
#pragma unroll
        for (int e = 0; e < 4; ++e) {
            int rl = wv * 16 + q * 4 + e;
            Os[rl * 128 + j * 16 + r] = f2bf(acc[j][e] + sbias[j * 16 + r]);
        }
    __syncthreads();
#pragma unroll
    for (int it = 0; it < 4; ++it) {
        int idx = tid + it * 256;
        int rl = idx >> 4, ch = idx & 15;
        int m = m0 + rl;
        if (m < M)
            *(bf16x8*)(out + (size_t)m * 128 + ch * 8) = *(const bf16x8*)&Os[rl * 128 + ch * 8];
    }
}

// ---------------- deformable sampling + weighted reduce (all-bf16 inputs) ----------------
__global__ void k_sample(const unsigned short* __restrict__ value,
                         const unsigned short* __restrict__ offsb,
                         const unsigned short* __restrict__ attn,
                         const float* __restrict__ wm,
                         const float* __restrict__ r2u, const float* __restrict__ r2v,
                         float* __restrict__ sampout) {
    const int Wl_[4] = {176, 88, 44, 22};
    const int Hl_[4] = {64, 32, 16, 8};
    const int s0_[4] = {0, 11264, 14080, 14784};
    int n = blockIdx.x, tid = threadIdx.x;
    __shared__ float s_attn[1024];
    __shared__ float s_offs[2048];
    __shared__ float s_wm[24], s_ru[24], s_rv[24];

    if (tid < 128) {
        bf16x8 v = *(const bf16x8*)(attn + (size_t)n * 1024 + tid * 8);
#pragma unroll
        for (int d = 0; d < 8; ++d) s_attn[tid * 8 + d] = bf2f(v[d]);
    }
    {
        bf16x8 v = *(const bf16x8*)(offsb + (size_t)n * 2048 + tid * 8);
#pragma unroll
        for (int d = 0; d < 8; ++d) s_offs[tid * 8 + d] = bf2f(v[d]);
    }
    if (tid < 24) {
        int cam = tid >> 2, r = tid & 3;
        int o = cam * (NQ * RR) + n * RR + r;
        s_wm[tid] = wm[o]; s_ru[tid] = r2u[o]; s_rv[tid] = r2v[o];
    }
    __syncthreads();

    int h = tid >> 5, slot = tid & 31;
    int l = slot >> 3, p = slot & 7;
    int Wl = Wl_[l], Hl = Hl_[l];
    float fWl = (float)Wl, fHl = (float)Hl;
    float acc[16];
#pragma unroll
    for (int d = 0; d < 16; ++d) acc[d] = 0.f;

    for (int cr = 0; cr < 24; ++cr) {
        int cam = cr >> 2, r = cr & 3;
        float ws = s_attn[h * 128 + r * 32 + l * 8 + p] * s_wm[cr];
        if (ws == 0.f) continue;
        float ox = s_offs[h * 256 + r * 64 + l * 16 + p * 2 + 0];
        float oy = s_offs[h * 256 + r * 64 + l * 16 + p * 2 + 1];
        float x = s_ru[cr] * fWl + ox - 0.5f;
        float y = s_rv[cr] * fHl + oy - 0.5f;
        float xf = floorf(x), yf = floorf(y);
        float wx = x - xf, wy = y - yf;
        int x0 = min(max((int)xf, 0), Wl - 1);
        int x1 = min(max((int)xf + 1, 0), Wl - 1);
        int y0 = min(max((int)yf, 0), Hl - 1);
        int y1 = min(max((int)yf + 1, 0), Hl - 1);
        size_t b = ((size_t)cam * S_TOT + s0_[l]) * CC + h * HDD;
        const unsigned short* p00 = value + b + (size_t)(y0 * Wl + x0) * CC;
        const unsigned short* p01 = value + b + (size_t)(y0 * Wl + x1) * CC;
        const unsigned short* p10 = value + b + (size_t)(y1 * Wl + x0) * CC;
        const unsigned short* p11 = value + b + (size_t)(y1 * Wl + x1) * CC;
        float w00 = ws * (1.f - wx) * (1.f - wy);
        float w01 = ws * wx * (1.f - wy);
        float w10 = ws * (1.f - wx) * wy;
        float w11 = ws * wx * wy;
        bf16x8 va0 = *(const bf16x8*)p00, va1 = *(const bf16x8*)(p00 + 8);
        bf16x8 vb0 = *(const bf16x8*)p01, vb1 = *(const bf16x8*)(p01 + 8);
        bf16x8 vc0 = *(const bf16x8*)p10, vc1 = *(const bf16x8*)(p10 + 8);
        bf16x8 vd0 = *(const bf16x8*)p11, vd1 = *(const bf16x8*)(p11 + 8);
#pragma unroll
        for (int d = 0; d < 8; ++d)
            acc[d] += w00 * bf2f(va0[d]) + w01 * bf2f(vb0[d]) + w10 * bf2f(vc0[d]) + w11 * bf2f(vd0[d]);
#pragma unroll
        for (int d = 0; d < 8; ++d)
            acc[8 + d] += w00 * bf2f(va1[d]) + w01 * bf2f(vb1[d]) + w10 * bf2f(vc1[d]) + w11 * bf2f(vd1[d]);
    }

#pragma unroll
    for (int d = 0; d < 16; ++d) {
        float a = acc[d];
#pragma unroll
        for (int s = 16; s >= 1; s >>= 1) a += __shfl_xor(a, s, 32);
        acc[d] = a;
    }
    if (slot == 0) {
#pragma unroll
        for (int d = 0; d < 16; ++d)
            sampout[(size_t)n * CC + h * HDD + d] = acc[d];
    }
}

// ---------------- fused tail: out-proj+LN -> FFN -> LN -> p1 -> p2 ----------------
// 32 blocks x 256 threads; block owns rows m0..m0+31. 4 waves in 2x2: each wave
// owns ONE 16-row tile (wr in {0,16}) x 64 cols (wc in {0,64}).
__global__ __launch_bounds__(256) void k_tail(
    const float* __restrict__ sampout,
    const unsigned short* __restrict__ outwT, const float* __restrict__ outb,
    const float* __restrict__ q1, const float* __restrict__ ang, const float* __restrict__ anb,
    const unsigned short* __restrict__ f1wT, const float* __restrict__ f1b,
    const unsigned short* __restrict__ f2wT, const float* __restrict__ f2b,
    const float* __restrict__ fng, const float* __restrict__ fnb,
    const unsigned short* __restrict__ p1wT, const float* __restrict__ p1b,
    const unsigned short* __restrict__ p2wT, const float* __restrict__ p2bp,
    const float* __restrict__ gp, float* __restrict__ outq, float* __restrict__ outp)
{
    __shared__ bf16x8 As[32 * 16];      // 8 KB: current K=128 input fragments
    __shared__ bf16x8 Aff[32 * 64];     // 32 KB: ffn1 fragments (K=512); reused as As2
    __shared__ float xrow[32 * 128];    // 16 KB: epilogue staging
    __shared__ float q2s[32 * 128];     // 16 KB: fp32 row cache (q2, then LN2 out)
    unsigned short* Affu = (unsigned short*)Aff;
    unsigned short* As2u = (unsigned short*)Aff;   // reuse after GEMM3
    int tid = threadIdx.x, m0 = blockIdx.x * 32;
    int lane = tid & 63, wv = tid >> 6;
    int wr = (wv >> 1) * 16, wc = (wv & 1) * 64;
    int r = lane & 15, q = lane >> 4;
    int lrow = tid >> 3, ls = tid & 7;            // LN: 8 threads/row

    // stage A from sampout
#pragma unroll
    for (int it = 0; it < 2; ++it) {
        int idx = tid + it * 256;
        int m = idx >> 4, c = idx & 15;
        const float* p = sampout + (size_t)(m0 + m) * 128 + c * 8;
        float4 a = *(const float4*)p;
        float4 b = *(const float4*)(p + 4);
        bf16x8 u;
        u[0] = (short)f2bf(a.x); u[1] = (short)f2bf(a.y);
        u[2] = (short)f2bf(a.z); u[3] = (short)f2bf(a.w);
        u[4] = (short)f2bf(b.x); u[5] = (short)f2bf(b.y);
        u[6] = (short)f2bf(b.z); u[7] = (short)f2bf(b.w);
        As[m * 16 + (c ^ (m & 15))] = u;
    }
    __syncthreads();

    f32x4 acc[4];
    // ---- GEMM1: out-proj (K=128,N=128) ----
#pragma unroll
    for (int j = 0; j < 4; ++j)
#pragma unroll
        for (int e = 0; e < 4; ++e) acc[j][e] = 0.f;
#pragma unroll
    for (int ks = 0; ks < 4; ++ks) {
        bf16x8 af = As[(wr + r) * 16 + ((ks * 4 + q) ^ r)];
#pragma unroll
        for (int j = 0; j < 4; ++j) {
            bf16x8 bfr = *(const bf16x8*)(outwT + (size_t)(wc + j * 16 + r) * 128 + (ks * 4 + q) * 8);
            acc[j] = __builtin_amdgcn_mfma_f32_16x16x32_bf16(af, bfr, acc[j], 0, 0, 0);
        }
    }
#pragma unroll
    for (int e = 0; e < 4; ++e) {
        int ml = wr + q * 4 + e;
#pragma unroll
        for (int j = 0; j < 4; ++j) {
            int cl = wc + j * 16 + r;
            xrow[ml * 128 + cl] = acc[j][e] + outb[cl] + q1[(size_t)(m0 + ml) * 128 + cl];
        }
    }
    __syncthreads();
    // LN1 -> q2s
    {
        float* xr = xrow + lrow * 128;
        float sum = 0.f;
#pragma unroll
        for (int e = ls; e < 128; e += 8) sum += xr[e];
#pragma unroll
        for (int d = 4; d; d >>= 1) sum += __shfl_xor(sum, d, 8);
        float mean = sum * (1.0f / 128.0f);
        float var = 0.f;
#pragma unroll
        for (int e = ls; e < 128; e += 8) { float dd = xr[e] - mean; var += dd * dd; }
#pragma unroll
        for (int d = 4; d; d >>= 1) var += __shfl_xor(var, d, 8);
        float rstd = rsqrtf(var * (1.0f / 128.0f) + 1e-5f);
#pragma unroll
        for (int e = ls; e < 128; e += 8)
            q2s[lrow * 128 + e] = (xr[e] - mean) * rstd * ang[e] + anb[e];
    }
    __syncthreads();
    // pack q2 -> As
#pragma unroll
    for (int it = 0; it < 2; ++it) {
        int idx = tid + it * 256;
        int m = idx >> 4, c = idx & 15;
        const float* p = q2s + m * 128 + c * 8;
        bf16x8 u;
#pragma unroll
        for (int d = 0; d < 8; ++d) u[d] = (short)f2bf(p[d]);
        As[m * 16 + (c ^ (m & 15))] = u;
    }
    __syncthreads();

    // ---- GEMM2: FFN1 (K=128,N=512, gelu) -> Aff ----
#pragma unroll
    for (int nt = 0; nt < 4; ++nt) {
#pragma unroll
        for (int j = 0; j < 4; ++j)
#pragma unroll
            for (int e = 0; e < 4; ++e) acc[j][e] = 0.f;
#pragma unroll
        for (int ks = 0; ks < 4; ++ks) {
            bf16x8 af = As[(wr + r) * 16 + ((ks * 4 + q) ^ r)];
#pragma unroll
            for (int j = 0; j < 4; ++j) {
                bf16x8 bfr = *(const bf16x8*)(f1wT + (size_t)(nt * 128 + wc + j * 16 + r) * 128 + (ks * 4 + q) * 8);
                acc[j] = __builtin_amdgcn_mfma_f32_16x16x32_bf16(af, bfr, acc[j], 0, 0, 0);
            }
        }
#pragma unroll
        for (int e = 0; e < 4; ++e) {
            int ml = wr + q * 4 + e;
#pragma unroll
            for (int j = 0; j < 4; ++j) {
                int col = nt * 128 + wc + j * 16 + r;
                float v = gelu_tanh(acc[j][e] + f1b[col]);
                Affu[(ml * 64 + ((col >> 3) ^ (ml & 15))) * 8 + (col & 7)] = f2bf(v);
            }
        }
    }
    __syncthreads();

    // ---- GEMM3: FFN2 (K=512,N=128) + resid(q2s) + LN -> outq, pack -> As ----
#pragma unroll
    for (int j = 0; j < 4; ++j)
#pragma unroll
        for (int e = 0; e < 4; ++e) acc[j][e] = 0.f;
#pragma unroll
    for (int ks = 0; ks < 16; ++ks) {
        bf16x8 af = Aff[(wr + r) * 64 + ((ks * 4 + q) ^ r)];
#pragma unroll
        for (int j = 0; j < 4; ++j) {
            bf16x8 bfr = *(const bf16x8*)(f2wT + (size_t)(wc + j * 16 + r) * 512 + (ks * 4 + q) * 8);
            acc[j] = __builtin_amdgcn_mfma_f32_16x16x32_bf16(af, bfr, acc[j], 0, 0, 0);
        }
    }
    __syncthreads();   // all waves done reading Aff before GEMM4 epilogue overwrites it
#pragma unroll
    for (int e = 0; e < 4; ++e) {
        int ml = wr + q * 4 + e;
#pragma unroll
        for (int j = 0; j < 4; ++j) {
            int cl = wc + j * 16 + r;
            xrow[ml * 128 + cl] = acc[j][e] + f2b[cl] + q2s[ml * 128 + cl];
        }
    }
    __syncthreads();
    {
        float* xr = xrow + lrow * 128;
        float sum = 0.f;
#pragma unroll
        for (int e = ls; e < 128; e += 8) sum += xr[e];
#pragma unroll
        for (int d = 4; d; d >>= 1) sum += __shfl_xor(sum, d, 8);
        float mean = sum * (1.0f / 128.0f);
        float var = 0.f;
#pragma unroll
        for (int e = ls; e < 128; e += 8) { float dd = xr[e] - mean; var += dd * dd; }
#pragma unroll
        for (int d = 4; d; d >>= 1) var += __shfl_xor(var, d, 8);
        float rstd = rsqrtf(var * (1.0f / 128.0f) + 1e-5f);
        float* oq = outq + (size_t)(m0 + lrow) * 128;
#pragma unroll
        for (int e = ls; e < 128; e += 8) {
            float v = (xr[e] - mean) * rstd * fng[e] + fnb[e];
            oq[e] = v;
            q2s[lrow * 128 + e] = v;
        }
    }
    __syncthreads();
#pragma unroll
    for (int it = 0; it < 2; ++it) {
        int idx = tid + it * 256;
        int m = idx >> 4, c = idx & 15;
        const float* p = q2s + m * 128 + c * 8;
        bf16x8 u;
#pragma unroll
        for (int d = 0; d < 8; ++d) u[d] = (short)f2bf(p[d]);
        As[m * 16 + (c ^ (m & 15))] = u;
    }
    __syncthreads();

    // ---- GEMM4: p1 (K=128,N=128, gelu) -> As2 (Aff region) ----
#pragma unroll
    for (int j = 0; j < 4; ++j)
#pragma unroll
        for (int e = 0; e < 4; ++e) acc[j][e] = 0.f;
#pragma unroll
    for (int ks = 0; ks < 4; ++ks) {
        bf16x8 af = As[(wr + r) * 16 + ((ks * 4 + q) ^ r)];
#pragma unroll
        for (int j = 0; j < 4; ++j) {
            bf16x8 bfr = *(const bf16x8*)(p1wT + (size_t)(wc + j * 16 + r) * 128 + (ks * 4 + q) * 8);
            acc[j] = __builtin_amdgcn_mfma_f32_16x16x32_bf16(af, bfr, acc[j], 0, 0, 0);
        }
    }
#pragma unroll
    for (int e = 0; e < 4; ++e) {
        int ml = wr + q * 4 + e;
#pragma unroll
        for (int j = 0; j < 4; ++j) {
            int cl = wc + j * 16 + r;
            float v = gelu_tanh(acc[j][e] + p1b[cl]);
            As2u[(ml * 16 + ((cl >> 3) ^ (ml & 15))) * 8 + (cl & 7)] = f2bf(v);
        }
    }
    __syncthreads();

    // ---- GEMM5: p2 (K=128, N=128 padded, valid cols < 28) + gp resid -> outp ----
#pragma unroll
    for (int j = 0; j < 4; ++j)
#pragma unroll
        for (int e = 0; e < 4; ++e) acc[j][e] = 0.f;
#pragma unroll
    for (int ks = 0; ks < 4; ++ks) {
        bf16x8 af = Aff[(wr + r) * 16 + ((ks * 4 + q) ^ r)];   // As2 view
#pragma unroll
        for (int j = 0; j < 4; ++j) {
            bf16x8 bfr = *(const bf16x8*)(p2wT + (size_t)(wc + j * 16 + r) * 128 + (ks * 4 + q) * 8);
            acc[j] = __builtin_amdgcn_mfma_f32_16x16x32_bf16(af, bfr, acc[j], 0, 0, 0);
        }
    }
#pragma unroll
    for (int e = 0; e < 4; ++e) {
        int m = m0 + wr + q * 4 + e;
#pragma unroll
        for (int j = 0; j < 4; ++j) {
            int cl = wc + j * 16 + r;
            if (cl < PROPN)
                outp[(size_t)m * PROPN + cl] = acc[j][e] + p2bp[cl] + gp[(size_t)m * PROPN + cl];
        }
    }
}

// ---------------- launch ----------------
extern "C" void kernel_launch(void* const* d_in, const int* in_sizes, int n_in,
                              void* d_out, int out_size, void* d_ws, size_t ws_size,
                              hipStream_t stream) {
    const float* query = (const float*)d_in[0];
    const float* gp    = (const float*)d_in[1];
    const float* ms    = (const float*)d_in[2];
    const float* depth = (const float*)d_in[3];
    const float* l2i   = (const float*)d_in[4];
    const int*   ih    = (const int*)d_in[5];
    const int*   iw    = (const int*)d_in[6];
    const float* Wsc   = (const float*)d_in[7];
    const float* bsc   = (const float*)d_in[8];
    const float* scg   = (const float*)d_in[9];
    const float* scb   = (const float*)d_in[10];
    const float* refw  = (const float*)d_in[11];
    const float* refb  = (const float*)d_in[12];
    const float* offw  = (const float*)d_in[13];
    const float* offbi = (const float*)d_in[14];
    const float* aww   = (const float*)d_in[15];
    const float* awb   = (const float*)d_in[16];
    const float* valw  = (const float*)d_in[17];
    const float* valb  = (const float*)d_in[18];
    const float* outw  = (const float*)d_in[19];
    const float* outb  = (const float*)d_in[20];
    const float* ang   = (const float*)d_in[21];
    const float* anb   = (const float*)d_in[22];
    const float* f1w   = (const float*)d_in[23];
    const float* f1b   = (const float*)d_in[24];
    const float* f2w   = (const float*)d_in[25];
    const float* f2b   = (const float*)d_in[26];
    const float* fng   = (const float*)d_in[27];
    const float* fnb   = (const float*)d_in[28];
    const float* p1w   = (const float*)d_in[29];
    const float* p1b   = (const float*)d_in[30];
    const float* p2w   = (const float*)d_in[31];
    const float* p2b   = (const float*)d_in[32];

    float* outq = (float*)d_out;            // 1024*128
    float* outp = outq + NQ * CC;           // 1024*28

    // workspace carve. [grid|cnt|flatidx|convacc] zeroed with one memset.
    float* ws = (float*)d_ws;
    size_t o = 0;
    float* grid    = ws + o; o += (size_t)GG * GG * GG * CC;
    float* cnt     = ws + o; o += GG * GG * GG;
    int*   flatidx = (int*)(ws + o); o += NQ;
    float* convacc = ws + o; o += NQ * CC;
    size_t zero_floats = o;
    float* q1      = ws + o; o += NQ * CC;
    float* wm      = ws + o; o += CAM * NQ * RR;
    float* r2u     = ws + o; o += CAM * NQ * RR;
    float* r2v     = ws + o; o += CAM * NQ * RR;
    float* sampout = ws + o; o += NQ * CC;
    float* p2bp    = ws + o; o += 128;
    unsigned short* u16base = (unsigned short*)(ws + o);
    size_t uo = 0;
    unsigned short* value = u16base + uo; uo += (size_t)CAM * S_TOT * CC;
    unsigned short* offsb = u16base + uo; uo += (size_t)NQ * 2048;
    unsigned short* attn  = u16base + uo; uo += (size_t)NQ * 1024;
    unsigned short* offwT = u16base + uo; uo += (size_t)2048 * 128;
    unsigned short* awwT  = u16base + uo; uo += (size_t)1024 * 128;
    unsigned short* valwT = u16base + uo; uo += 128 * 128;
    unsigned short* outwT = u16base + uo; uo += 128 * 128;
    unsigned short* f1wT  = u16base + uo; uo += 512 * 128;
    unsigned short* f2wT  = u16base + uo; uo += 128 * 512;
    unsigned short* p1wT  = u16base + uo; uo += 128 * 128;
    unsigned short* p2wT  = u16base + uo; uo += 128 * 128;
    unsigned short* WscT  = u16base + uo; uo += (size_t)27 * 128 * 128;
    (void)ws_size; (void)in_sizes; (void)n_in; (void)out_size;

    k_wt_all<<<dim3(2, 2, 63), 256, 0, stream>>>(Wsc, WscT, valw, valwT, outw, outwT,
                                                 p1w, p1wT, f1w, f1wT, f2w, f2wT,
                                                 offw, offwT, aww, awwT, p2w, p2wT, p2b, p2bp);
    hipMemsetAsync(ws, 0, zero_floats * sizeof(float), stream);

    k_scatter<<<NQ, CC, 0, stream>>>(query, gp, grid, cnt, flatidx);
    k_conv1m<<<dim3(8, 27), 256, 0, stream>>>(grid, cnt, flatidx, WscT, convacc);
    k_ln_conv_proj<<<NQ, CC, 0, stream>>>(query, convacc, bsc, scg, scb, q1,
                                          refw, refb, gp, l2i, depth, ih, iw, wm, r2u, r2v);

    k_qhead<<<dim3(24, 8), 256, 0, stream>>>(q1, offwT, offbi, offsb, awwT, awb, attn);
    k_valproj<<<(CAM * S_TOT + 63) / 64, 256, 0, stream>>>(ms, valwT, valb, value, CAM * S_TOT);
    k_sample<<<NQ, 256, 0, stream>>>(value, offsb, attn, wm, r2u, r2v, sampout);

    k_tail<<<32, 256, 0, stream>>>(sampout, outwT, outb, q1, ang, anb,
                                   f1wT, f1b, f2wT, f2b, fng, fnb,
                                   p1wT, p1b, p2wT, p2bp, gp, outq, outp);
}

// Round 10
// 269.396 us; speedup vs baseline: 3.1398x; 1.0492x over previous
//
#include <hip/hip_runtime.h>
#include <hip/hip_bf16.h>
#include <math.h>

// ---------------- constants ----------------
#define NQ    1024
#define CC    128
#define CAM   6
#define RR    4
#define LL    4
#define PP    8
#define HHD   8     // heads
#define HDD   16    // head dim
#define GG    32
#define S_TOT 14960
#define PROPN 28

typedef __attribute__((ext_vector_type(8))) short bf16x8;
typedef __attribute__((ext_vector_type(4))) float f32x4;

__device__ __forceinline__ float gelu_tanh(float x) {
    return 0.5f * x * (1.0f + tanhf(0.7978845608028654f * (x + 0.044715f * x * x * x)));
}

__device__ __forceinline__ unsigned short f2bf(float f) {
    union { float f; unsigned int u; } x; x.f = f;
    unsigned int r = (x.u + 0x7FFFu + ((x.u >> 16) & 1u)) >> 16;
    return (unsigned short)r;
}

__device__ __forceinline__ float bf2f(short s) {
    union { unsigned int u; float f; } x;
    x.u = ((unsigned int)(unsigned short)s) << 16;
    return x.f;
}

// stage a 128x128 bf16 weight tile (row-major [n][Kw], k-window k0) into swizzled LDS
__device__ __forceinline__ void stageB(bf16x8* dst, const unsigned short* src,
                                       int Kw, int k0, int tid) {
#pragma unroll
    for (int it = 0; it < 8; ++it) {
        int idx = tid + it * 256;
        int nn = idx >> 4, cc = idx & 15;
        dst[nn * 16 + (cc ^ (nn & 15))] = *(const bf16x8*)(src + (size_t)nn * Kw + k0 + cc * 8);
    }
}

// ---------------- fused weight transpose+convert (all weights, one dispatch) ----------
__global__ void k_wt_all(const float* __restrict__ Wsc, unsigned short* __restrict__ WscT,
                         const float* __restrict__ valw, unsigned short* __restrict__ valwT,
                         const float* __restrict__ outw, unsigned short* __restrict__ outwT,
                         const float* __restrict__ p1w, unsigned short* __restrict__ p1wT,
                         const float* __restrict__ f1w, unsigned short* __restrict__ f1wT,
                         const float* __restrict__ f2w, unsigned short* __restrict__ f2wT,
                         const float* __restrict__ offw, unsigned short* __restrict__ offwT,
                         const float* __restrict__ aww, unsigned short* __restrict__ awwT,
                         const float* __restrict__ p2w, unsigned short* __restrict__ p2wT,
                         const float* __restrict__ p2b, float* __restrict__ p2bp) {
    __shared__ float t[64][65];
    int z = blockIdx.z;
    int n0 = blockIdx.x * 64, k0 = blockIdx.y * 64, tid = threadIdx.x;
    if (z == 62) {
#pragma unroll
        for (int it = 0; it < 16; ++it) {
            int idx = tid + it * 256;
            int r = idx >> 6, c = idx & 63;
            t[r][c] = (n0 + c < PROPN) ? p2w[(size_t)(k0 + r) * PROPN + n0 + c] : 0.f;
        }
        __syncthreads();
#pragma unroll
        for (int it = 0; it < 16; ++it) {
            int idx = tid + it * 256;
            int r = idx >> 6, c = idx & 63;
            p2wT[(size_t)(n0 + r) * 128 + k0 + c] = f2bf(t[c][r]);
        }
        if (blockIdx.x == 0 && blockIdx.y == 0 && tid < 128)
            p2bp[tid] = (tid < PROPN) ? p2b[tid] : 0.f;
        return;
    }
    const float* src; unsigned short* dst; int ss, ds;
    if (z < 27)       { src = Wsc + (size_t)z * 16384; dst = WscT + (size_t)z * 16384; ss = 128; ds = 128; }
    else if (z == 27) { src = valw; dst = valwT; ss = 128; ds = 128; }
    else if (z == 28) { src = outw; dst = outwT; ss = 128; ds = 128; }
    else if (z == 29) { src = p1w;  dst = p1wT;  ss = 128; ds = 128; }
    else if (z < 34)  { int q = z - 30; src = f1w + q * 128; dst = f1wT + (size_t)q * 16384; ss = 512;  ds = 128; }
    else if (z < 38)  { int q = z - 34; src = f2w + (size_t)q * 16384; dst = f2wT + q * 128; ss = 128;  ds = 512; }
    else if (z < 54)  { int q = z - 38; src = offw + q * 128; dst = offwT + (size_t)q * 16384; ss = 2048; ds = 128; }
    else              { int q = z - 54; src = aww + q * 128;  dst = awwT + (size_t)q * 16384; ss = 1024; ds = 128; }
#pragma unroll
    for (int it = 0; it < 16; ++it) {
        int idx = tid + it * 256;
        int r = idx >> 6, c = idx & 63;
        t[r][c] = src[(size_t)(k0 + r) * ss + n0 + c];
    }
    __syncthreads();
#pragma unroll
    for (int it = 0; it < 16; ++it) {
        int idx = tid + it * 256;
        int r = idx >> 6, c = idx & 63;
        dst[(size_t)(n0 + r) * ds + k0 + c] = f2bf(t[c][r]);
    }
}

// ---------------- scatter-add into voxel grid ----------------
__global__ void k_scatter(const float* __restrict__ q, const float* __restrict__ gp,
                          float* __restrict__ grid, float* __restrict__ cnt,
                          int* __restrict__ flatidx) {
    int n = blockIdx.x;
    int c = threadIdx.x;
    __shared__ int sflat;
    if (c == 0) {
        float mx = gp[n * PROPN + 0], my = gp[n * PROPN + 1], mz = gp[n * PROPN + 2];
        int vx = (int)floorf((mx + 4.0f) * 4.0f);
        int vy = (int)floorf((my + 4.0f) * 4.0f);
        int vz = (int)floorf((mz + 4.0f) * 4.0f);
        vx = min(max(vx, 0), GG - 1);
        vy = min(max(vy, 0), GG - 1);
        vz = min(max(vz, 0), GG - 1);
        int f = (vx * GG + vy) * GG + vz;
        sflat = f;
        flatidx[n] = f;
        atomicAdd(&cnt[f], 1.0f);
    }
    __syncthreads();
    atomicAdd(&grid[sflat * CC + c], q[n * CC + c]);
}

// ---------------- conv as 27 per-tap MFMA GEMMs with atomic accumulate ----------------
__global__ __launch_bounds__(256) void k_conv1m(
    const float* __restrict__ grid, const float* __restrict__ cnt,
    const int* __restrict__ flatidx, const unsigned short* __restrict__ WT,
    float* __restrict__ accum) {
    __shared__ bf16x8 As[128 * 16];
    __shared__ bf16x8 Bs[128 * 16];
    __shared__ int   nbase[128];
    __shared__ float nscale[128];
    int tid = threadIdx.x;
    int tap = blockIdx.y;
    int q0 = blockIdx.x * 128;
    int dz = tap / 9 - 1, dy = (tap / 3) % 3 - 1, dx = tap % 3 - 1;

    if (tid < 128) {
        int f = flatidx[q0 + tid];
        int nx = (f >> 10) + dz, ny = ((f >> 5) & 31) + dy, nz = (f & 31) + dx;
        bool ok = (nx >= 0 && nx < GG && ny >= 0 && ny < GG && nz >= 0 && nz < GG);
        int nf = ok ? (nx * GG + ny) * GG + nz : 0;
        nbase[tid] = nf;
        nscale[tid] = ok ? 1.0f / fmaxf(cnt[nf], 1.0f) : 0.f;
    }
    __syncthreads();
#pragma unroll
    for (int it = 0; it < 8; ++it) {
        int idx = tid + it * 256;
        int m = idx >> 4, c = idx & 15;
        const float* p = grid + (size_t)nbase[m] * CC + c * 8;
        float s = nscale[m];
        float4 a = *(const float4*)p;
        float4 b = *(const float4*)(p + 4);
        bf16x8 u;
        u[0] = (short)f2bf(a.x * s); u[1] = (short)f2bf(a.y * s);
        u[2] = (short)f2bf(a.z * s); u[3] = (short)f2bf(a.w * s);
        u[4] = (short)f2bf(b.x * s); u[5] = (short)f2bf(b.y * s);
        u[6] = (short)f2bf(b.z * s); u[7] = (short)f2bf(b.w * s);
        As[m * 16 + (c ^ (m & 15))] = u;
    }
    const unsigned short* Wt = WT + (size_t)tap * CC * CC;
#pragma unroll
    for (int it = 0; it < 8; ++it) {
        int idx = tid + it * 256;
        int n = idx >> 4, c = idx & 15;
        bf16x8 w = *(const bf16x8*)(Wt + (size_t)n * CC + c * 8);
        Bs[n * 16 + (c ^ (n & 15))] = w;
    }
    __syncthreads();

    int lane = tid & 63, wv = tid >> 6;
    int wr = (wv >> 1) * 64, wc = (wv & 1) * 64;
    int r = lane & 15, q = lane >> 4;
    f32x4 acc[4][4];
#pragma unroll
    for (int i = 0; i < 4; ++i)
#pragma unroll
        for (int j = 0; j < 4; ++j)
#pragma unroll
            for (int e = 0; e < 4; ++e) acc[i][j][e] = 0.f;
#pragma unroll
    for (int ks = 0; ks < 4; ++ks) {
        bf16x8 bfr[4];
#pragma unroll
        for (int j = 0; j < 4; ++j)
            bfr[j] = Bs[(wc + j * 16 + r) * 16 + ((ks * 4 + q) ^ r)];
#pragma unroll
        for (int i = 0; i < 4; ++i) {
            bf16x8 af = As[(wr + i * 16 + r) * 16 + ((ks * 4 + q) ^ r)];
#pragma unroll
            for (int j = 0; j < 4; ++j)
                acc[i][j] = __builtin_amdgcn_mfma_f32_16x16x32_bf16(af, bfr[j], acc[i][j], 0, 0, 0);
        }
    }
#pragma unroll
    for (int i = 0; i < 4; ++i)
#pragma unroll
        for (int e = 0; e < 4; ++e) {
            int m = q0 + wr + i * 16 + q * 4 + e;
#pragma unroll
            for (int j = 0; j < 4; ++j) {
                int col = wc + j * 16 + r;
                atomicAdd(&accum[(size_t)m * CC + col], acc[i][j][e]);
            }
        }
}

// ---------------- LN(conv) + refoff dots + projection, fused per query ----------------
__global__ void k_ln_conv_proj(const float* __restrict__ a, const float* __restrict__ accum,
                               const float* __restrict__ bconv,
                               const float* __restrict__ g, const float* __restrict__ be,
                               float* __restrict__ out,
                               const float* __restrict__ refw, const float* __restrict__ refb,
                               const float* __restrict__ gp, const float* __restrict__ l2i,
                               const float* __restrict__ depth,
                               const int* __restrict__ ih, const int* __restrict__ iw,
                               float* __restrict__ wm, float* __restrict__ r2u,
                               float* __restrict__ r2v) {
    int n = blockIdx.x, c = threadIdx.x;
    float x = a[n * CC + c] + gelu_tanh(accum[n * CC + c] + bconv[c]);
    __shared__ float red[CC];
    __shared__ float qrow[CC];
    __shared__ float ro[12];
    red[c] = x;
    __syncthreads();
    for (int s = 64; s >= 1; s >>= 1) { if (c < s) red[c] += red[c + s]; __syncthreads(); }
    float m = red[0] * (1.0f / CC);
    __syncthreads();
    float d = x - m;
    red[c] = d * d;
    __syncthreads();
    for (int s = 64; s >= 1; s >>= 1) { if (c < s) red[c] += red[c + s]; __syncthreads(); }
    float v = red[0] * (1.0f / CC);
    float qv = d * rsqrtf(v + 1e-5f) * g[c] + be[c];
    out[n * CC + c] = qv;
    qrow[c] = qv;
    __syncthreads();
    if (c < 12) {
        float s = refb[c];
#pragma unroll 4
        for (int k = 0; k < 128; ++k) s += qrow[k] * refw[k * 12 + c];
        ro[c] = s;
    }
    __syncthreads();
    if (c < 24) {
        int cam = c >> 2, r = c & 3;
        float fH = (float)(*ih), fW = (float)(*iw);
        const float* M = l2i + cam * 16;
        float px = gp[n * PROPN + 0] + ro[r * 3 + 0];
        float py = gp[n * PROPN + 1] + ro[r * 3 + 1];
        float pz = gp[n * PROPN + 2] + ro[r * 3 + 2];
        float p0 = M[0] * px + M[1] * py + M[2]  * pz + M[3];
        float p1 = M[4] * px + M[5] * py + M[6]  * pz + M[7];
        float p2 = M[8] * px + M[9] * py + M[10] * pz + M[11];
        float zc = fmaxf(p2, 1e-5f);
        float u = p0 / zc, vv = p1 / zc;
        bool valid = (p2 > 1e-5f) && (u >= 0.f) && (u < fW) && (vv >= 0.f) && (vv < fH);
        int iu = min(max((int)(u / fW * 176.f), 0), 175);
        int iv = min(max((int)(vv / fH * 64.f), 0), 63);
        float ds = depth[cam * 64 * 176 + iv * 176 + iu];
        int o = cam * (NQ * RR) + n * RR + r;
        wm[o]  = valid ? expf(-fabsf(p2 - ds)) : 0.f;
        r2u[o] = u / fW;
        r2v[o] = vv / fH;
    }
}

// ---------------- fused off + attn GEMMs (both K=128, M=1024, bf16 out) --------------
__global__ __launch_bounds__(256) void k_qhead(
    const float* __restrict__ A,
    const unsigned short* __restrict__ offwT, const float* __restrict__ offb,
    unsigned short* __restrict__ offsb,
    const unsigned short* __restrict__ awwT, const float* __restrict__ awb,
    unsigned short* __restrict__ attn)
{
    __shared__ bf16x8 As[128 * 16];
    __shared__ bf16x8 Bs[128 * 16];
    __shared__ float xrow[128 * 128];
    bool isoff = blockIdx.x < 16;
    int n0 = (isoff ? blockIdx.x : (blockIdx.x - 16)) * 128;
    const unsigned short* WT = isoff ? offwT : awwT;
    int m0 = blockIdx.y * 128;
    int tid = threadIdx.x, lane = tid & 63, wv = tid >> 6;
    int wr = (wv >> 1) * 64, wc = (wv & 1) * 64;
    int r = lane & 15, q = lane >> 4;

#pragma unroll
    for (int it = 0; it < 8; ++it) {
        int idx = tid + it * 256;
        int m = idx >> 4, c = idx & 15;
        const float* p = A + (size_t)(m0 + m) * 128 + c * 8;
        float4 a = *(const float4*)p;
        float4 b = *(const float4*)(p + 4);
        bf16x8 u;
        u[0] = (short)f2bf(a.x); u[1] = (short)f2bf(a.y);
        u[2] = (short)f2bf(a.z); u[3] = (short)f2bf(a.w);
        u[4] = (short)f2bf(b.x); u[5] = (short)f2bf(b.y);
        u[6] = (short)f2bf(b.z); u[7] = (short)f2bf(b.w);
        As[m * 16 + (c ^ (m & 15))] = u;
    }
#pragma unroll
    for (int it = 0; it < 8; ++it) {
        int idx = tid + it * 256;
        int n = idx >> 4, c = idx & 15;
        Bs[n * 16 + (c ^ (n & 15))] = *(const bf16x8*)(WT + (size_t)(n0 + n) * 128 + c * 8);
    }
    __syncthreads();

    f32x4 acc[4][4];
#pragma unroll
    for (int i = 0; i < 4; ++i)
#pragma unroll
        for (int j = 0; j < 4; ++j)
#pragma unroll
            for (int e = 0; e < 4; ++e) acc[i][j][e] = 0.f;
#pragma unroll
    for (int ks = 0; ks < 4; ++ks) {
        bf16x8 bfr[4];
#pragma unroll
        for (int j = 0; j < 4; ++j)
            bfr[j] = Bs[(wc + j * 16 + r) * 16 + ((ks * 4 + q) ^ r)];
#pragma unroll
        for (int i = 0; i < 4; ++i) {
            bf16x8 af = As[(wr + i * 16 + r) * 16 + ((ks * 4 + q) ^ r)];
#pragma unroll
            for (int j = 0; j < 4; ++j)
                acc[i][j] = __builtin_amdgcn_mfma_f32_16x16x32_bf16(af, bfr[j], acc[i][j], 0, 0, 0);
        }
    }

    if (isoff) {
#pragma unroll
        for (int i = 0; i < 4; ++i)
#pragma unroll
            for (int e = 0; e < 4; ++e) {
                int m = m0 + wr + i * 16 + q * 4 + e;
#pragma unroll
                for (int j = 0; j < 4; ++j) {
                    int col = n0 + wc + j * 16 + r;
                    offsb[(size_t)m * 2048 + col] = f2bf(acc[i][j][e] + offb[col]);
                }
            }
    } else {
#pragma unroll
        for (int i = 0; i < 4; ++i)
#pragma unroll
            for (int e = 0; e < 4; ++e) {
                int ml = wr + i * 16 + q * 4 + e;
#pragma unroll
                for (int j = 0; j < 4; ++j) {
                    int cl = wc + j * 16 + r;
                    xrow[ml * 128 + cl] = acc[i][j][e] + awb[n0 + cl];
                }
            }
        __syncthreads();
        int row = tid >> 1, s = tid & 1;   // TPR = 2
        float* xr = xrow + row * 128;
        float mx = -1e30f;
#pragma unroll
        for (int e = s; e < 128; e += 2) mx = fmaxf(mx, xr[e]);
        mx = fmaxf(mx, __shfl_xor(mx, 1, 2));
        float sum = 0.f;
#pragma unroll
        for (int e = s; e < 128; e += 2) { float ee = expf(xr[e] - mx); xr[e] = ee; sum += ee; }
        sum += __shfl_xor(sum, 1, 2);
        float inv = 1.0f / sum;
        unsigned short* orow = attn + (size_t)(m0 + row) * 1024 + n0;
#pragma unroll
        for (int e = s; e < 128; e += 2) orow[e] = f2bf(xr[e] * inv);
    }
}

// ---------------- value projection: A[M,128] @ WT[128,128]^T -> bf16 out ----------------
__global__ __launch_bounds__(256) void k_valproj(
    const float* __restrict__ A, const unsigned short* __restrict__ WT,
    const float* __restrict__ bias, unsigned short* __restrict__ out, int M)
{
    __shared__ bf16x8 Bs[128 * 16];
    __shared__ unsigned short Os[64 * 128];
    __shared__ float sbias[128];
    int tid = threadIdx.x;
    int m0 = blockIdx.x * 64;
    int lane = tid & 63, wv = tid >> 6;
    int r = lane & 15, q = lane >> 4;

#pragma unroll
    for (int it = 0; it < 8; ++it) {
        int idx = tid + it * 256;
        int n = idx >> 4, c = idx & 15;
        Bs[n * 16 + (c ^ (n & 15))] = *(const bf16x8*)(WT + (size_t)n * 128 + c * 8);
    }
    if (tid < 128) sbias[tid] = bias[tid];
    __syncthreads();

    int row = m0 + wv * 16 + r;
    int mg = min(row, M - 1);
    const float* pA = A + (size_t)mg * 128;

    f32x4 acc[8];
#pragma unroll
    for (int j = 0; j < 8; ++j)
#pragma unroll
        for (int e = 0; e < 4; ++e) acc[j][e] = 0.f;

#pragma unroll
    for (int ks = 0; ks < 4; ++ks) {
        const float* p = pA + ks * 32 + q * 8;
        float4 a = *(const float4*)p;
        float4 b = *(const float4*)(p + 4);
        bf16x8 af;
        af[0] = (short)f2bf(a.x); af[1] = (short)f2bf(a.y);
        af[2] = (short)f2bf(a.z); af[3] = (short)f2bf(a.w);
        af[4] = (short)f2bf(b.x); af[5] = (short)f2bf(b.y);
        af[6] = (short)f2bf(b.z); af[7] = (short)f2bf(b.w);
        bf16x8 bfr[8];
#pragma unroll
        for (int j = 0; j < 8; ++j)
            bfr[j] = Bs[(j * 16 + r) * 16 + ((ks * 4 + q) ^ r)];
#pragma unroll
        for (int j = 0; j < 8; ++j)
            acc[j] = __builtin_amdgcn_mfma_f32_16x16x32_bf16(af, bfr[j], acc[j], 0, 0, 0);
    }

#pragma unroll
    for (int j = 0; j < 8; ++j)
#pragma unroll
        for (int e = 0; e < 4; ++e) {
            int rl = wv * 16 + q * 4 + e;
            Os[rl * 128 + j * 16 + r] = f2bf(acc[j][e] + sbias[j * 16 + r]);
        }
    __syncthreads();
#pragma unroll
    for (int it = 0; it < 4; ++it) {
        int idx = tid + it * 256;
        int rl = idx >> 4, ch = idx & 15;
        int m = m0 + rl;
        if (m < M)
            *(bf16x8*)(out + (size_t)m * 128 + ch * 8) = *(const bf16x8*)&Os[rl * 128 + ch * 8];
    }
}

// ---------------- deformable sampling + weighted reduce (all-bf16 inputs) ----------------
__global__ void k_sample(const unsigned short* __restrict__ value,
                         const unsigned short* __restrict__ offsb,
                         const unsigned short* __restrict__ attn,
                         const float* __restrict__ wm,
                         const float* __restrict__ r2u, const float* __restrict__ r2v,
                         float* __restrict__ sampout) {
    const int Wl_[4] = {176, 88, 44, 22};
    const int Hl_[4] = {64, 32, 16, 8};
    const int s0_[4] = {0, 11264, 14080, 14784};
    int n = blockIdx.x, tid = threadIdx.x;
    __shared__ float s_attn[1024];
    __shared__ float s_offs[2048];
    __shared__ float s_wm[24], s_ru[24], s_rv[24];

    if (tid < 128) {
        bf16x8 v = *(const bf16x8*)(attn + (size_t)n * 1024 + tid * 8);
#pragma unroll
        for (int d = 0; d < 8; ++d) s_attn[tid * 8 + d] = bf2f(v[d]);
    }
    {
        bf16x8 v = *(const bf16x8*)(offsb + (size_t)n * 2048 + tid * 8);
#pragma unroll
        for (int d = 0; d < 8; ++d) s_offs[tid * 8 + d] = bf2f(v[d]);
    }
    if (tid < 24) {
        int cam = tid >> 2, r = tid & 3;
        int o = cam * (NQ * RR) + n * RR + r;
        s_wm[tid] = wm[o]; s_ru[tid] = r2u[o]; s_rv[tid] = r2v[o];
    }
    __syncthreads();

    int h = tid >> 5, slot = tid & 31;
    int l = slot >> 3, p = slot & 7;
    int Wl = Wl_[l], Hl = Hl_[l];
    float fWl = (float)Wl, fHl = (float)Hl;
    float acc[16];
#pragma unroll
    for (int d = 0; d < 16; ++d) acc[d] = 0.f;

    for (int cr = 0; cr < 24; ++cr) {
        int cam = cr >> 2, r = cr & 3;
        float ws = s_attn[h * 128 + r * 32 + l * 8 + p] * s_wm[cr];
        if (ws == 0.f) continue;
        float ox = s_offs[h * 256 + r * 64 + l * 16 + p * 2 + 0];
        float oy = s_offs[h * 256 + r * 64 + l * 16 + p * 2 + 1];
        float x = s_ru[cr] * fWl + ox - 0.5f;
        float y = s_rv[cr] * fHl + oy - 0.5f;
        float xf = floorf(x), yf = floorf(y);
        float wx = x - xf, wy = y - yf;
        int x0 = min(max((int)xf, 0), Wl - 1);
        int x1 = min(max((int)xf + 1, 0), Wl - 1);
        int y0 = min(max((int)yf, 0), Hl - 1);
        int y1 = min(max((int)yf + 1, 0), Hl - 1);
        size_t b = ((size_t)cam * S_TOT + s0_[l]) * CC + h * HDD;
        const unsigned short* p00 = value + b + (size_t)(y0 * Wl + x0) * CC;
        const unsigned short* p01 = value + b + (size_t)(y0 * Wl + x1) * CC;
        const unsigned short* p10 = value + b + (size_t)(y1 * Wl + x0) * CC;
        const unsigned short* p11 = value + b + (size_t)(y1 * Wl + x1) * CC;
        float w00 = ws * (1.f - wx) * (1.f - wy);
        float w01 = ws * wx * (1.f - wy);
        float w10 = ws * (1.f - wx) * wy;
        float w11 = ws * wx * wy;
        bf16x8 va0 = *(const bf16x8*)p00, va1 = *(const bf16x8*)(p00 + 8);
        bf16x8 vb0 = *(const bf16x8*)p01, vb1 = *(const bf16x8*)(p01 + 8);
        bf16x8 vc0 = *(const bf16x8*)p10, vc1 = *(const bf16x8*)(p10 + 8);
        bf16x8 vd0 = *(const bf16x8*)p11, vd1 = *(const bf16x8*)(p11 + 8);
#pragma unroll
        for (int d = 0; d < 8; ++d)
            acc[d] += w00 * bf2f(va0[d]) + w01 * bf2f(vb0[d]) + w10 * bf2f(vc0[d]) + w11 * bf2f(vd0[d]);
#pragma unroll
        for (int d = 0; d < 8; ++d)
            acc[8 + d] += w00 * bf2f(va1[d]) + w01 * bf2f(vb1[d]) + w10 * bf2f(vc1[d]) + w11 * bf2f(vd1[d]);
    }

#pragma unroll
    for (int d = 0; d < 16; ++d) {
        float a = acc[d];
#pragma unroll
        for (int s = 16; s >= 1; s >>= 1) a += __shfl_xor(a, s, 32);
        acc[d] = a;
    }
    if (slot == 0) {
#pragma unroll
        for (int d = 0; d < 16; ++d)
            sampout[(size_t)n * CC + h * HDD + d] = acc[d];
    }
}

// ---------------- fused tail with double-buffered LDS weight staging ----------------
__global__ __launch_bounds__(256) void k_tail(
    const float* __restrict__ sampout,
    const unsigned short* __restrict__ outwT, const float* __restrict__ outb,
    const float* __restrict__ q1, const float* __restrict__ ang, const float* __restrict__ anb,
    const unsigned short* __restrict__ f1wT, const float* __restrict__ f1b,
    const unsigned short* __restrict__ f2wT, const float* __restrict__ f2b,
    const float* __restrict__ fng, const float* __restrict__ fnb,
    const unsigned short* __restrict__ p1wT, const float* __restrict__ p1b,
    const unsigned short* __restrict__ p2wT, const float* __restrict__ p2bp,
    const float* __restrict__ gp, float* __restrict__ outq, float* __restrict__ outp)
{
    __shared__ bf16x8 As[32 * 16];       // 8 KB
    __shared__ bf16x8 Bst[2][128 * 16];  // 64 KB
    __shared__ bf16x8 Aff[32 * 64];      // 32 KB
    __shared__ float xrow[32 * 128];     // 16 KB
    __shared__ float q2s[32 * 128];      // 16 KB
    unsigned short* Affu = (unsigned short*)Aff;
    unsigned short* As2u = (unsigned short*)Aff;
    int tid = threadIdx.x, m0 = blockIdx.x * 32;
    int lane = tid & 63, wv = tid >> 6;
    int wr = (wv >> 1) * 16, wc = (wv & 1) * 64;
    int r = lane & 15, q = lane >> 4;
    int lrow = tid >> 3, ls = tid & 7;

    stageB(Bst[0], outwT, 128, 0, tid);            // T0 = out-proj weights
#pragma unroll
    for (int it = 0; it < 2; ++it) {
        int idx = tid + it * 256;
        int m = idx >> 4, c = idx & 15;
        const float* p = sampout + (size_t)(m0 + m) * 128 + c * 8;
        float4 a = *(const float4*)p;
        float4 b = *(const float4*)(p + 4);
        bf16x8 u;
        u[0] = (short)f2bf(a.x); u[1] = (short)f2bf(a.y);
        u[2] = (short)f2bf(a.z); u[3] = (short)f2bf(a.w);
        u[4] = (short)f2bf(b.x); u[5] = (short)f2bf(b.y);
        u[6] = (short)f2bf(b.z); u[7] = (short)f2bf(b.w);
        As[m * 16 + (c ^ (m & 15))] = u;
    }
    __syncthreads();                               // T0 + A ready

    f32x4 acc[4];
    // GEMM1: out-proj from buf0; prefetch f1 nt0 -> buf1
    stageB(Bst[1], f1wT, 128, 0, tid);
#pragma unroll
    for (int j = 0; j < 4; ++j)
#pragma unroll
        for (int e = 0; e < 4; ++e) acc[j][e] = 0.f;
#pragma unroll
    for (int ks = 0; ks < 4; ++ks) {
        bf16x8 af = As[(wr + r) * 16 + ((ks * 4 + q) ^ r)];
#pragma unroll
        for (int j = 0; j < 4; ++j) {
            bf16x8 bfr = Bst[0][(wc + j * 16 + r) * 16 + ((ks * 4 + q) ^ r)];
            acc[j] = __builtin_amdgcn_mfma_f32_16x16x32_bf16(af, bfr, acc[j], 0, 0, 0);
        }
    }
#pragma unroll
    for (int e = 0; e < 4; ++e) {
        int ml = wr + q * 4 + e;
#pragma unroll
        for (int j = 0; j < 4; ++j) {
            int cl = wc + j * 16 + r;
            xrow[ml * 128 + cl] = acc[j][e] + outb[cl] + q1[(size_t)(m0 + ml) * 128 + cl];
        }
    }
    __syncthreads();                               // buf0 free; f1 nt0 ready
    stageB(Bst[0], f1wT + 1 * 128 * 128, 128, 0, tid);   // f1 nt1 -> buf0
    {   // LN1 -> q2s
        float* xr = xrow + lrow * 128;
        float sum = 0.f;
#pragma unroll
        for (int e = ls; e < 128; e += 8) sum += xr[e];
#pragma unroll
        for (int d = 4; d; d >>= 1) sum += __shfl_xor(sum, d, 8);
        float mean = sum * (1.0f / 128.0f);
        float var = 0.f;
#pragma unroll
        for (int e = ls; e < 128; e += 8) { float dd = xr[e] - mean; var += dd * dd; }
#pragma unroll
        for (int d = 4; d; d >>= 1) var += __shfl_xor(var, d, 8);
        float rstd = rsqrtf(var * (1.0f / 128.0f) + 1e-5f);
#pragma unroll
        for (int e = ls; e < 128; e += 8)
            q2s[lrow * 128 + e] = (xr[e] - mean) * rstd * ang[e] + anb[e];
    }
    __syncthreads();
#pragma unroll
    for (int it = 0; it < 2; ++it) {               // pack q2 -> As
        int idx = tid + it * 256;
        int m = idx >> 4, c = idx & 15;
        const float* p = q2s + m * 128 + c * 8;
        bf16x8 u;
#pragma unroll
        for (int d = 0; d < 8; ++d) u[d] = (short)f2bf(p[d]);
        As[m * 16 + (c ^ (m & 15))] = u;
    }
    __syncthreads();

    // GEMM2: FFN1. nt0 reads buf1, nt1 reads buf0 (+stage nt2->buf1),
    // nt2 reads buf1 (+stage nt3->buf0), nt3 reads buf0. No stage at nt0.
#pragma unroll
    for (int nt = 0; nt < 4; ++nt) {
        int cur;
        if (nt == 0) { cur = 1; }
        else if (nt == 1) { cur = 0; stageB(Bst[1], f1wT + 2 * 128 * 128, 128, 0, tid); }
        else if (nt == 2) { cur = 1; stageB(Bst[0], f1wT + 3 * 128 * 128, 128, 0, tid); }
        else { cur = 0; }
#pragma unroll
        for (int j = 0; j < 4; ++j)
#pragma unroll
            for (int e = 0; e < 4; ++e) acc[j][e] = 0.f;
#pragma unroll
        for (int ks = 0; ks < 4; ++ks) {
            bf16x8 af = As[(wr + r) * 16 + ((ks * 4 + q) ^ r)];
#pragma unroll
            for (int j = 0; j < 4; ++j) {
                bf16x8 bfr = Bst[cur][(wc + j * 16 + r) * 16 + ((ks * 4 + q) ^ r)];
                acc[j] = __builtin_amdgcn_mfma_f32_16x16x32_bf16(af, bfr, acc[j], 0, 0, 0);
            }
        }
#pragma unroll
        for (int e = 0; e < 4; ++e) {
            int ml = wr + q * 4 + e;
#pragma unroll
            for (int j = 0; j < 4; ++j) {
                int col = nt * 128 + wc + j * 16 + r;
                float v = gelu_tanh(acc[j][e] + f1b[col]);
                Affu[(ml * 64 + ((col >> 3) ^ (ml & 15))) * 8 + (col & 7)] = f2bf(v);
            }
        }
        __syncthreads();
    }

    // GEMM3: FFN2 over 4 k-chunks, stage-then-compute (alternating buffers)
#pragma unroll
    for (int j = 0; j < 4; ++j)
#pragma unroll
        for (int e = 0; e < 4; ++e) acc[j][e] = 0.f;
    for (int kc = 0; kc < 4; ++kc) {
        stageB(Bst[kc & 1], f2wT, 512, kc * 128, tid);
        __syncthreads();
#pragma unroll
        for (int ks = 0; ks < 4; ++ks) {
            bf16x8 af = Aff[(wr + r) * 64 + ((kc * 16 + ks * 4 + q) ^ r)];
#pragma unroll
            for (int j = 0; j < 4; ++j) {
                bf16x8 bfr = Bst[kc & 1][(wc + j * 16 + r) * 16 + ((ks * 4 + q) ^ r)];
                acc[j] = __builtin_amdgcn_mfma_f32_16x16x32_bf16(af, bfr, acc[j], 0, 0, 0);
            }
        }
        __syncthreads();
    }
#pragma unroll
    for (int e = 0; e < 4; ++e) {
        int ml = wr + q * 4 + e;
#pragma unroll
        for (int j = 0; j < 4; ++j) {
            int cl = wc + j * 16 + r;
            xrow[ml * 128 + cl] = acc[j][e] + f2b[cl] + q2s[ml * 128 + cl];
        }
    }
    __syncthreads();
    stageB(Bst[0], p1wT, 128, 0, tid);
    {   // LN2 -> outq + q2s
        float* xr = xrow + lrow * 128;
        float sum = 0.f;
#pragma unroll
        for (int e = ls; e < 128; e += 8) sum += xr[e];
#pragma unroll
        for (int d = 4; d; d >>= 1) sum += __shfl_xor(sum, d, 8);
        float mean = sum * (1.0f / 128.0f);
        float var = 0.f;
#pragma unroll
        for (int e = ls; e < 128; e += 8) { float dd = xr[e] - mean; var += dd * dd; }
#pragma unroll
        for (int d = 4; d; d >>= 1) var += __shfl_xor(var, d, 8);
        float rstd = rsqrtf(var * (1.0f / 128.0f) + 1e-5f);
        float* oq = outq + (size_t)(m0 + lrow) * 128;
#pragma unroll
        for (int e = ls; e < 128; e += 8) {
            float v = (xr[e] - mean) * rstd * fng[e] + fnb[e];
            oq[e] = v;
            q2s[lrow * 128 + e] = v;
        }
    }
    __syncthreads();
    stageB(Bst[1], p2wT, 128, 0, tid);
#pragma unroll
    for (int it = 0; it < 2; ++it) {               // pack LN2 -> As
        int idx = tid + it * 256;
        int m = idx >> 4, c = idx & 15;
        const float* p = q2s + m * 128 + c * 8;
        bf16x8 u;
#pragma unroll
        for (int d = 0; d < 8; ++d) u[d] = (short)f2bf(p[d]);
        As[m * 16 + (c ^ (m & 15))] = u;
    }
    __syncthreads();

    // GEMM4: p1 (buf0) -> As2
#pragma unroll
    for (int j = 0; j < 4; ++j)
#pragma unroll
        for (int e = 0; e < 4; ++e) acc[j][e] = 0.f;
#pragma unroll
    for (int ks = 0; ks < 4; ++ks) {
        bf16x8 af = As[(wr + r) * 16 + ((ks * 4 + q) ^ r)];
#pragma unroll
        for (int j = 0; j < 4; ++j) {
            bf16x8 bfr = Bst[0][(wc + j * 16 + r) * 16 + ((ks * 4 + q) ^ r)];
            acc[j] = __builtin_amdgcn_mfma_f32_16x16x32_bf16(af, bfr, acc[j], 0, 0, 0);
        }
    }
#pragma unroll
    for (int e = 0; e < 4; ++e) {
        int ml = wr + q * 4 + e;
#pragma unroll
        for (int j = 0; j < 4; ++j) {
            int cl = wc + j * 16 + r;
            float v = gelu_tanh(acc[j][e] + p1b[cl]);
            As2u[(ml * 16 + ((cl >> 3) ^ (ml & 15))) * 8 + (cl & 7)] = f2bf(v);
        }
    }
    __syncthreads();

    // GEMM5: p2 (buf1) + gp resid -> outp
#pragma unroll
    for (int j = 0; j < 4; ++j)
#pragma unroll
        for (int e = 0; e < 4; ++e) acc[j][e] = 0.f;
#pragma unroll
    for (int ks = 0; ks < 4; ++ks) {
        bf16x8 af = Aff[(wr + r) * 16 + ((ks * 4 + q) ^ r)];   // As2 view
#pragma unroll
        for (int j = 0; j < 4; ++j) {
            bf16x8 bfr = Bst[1][(wc + j * 16 + r) * 16 + ((ks * 4 + q) ^ r)];
            acc[j] = __builtin_amdgcn_mfma_f32_16x16x32_bf16(af, bfr, acc[j], 0, 0, 0);
        }
    }
#pragma unroll
    for (int e = 0; e < 4; ++e) {
        int m = m0 + wr + q * 4 + e;
#pragma unroll
        for (int j = 0; j < 4; ++j) {
            int cl = wc + j * 16 + r;
            if (cl < PROPN)
                outp[(size_t)m * PROPN + cl] = acc[j][e] + p2bp[cl] + gp[(size_t)m * PROPN + cl];
        }
    }
}

// ---------------- launch ----------------
extern "C" void kernel_launch(void* const* d_in, const int* in_sizes, int n_in,
                              void* d_out, int out_size, void* d_ws, size_t ws_size,
                              hipStream_t stream) {
    const float* query = (const float*)d_in[0];
    const float* gp    = (const float*)d_in[1];
    const float* ms    = (const float*)d_in[2];
    const float* depth = (const float*)d_in[3];
    const float* l2i   = (const float*)d_in[4];
    const int*   ih    = (const int*)d_in[5];
    const int*   iw    = (const int*)d_in[6];
    const float* Wsc   = (const float*)d_in[7];
    const float* bsc   = (const float*)d_in[8];
    const float* scg   = (const float*)d_in[9];
    const float* scb   = (const float*)d_in[10];
    const float* refw  = (const float*)d_in[11];
    const float* refb  = (const float*)d_in[12];
    const float* offw  = (const float*)d_in[13];
    const float* offbi = (const float*)d_in[14];
    const float* aww   = (const float*)d_in[15];
    const float* awb   = (const float*)d_in[16];
    const float* valw  = (const float*)d_in[17];
    const float* valb  = (const float*)d_in[18];
    const float* outw  = (const float*)d_in[19];
    const float* outb  = (const float*)d_in[20];
    const float* ang   = (const float*)d_in[21];
    const float* anb   = (const float*)d_in[22];
    const float* f1w   = (const float*)d_in[23];
    const float* f1b   = (const float*)d_in[24];
    const float* f2w   = (const float*)d_in[25];
    const float* f2b   = (const float*)d_in[26];
    const float* fng   = (const float*)d_in[27];
    const float* fnb   = (const float*)d_in[28];
    const float* p1w   = (const float*)d_in[29];
    const float* p1b   = (const float*)d_in[30];
    const float* p2w   = (const float*)d_in[31];
    const float* p2b   = (const float*)d_in[32];

    float* outq = (float*)d_out;            // 1024*128
    float* outp = outq + NQ * CC;           // 1024*28

    float* ws = (float*)d_ws;
    size_t o = 0;
    float* grid    = ws + o; o += (size_t)GG * GG * GG * CC;
    float* cnt     = ws + o; o += GG * GG * GG;
    int*   flatidx = (int*)(ws + o); o += NQ;
    float* convacc = ws + o; o += NQ * CC;
    size_t zero_floats = o;
    float* q1      = ws + o; o += NQ * CC;
    float* wm      = ws + o; o += CAM * NQ * RR;
    float* r2u     = ws + o; o += CAM * NQ * RR;
    float* r2v     = ws + o; o += CAM * NQ * RR;
    float* sampout = ws + o; o += NQ * CC;
    float* p2bp    = ws + o; o += 128;
    unsigned short* u16base = (unsigned short*)(ws + o);
    size_t uo = 0;
    unsigned short* value = u16base + uo; uo += (size_t)CAM * S_TOT * CC;
    unsigned short* offsb = u16base + uo; uo += (size_t)NQ * 2048;
    unsigned short* attn  = u16base + uo; uo += (size_t)NQ * 1024;
    unsigned short* offwT = u16base + uo; uo += (size_t)2048 * 128;
    unsigned short* awwT  = u16base + uo; uo += (size_t)1024 * 128;
    unsigned short* valwT = u16base + uo; uo += 128 * 128;
    unsigned short* outwT = u16base + uo; uo += 128 * 128;
    unsigned short* f1wT  = u16base + uo; uo += 512 * 128;
    unsigned short* f2wT  = u16base + uo; uo += 128 * 512;
    unsigned short* p1wT  = u16base + uo; uo += 128 * 128;
    unsigned short* p2wT  = u16base + uo; uo += 128 * 128;
    unsigned short* WscT  = u16base + uo; uo += (size_t)27 * 128 * 128;
    (void)ws_size; (void)in_sizes; (void)n_in; (void)out_size;

    k_wt_all<<<dim3(2, 2, 63), 256, 0, stream>>>(Wsc, WscT, valw, valwT, outw, outwT,
                                                 p1w, p1wT, f1w, f1wT, f2w, f2wT,
                                                 offw, offwT, aww, awwT, p2w, p2wT, p2b, p2bp);
    hipMemsetAsync(ws, 0, zero_floats * sizeof(float), stream);

    k_scatter<<<NQ, CC, 0, stream>>>(query, gp, grid, cnt, flatidx);
    k_conv1m<<<dim3(8, 27), 256, 0, stream>>>(grid, cnt, flatidx, WscT, convacc);
    k_ln_conv_proj<<<NQ, CC, 0, stream>>>(query, convacc, bsc, scg, scb, q1,
                                          refw, refb, gp, l2i, depth, ih, iw, wm, r2u, r2v);

    k_qhead<<<dim3(24, 8), 256, 0, stream>>>(q1, offwT, offbi, offsb, awwT, awb, attn);
    k_valproj<<<(CAM * S_TOT + 63) / 64, 256, 0, stream>>>(ms, valwT, valb, value, CAM * S_TOT);
    k_sample<<<NQ, 256, 0, stream>>>(value, offsb, attn, wm, r2u, r2v, sampout);

    k_tail<<<32, 256, 0, stream>>>(sampout, outwT, outb, q1, ang, anb,
                                   f1wT, f1b, f2wT, f2b, fng, fnb,
                                   p1wT, p1b, p2wT, p2bp, gp, outq, outp);
}